// Round 15
// baseline (564.344 us; speedup 1.0000x reference)
//
#include <hip/hip_runtime.h>
#include <cstdint>
#include <cstddef>

typedef __bf16 bf16_t;
typedef __attribute__((ext_vector_type(8))) __bf16 bf16x8;
typedef __attribute__((ext_vector_type(4))) __bf16 bf16x4;
typedef __attribute__((ext_vector_type(4))) float f32x4;

constexpr int D  = 1024;   // d_model
constexpr int TT = 1024;   // seq len
constexpr int BB = 4;      // batch
constexpr int NH = 16;     // heads
constexpr int HS = 64;     // head size
constexpr int MR = BB * TT; // 4096 rows
constexpr int HF = 4096;   // ffn hidden

__device__ inline void gload_lds16(const bf16_t* g, bf16_t* l)
{
    __builtin_amdgcn_global_load_lds(
        (const __attribute__((address_space(1))) void*)g,
        (__attribute__((address_space(3))) void*)l, 16, 0, 0);
}

// ---------------------------------------------------------------------------
// RMSNorm: f32 in -> bf16 hi (+ optional lo) planes. One block per row.
// ---------------------------------------------------------------------------
template<bool LO>
__global__ __launch_bounds__(256) void rmsnorm_kernel(const float* __restrict__ x,
                                                      const float* __restrict__ gamma,
                                                      bf16_t* __restrict__ oh,
                                                      bf16_t* __restrict__ ol)
{
    int row = blockIdx.x;
    int t   = threadIdx.x;
    const float* xr = x + (size_t)row * D;
    float4 xv = *(const float4*)(xr + t * 4);
    float ss = xv.x * xv.x + xv.y * xv.y + xv.z * xv.z + xv.w * xv.w;
#pragma unroll
    for (int m = 1; m < 64; m <<= 1) ss += __shfl_xor(ss, m, 64);
    __shared__ float part[4];
    if ((t & 63) == 0) part[t >> 6] = ss;
    __syncthreads();
    float tot   = part[0] + part[1] + part[2] + part[3];
    float scale = rsqrtf(tot * (1.0f / D) + 1e-6f);
    float4 gv = *(const float4*)(gamma + t * 4);
    float vals[4] = {xv.x * scale * gv.x, xv.y * scale * gv.y,
                     xv.z * scale * gv.z, xv.w * scale * gv.w};
    bf16x4 vh, vl;
#pragma unroll
    for (int j = 0; j < 4; ++j) {
        bf16_t h = (bf16_t)vals[j];
        vh[j] = h;
        vl[j] = (bf16_t)(vals[j] - (float)h);
    }
    *(bf16x4*)(oh + (size_t)row * D + t * 4) = vh;
    if (LO) *(bf16x4*)(ol + (size_t)row * D + t * 4) = vl;
}

// ---------------------------------------------------------------------------
// concat 3x [1024] f32 biases into one [3072] buffer
// ---------------------------------------------------------------------------
__global__ __launch_bounds__(256) void concat_bias_kernel(const float* __restrict__ a,
                                                          const float* __restrict__ b,
                                                          const float* __restrict__ c,
                                                          float* __restrict__ o)
{
    int i = blockIdx.x * 256 + threadIdx.x;
    o[i] = i < 1024 ? a[i] : (i < 2048 ? b[i - 1024] : c[i - 2048]);
}

// ---------------------------------------------------------------------------
// Weight convert: W f32 [K][N] -> dH (+ optional dL) bf16 [N][K] (transposed).
// ---------------------------------------------------------------------------
template<bool LO>
__global__ __launch_bounds__(256) void convw_kernel(const float* __restrict__ W,
                                                    bf16_t* __restrict__ dH,
                                                    bf16_t* __restrict__ dL,
                                                    int K, int N)
{
    __shared__ float sld[64][65];
    int t = threadIdx.x;
    int k0 = blockIdx.x * 64, n0 = blockIdx.y * 64;
    int kr = t >> 4, nc = (t & 15) * 4;
#pragma unroll
    for (int p = 0; p < 4; ++p) {
        int k = p * 16 + kr;
        float4 v = *(const float4*)(W + (size_t)(k0 + k) * N + n0 + nc);
        sld[k][nc] = v.x; sld[k][nc + 1] = v.y; sld[k][nc + 2] = v.z; sld[k][nc + 3] = v.w;
    }
    __syncthreads();
    int n = t >> 2, kh = (t & 3) * 16;
    bf16x8 h0, l0, h1, l1;
#pragma unroll
    for (int j = 0; j < 8; ++j) {
        float v = sld[kh + j][n];
        bf16_t h = (bf16_t)v;
        h0[j] = h; l0[j] = (bf16_t)(v - (float)h);
    }
#pragma unroll
    for (int j = 0; j < 8; ++j) {
        float v = sld[kh + 8 + j][n];
        bf16_t h = (bf16_t)v;
        h1[j] = h; l1[j] = (bf16_t)(v - (float)h);
    }
    size_t o = (size_t)(n0 + n) * K + k0 + kh;
    *(bf16x8*)(dH + o)     = h0;
    *(bf16x8*)(dH + o + 8) = h1;
    if (LO) {
        *(bf16x8*)(dL + o)     = l0;
        *(bf16x8*)(dL + o + 8) = l1;
    }
}

// ---------------------------------------------------------------------------
// Split-precision GEMM, 128xTN tile (TN = 64 or 128), BK=32, 4 waves.
// ---------------------------------------------------------------------------
template<int TN, bool CM, bool ALO, bool WLO, int OUTM, bool RELU, bool RESID>
__global__ __launch_bounds__(256, 2) void gemm_kernel(
    const bf16_t* __restrict__ Ahp, const bf16_t* __restrict__ Alp,
    const bf16_t* __restrict__ Whp, const bf16_t* __restrict__ Wlp,
    const float* __restrict__ bias, const float* resid,
    float* outf, bf16_t* __restrict__ outh, bf16_t* __restrict__ outl,
    int N, int K)
{
    constexpr int NF = TN / 32;          // n-frags per wave
    constexpr int AP = ALO ? 2 : 1;      // A planes
    constexpr int WP = WLO ? 2 : 1;      // W planes
    __shared__ bf16_t sA[AP][128][32];   // [plane][m][k], linear (gload_lds dest)
    __shared__ bf16_t sW[WP][TN][32];    // [plane][n][k]

    int t = threadIdx.x;
    int l = t & 63, w = t >> 6;
    int lr = l & 15, lg = l >> 4;

    int gx  = gridDim.x;
    int gy  = gridDim.y;
    int nwg = gx * gy;
    int bid = blockIdx.y * gx + blockIdx.x;
    int xcd = bid & 7, idx = bid >> 3;
    int nb, mb;
    if (CM) {
        // B-chunk resident: XCD owns nb in [xcd*gx/8, (xcd+1)*gx/8), mb fast
        int cw = gx >> 3;
        mb = idx % gy;
        nb = xcd * cw + idx / gy;
    } else {
        // A-chunk resident: XCD owns contiguous s-range (nb fast)
        int s = xcd * (nwg >> 3) + idx;
        nb = s % gx; mb = s / gx;
    }
    int m0 = mb * 128, n0 = nb * TN;
    int wr = (w >> 1) * 64, wc = (w & 1) * (TN / 2);

    f32x4 acc[4][NF] = {};

    int srow = (l >> 2);      // 0..15 within chunk
    int sch  = l & 3;         // 16B slot within 64B row

    for (int kk = 0; kk < K; kk += 32) {
        __syncthreads();
        // A planes: 128 rows = 4 waves x 2 chunks x 16
#pragma unroll
        for (int c = 0; c < 2; ++c) {
            int rbase = w * 32 + c * 16;
            int row = rbase + srow;
            int f = (row >> 1) & 3;
            size_t goff = (size_t)row * K + kk + (size_t)((sch ^ f)) * 8;
            gload_lds16(Ahp + (size_t)m0 * K + goff, &sA[0][rbase][0]);
            if (ALO) gload_lds16(Alp + (size_t)m0 * K + goff, &sA[AP - 1][rbase][0]);
        }
        // W planes: TN rows = 4 waves x (TN/64) chunks x 16
#pragma unroll
        for (int c = 0; c < TN / 64; ++c) {
            int rbase = w * (TN / 4) + c * 16;
            int row = rbase + srow;
            int f = (row >> 1) & 3;
            size_t goff = (size_t)row * K + kk + (size_t)((sch ^ f)) * 8;
            gload_lds16(Whp + (size_t)n0 * K + goff, &sW[0][rbase][0]);
            if (WLO) gload_lds16(Wlp + (size_t)n0 * K + goff, &sW[WP - 1][rbase][0]);
        }
        __syncthreads();

        bf16x8 a0[4], a1[4], b0[NF], b1[NF];
#pragma unroll
        for (int m = 0; m < 4; ++m) {
            int row = wr + m * 16 + lr;
            int sl = lg ^ ((row >> 1) & 3);
            a0[m] = *(const bf16x8*)&sA[0][row][sl * 8];
            if (ALO) a1[m] = *(const bf16x8*)&sA[AP - 1][row][sl * 8];
        }
#pragma unroll
        for (int n = 0; n < NF; ++n) {
            int row = wc + n * 16 + lr;
            int sl = lg ^ ((row >> 1) & 3);
            b0[n] = *(const bf16x8*)&sW[0][row][sl * 8];
            if (WLO) b1[n] = *(const bf16x8*)&sW[WP - 1][row][sl * 8];
        }
        // hh pass, then (if WLO) hl, then (if ALO) lh
#pragma unroll
        for (int m = 0; m < 4; ++m)
#pragma unroll
            for (int n = 0; n < NF; ++n)
                acc[m][n] = __builtin_amdgcn_mfma_f32_16x16x32_bf16(a0[m], b0[n], acc[m][n], 0, 0, 0);
        if (WLO) {
#pragma unroll
            for (int m = 0; m < 4; ++m)
#pragma unroll
                for (int n = 0; n < NF; ++n)
                    acc[m][n] = __builtin_amdgcn_mfma_f32_16x16x32_bf16(a0[m], b1[n], acc[m][n], 0, 0, 0);
        }
        if (ALO) {
#pragma unroll
            for (int m = 0; m < 4; ++m)
#pragma unroll
                for (int n = 0; n < NF; ++n)
                    acc[m][n] = __builtin_amdgcn_mfma_f32_16x16x32_bf16(a1[m], b0[n], acc[m][n], 0, 0, 0);
        }
    }

#pragma unroll
    for (int m = 0; m < 4; ++m) {
#pragma unroll
        for (int n = 0; n < NF; ++n) {
            int col = n0 + wc + n * 16 + lr;
            float bv = bias[col];
#pragma unroll
            for (int r = 0; r < 4; ++r) {
                int row = m0 + wr + m * 16 + lg * 4 + r;
                float v = acc[m][n][r] + bv;
                if (RELU)  v = (v >= 0.0f) ? v : 0.1f * v;
                if (RESID) v += resid[(size_t)row * N + col];
                if (OUTM == 0) {
                    outf[(size_t)row * N + col] = v;
                } else if (OUTM == 2) {
                    outh[(size_t)row * N + col] = (bf16_t)v;
                } else {
                    bf16_t h = (bf16_t)v;
                    outh[(size_t)row * N + col] = h;
                    if (OUTM == 1 || col < 2048)
                        outl[(size_t)row * N + col] = (bf16_t)(v - (float)h);
                }
            }
        }
    }
}

// ---------------------------------------------------------------------------
// K-split flash attention (split-softmax). Grid (NH, 16, BB), 256 thr.
// y encodes (q0 = y>>1, half = y&1). Causal: qb = (b&1) ? 7-q0 : q0 so the
// co-CU blocks (ids +-256 <=> z+-1) pair complementary qb -> every CU gets
// exactly 18 tiles; non-causal: qb = q0, uniform 8 tiles. 1024 blocks =
// 4 blocks/CU = 16 waves/CU (vs r11's 2 blocks/CU, Occ 20%) -- the
// concurrency fix. h = blockIdx.x keeps head->XCD L2 pinning (FETCH 20MB).
// Halves: causal half0 = kt [0,qb], half1 = [qb+1, 2qb+1] (qb+1 tiles each);
// non-causal half*8 .. half*8+7. Each block writes NORMALIZED partial O
// (bf16) + LSE = m + log(l) (f32); combine_kernel merges exactly. Fully
// masked rows (qb=0,half1 rows 0..63) get LSE ~ -1e30 -> weight 0.
// K(t+1) reg prefetch + single-barrier V dbuf (r9); QK^T split-precision;
// PV pure bf16-hi.
// ---------------------------------------------------------------------------
template<bool CAUSAL>
__global__ __launch_bounds__(256, 2) void attn_kernel(
    const bf16_t* __restrict__ qkvH, const bf16_t* __restrict__ qkvL,
    bf16_t* __restrict__ Opart, float* __restrict__ LSE)
{
    __shared__ bf16_t Vth[2][64][70];  // double-buffered V^T (hi), pad 70
    __shared__ bf16_t Ph[4][32][70];   // per-wave P tile (hi)

    int tid = threadIdx.x;
    int h = blockIdx.x;
    int y = blockIdx.y;
    int b = blockIdx.z;
    int half = y & 1;
    int q0 = y >> 1;
    int qb = (CAUSAL && (b & 1)) ? (7 - q0) : q0;

    int kt0, kt1;
    if (CAUSAL) { kt0 = half ? (qb + 1) : 0; kt1 = half ? (2 * qb + 1) : qb; }
    else        { kt0 = half * 8;            kt1 = kt0 + 7; }

    int l = tid & 63, w = tid >> 6;
    int lr = l & 15, lg = l >> 4;
    int qbase = qb * 128;
    const int QS = 3 * D;

    // Q frags: 32 rows per wave (2 x 16-row frags), hi/lo, both k-halves
    bf16x8 aqh[2][2], aql[2][2];
#pragma unroll
    for (int m = 0; m < 2; ++m) {
        size_t qoff = (size_t)(b * TT + qbase + w * 32 + m * 16 + lr) * QS + h * HS;
#pragma unroll
        for (int c = 0; c < 2; ++c) {
            aqh[m][c] = *(const bf16x8*)(qkvH + qoff + c * 32 + lg * 8);
            aql[m][c] = *(const bf16x8*)(qkvL + qoff + c * 32 + lg * 8);
        }
    }

    float mrow[2][4], lsum[2][4];
    f32x4 acc_o[2][4] = {};
#pragma unroll
    for (int m = 0; m < 2; ++m)
#pragma unroll
        for (int r = 0; r < 4; ++r) { mrow[m][r] = -1e30f; lsum[m][r] = 0.0f; }

    int vrow = tid >> 3;          // 0..31 (2 rows per thread, +32 apart)
    int vcol = (tid & 7) * 8;

    // prologue: V(kt0) -> LDS buf0; K(kt0) -> regs
    bf16x8 vreg[2];
#pragma unroll
    for (int rr = 0; rr < 2; ++rr)
        vreg[rr] = *(const bf16x8*)(qkvH + (size_t)(b * TT + kt0 * 64 + vrow + rr * 32) * QS + 2 * D + h * HS + vcol);
#pragma unroll
    for (int rr = 0; rr < 2; ++rr)
#pragma unroll
        for (int j = 0; j < 8; ++j) Vth[0][vcol + j][vrow + rr * 32] = vreg[rr][j];

    bf16x8 kh0[4], kl0[4], kh1[4], kl1[4];
    {
        size_t koff = (size_t)(b * TT + kt0 * 64 + lr) * QS + D + h * HS;
#pragma unroll
        for (int nt = 0; nt < 4; ++nt) {
            size_t ko = koff + (size_t)(nt * 16) * QS;
            kh0[nt] = *(const bf16x8*)(qkvH + ko + lg * 8);
            kl0[nt] = *(const bf16x8*)(qkvL + ko + lg * 8);
            kh1[nt] = *(const bf16x8*)(qkvH + ko + 32 + lg * 8);
            kl1[nt] = *(const bf16x8*)(qkvL + ko + 32 + lg * 8);
        }
    }
    __syncthreads();
    int cur = 0;

    for (int kt = kt0; kt <= kt1; ++kt) {
        int kbase = kt * 64;
        int ktn = kt < kt1 ? kt + 1 : kt1;

        // issue V(t+1) loads (hide under QK^T + softmax + PV)
#pragma unroll
        for (int rr = 0; rr < 2; ++rr)
            vreg[rr] = *(const bf16x8*)(qkvH + (size_t)(b * TT + ktn * 64 + vrow + rr * 32) * QS + 2 * D + h * HS + vcol);

        // S = Q K^T  (32 q-rows x 64 k-cols per wave), split 3-MFMA, K from regs
        f32x4 accs[2][4];
#pragma unroll
        for (int nt = 0; nt < 4; ++nt) {
            __builtin_amdgcn_s_setprio(1);
#pragma unroll
            for (int m = 0; m < 2; ++m) {
                f32x4 s = {};
                s = __builtin_amdgcn_mfma_f32_16x16x32_bf16(aqh[m][0], kh0[nt], s, 0, 0, 0);
                s = __builtin_amdgcn_mfma_f32_16x16x32_bf16(aqh[m][0], kl0[nt], s, 0, 0, 0);
                s = __builtin_amdgcn_mfma_f32_16x16x32_bf16(aql[m][0], kh0[nt], s, 0, 0, 0);
                s = __builtin_amdgcn_mfma_f32_16x16x32_bf16(aqh[m][1], kh1[nt], s, 0, 0, 0);
                s = __builtin_amdgcn_mfma_f32_16x16x32_bf16(aqh[m][1], kl1[nt], s, 0, 0, 0);
                s = __builtin_amdgcn_mfma_f32_16x16x32_bf16(aql[m][1], kh1[nt], s, 0, 0, 0);
                accs[m][nt] = s * 8.0f;   // * sqrt(head_size), faithful to reference
            }
            __builtin_amdgcn_s_setprio(0);
        }

        // prefetch K(t+1) fragments (old K regs dead; softmax+PV hide latency)
        {
            size_t koffn = (size_t)(b * TT + ktn * 64 + lr) * QS + D + h * HS;
#pragma unroll
            for (int nt = 0; nt < 4; ++nt) {
                size_t ko = koffn + (size_t)(nt * 16) * QS;
                kh0[nt] = *(const bf16x8*)(qkvH + ko + lg * 8);
                kl0[nt] = *(const bf16x8*)(qkvL + ko + lg * 8);
                kh1[nt] = *(const bf16x8*)(qkvH + ko + 32 + lg * 8);
                kl1[nt] = *(const bf16x8*)(qkvL + ko + 32 + lg * 8);
            }
        }

        if (CAUSAL && kt >= 2 * qb) {
#pragma unroll
            for (int m = 0; m < 2; ++m)
#pragma unroll
                for (int nt = 0; nt < 4; ++nt)
#pragma unroll
                    for (int r = 0; r < 4; ++r) {
                        int qrow = qbase + w * 32 + m * 16 + lg * 4 + r;
                        int kcol = kbase + nt * 16 + lr;
                        if (kcol > qrow) accs[m][nt][r] = -1e30f;
                    }
        }

        // online softmax (row-wise over the 16 lanes holding this row)
#pragma unroll
        for (int m = 0; m < 2; ++m) {
            float alpha[4];
#pragma unroll
            for (int r = 0; r < 4; ++r) {
                float mx = fmaxf(fmaxf(accs[m][0][r], accs[m][1][r]),
                                 fmaxf(accs[m][2][r], accs[m][3][r]));
#pragma unroll
                for (int msk = 1; msk < 16; msk <<= 1) mx = fmaxf(mx, __shfl_xor(mx, msk, 64));
                float mnew = fmaxf(mrow[m][r], mx);
                float sum = 0.0f;
#pragma unroll
                for (int nt = 0; nt < 4; ++nt) {
                    float p = __expf(accs[m][nt][r] - mnew);
                    accs[m][nt][r] = p;
                    sum += p;
                }
#pragma unroll
                for (int msk = 1; msk < 16; msk <<= 1) sum += __shfl_xor(sum, msk, 64);
                alpha[r] = __expf(mrow[m][r] - mnew);
                lsum[m][r] = lsum[m][r] * alpha[r] + sum;
                mrow[m][r] = mnew;
            }
#pragma unroll
            for (int et = 0; et < 4; ++et)
#pragma unroll
                for (int r = 0; r < 4; ++r) acc_o[m][et][r] *= alpha[r];

            // P -> LDS (bf16 hi only; wave-private, no barrier needed)
#pragma unroll
            for (int nt = 0; nt < 4; ++nt)
#pragma unroll
                for (int r = 0; r < 4; ++r)
                    Ph[w][m * 16 + lg * 4 + r][nt * 16 + lr] = (bf16_t)accs[m][nt][r];
        }

        // O += P @ V  (pure bf16) from current V buffer
#pragma unroll
        for (int m = 0; m < 2; ++m) {
            bf16x8 ap0 = *(const bf16x8*)&Ph[w][m * 16 + lr][lg * 8];
            bf16x8 ap1 = *(const bf16x8*)&Ph[w][m * 16 + lr][32 + lg * 8];
            __builtin_amdgcn_s_setprio(1);
#pragma unroll
            for (int et = 0; et < 4; ++et) {
                bf16x8 bv0 = *(const bf16x8*)&Vth[cur][et * 16 + lr][lg * 8];
                bf16x8 bv1 = *(const bf16x8*)&Vth[cur][et * 16 + lr][32 + lg * 8];
                acc_o[m][et] = __builtin_amdgcn_mfma_f32_16x16x32_bf16(ap0, bv0, acc_o[m][et], 0, 0, 0);
                acc_o[m][et] = __builtin_amdgcn_mfma_f32_16x16x32_bf16(ap1, bv1, acc_o[m][et], 0, 0, 0);
            }
            __builtin_amdgcn_s_setprio(0);
        }

        // stage V(t+1) into the other buffer, then the single barrier
#pragma unroll
        for (int rr = 0; rr < 2; ++rr)
#pragma unroll
            for (int j = 0; j < 8; ++j) Vth[cur ^ 1][vcol + j][vrow + rr * 32] = vreg[rr][j];
        __syncthreads();
        cur ^= 1;
    }

    // epilogue: write normalized partial O (bf16) + LSE (f32)
    size_t slice = ((((size_t)b * NH + h) * 8 + qb) * 2 + half);
#pragma unroll
    for (int m = 0; m < 2; ++m) {
#pragma unroll
        for (int r = 0; r < 4; ++r) {
            int rowl = w * 32 + m * 16 + lg * 4 + r;
            float inv = 1.0f / lsum[m][r];
#pragma unroll
            for (int et = 0; et < 4; ++et)
                Opart[(slice * 128 + rowl) * 64 + et * 16 + lr] = (bf16_t)(acc_o[m][et][r] * inv);
            if (lr == 0)
                LSE[slice * 128 + rowl] = mrow[m][r] + __logf(lsum[m][r]);
        }
    }
}

// ---------------------------------------------------------------------------
// Combine: merge the two k-split halves exactly.
// out[b*TT+qb*128+r][h*64+e] = (w0*O0 + w1*O1), w_i = e^{LSE_i - max}/sum.
// flat thread -> (e8, r, qb, h, b); 8 bf16 per thread. 2048 blocks x 256.
// ---------------------------------------------------------------------------
__global__ __launch_bounds__(256) void combine_kernel(const bf16_t* __restrict__ Op,
                                                      const float* __restrict__ LSE,
                                                      bf16_t* __restrict__ ao)
{
    int flat = blockIdx.x * 256 + threadIdx.x;
    int e8 = flat & 7;
    int tmp = flat >> 3;
    int r = tmp & 127;
    int qb = (tmp >> 7) & 7;
    int h = (tmp >> 10) & 15;
    int b = tmp >> 14;
    size_t s0 = ((((size_t)b * NH + h) * 8 + qb) * 2) * 128 + r;
    size_t s1 = s0 + 128;
    float l0 = LSE[s0], l1 = LSE[s1];
    float M = fmaxf(l0, l1);
    float w0 = __expf(l0 - M), w1 = __expf(l1 - M);
    float inv = 1.0f / (w0 + w1);
    w0 *= inv; w1 *= inv;
    bf16x8 o0 = *(const bf16x8*)(Op + s0 * 64 + e8 * 8);
    bf16x8 o1 = *(const bf16x8*)(Op + s1 * 64 + e8 * 8);
    bf16x8 o;
#pragma unroll
    for (int j = 0; j < 8; ++j)
        o[j] = (bf16_t)(w0 * (float)o0[j] + w1 * (float)o1[j]);
    *(bf16x8*)(ao + (size_t)(b * TT + qb * 128 + r) * D + h * 64 + e8 * 8) = o;
}

// ---------------------------------------------------------------------------
extern "C" void kernel_launch(void* const* d_in, const int* in_sizes, int n_in,
                              void* d_out, int out_size, void* d_ws, size_t ws_size,
                              hipStream_t stream)
{
    const float* x     = (const float*)d_in[0];
    const float* Wq    = (const float*)d_in[1];
    const float* bq    = (const float*)d_in[2];
    const float* Wk    = (const float*)d_in[3];
    const float* bk    = (const float*)d_in[4];
    const float* Wv    = (const float*)d_in[5];
    const float* bv    = (const float*)d_in[6];
    const float* Wp    = (const float*)d_in[7];
    const float* bp    = (const float*)d_in[8];
    const float* gamma = (const float*)d_in[9];
    const float* W1    = (const float*)d_in[10];
    const float* b1    = (const float*)d_in[11];
    const float* W2    = (const float*)d_in[12];
    const float* b2    = (const float*)d_in[13];
    float* out = (float*)d_out;

    // workspace layout (96 MB):
    //  0..8   : nrm hi; ao hi (aliased, nrm dead once QKV GEMM done)
    //  8..16  : nrm lo; LSE (0.5 MB, aliased; nrm-lo dead once QKV GEMM done)
    // 16..64  : qkv hi (24) + qkv lo (24); h1 bf16-hi (32) aliases 16..48
    // 48..64  : W1 conv slot (16 MB, ffn phase; aliases qkv lo tail)
    // 64..80  : bias3072 / attn Opart (16 MB) / W2 conv slot -- all
    //           stream-ordered: bias3 read by QKV GEMM before attn writes
    //           Opart; Opart consumed by combine before FFN uses W2 slot.
    // 80..96  : persistent attn weights: wqkv hi 6, wqkv lo 6, wp hi 2, lo 2
    char* base = (char*)d_ws;
    bf16_t* nrmH  = (bf16_t*)(base);
    bf16_t* nrmL  = (bf16_t*)(base + (8u  << 20));
    bf16_t* qkvH  = (bf16_t*)(base + (16u << 20));
    bf16_t* qkvL  = (bf16_t*)(base + (40u << 20));
    bf16_t* h1H   = (bf16_t*)(base + (16u << 20));   // 32 MB, hi only
    bf16_t* w1sl  = (bf16_t*)(base + (48u << 20));   // 16 MB (hi+lo)
    float*  bias3 = (float*)(base + (64u << 20));
    bf16_t* opart = (bf16_t*)(base + (64u << 20));   // 16 MB partial O
    bf16_t* w2sl  = (bf16_t*)(base + (64u << 20));   // 8 MB (hi only)
    float*  lse   = (float*)(base + (8u << 20));     // 0.5 MB (nrmL slot)
    bf16_t* wsl   = (bf16_t*)(base + (80u << 20));   // 16 MB persistent
    bf16_t* aoH = nrmH;
    float* abuf = out;   // 'a' lives in d_out, dead before final write
    float* bbuf = out;   // 'b' overwrites 'a' in d_out (a unused after rmsnorm)

    // persistent attn weights: wqkv hi [3072][1024], wqkv lo, wp hi, wp lo
    size_t DD = (size_t)D * D;
    bf16_t* wqkvH = wsl;
    bf16_t* wqkvL = wsl + 3 * DD;
    bf16_t* wpH   = wsl + 6 * DD;
    bf16_t* wpL   = wsl + 7 * DD;

    dim3 blk(256);
    dim3 gcvD(D / 64, D / 64);
    dim3 gcv1(D / 64, HF / 64);
    dim3 gcv2(HF / 64, D / 64);
    dim3 gQKV(3 * D / 128, MR / 128);   // 24 x 32 = 768 blocks, TN=128
    dim3 gP(D / 64, MR / 128);          // 16 x 32 = 512 blocks, TN=64
    dim3 gF(HF / 128, MR / 128);        // 32 x 32 = 1024 blocks, TN=128
    dim3 gA(NH, 16, BB);                // k-split: 1024 blocks, 4/CU
    dim3 gC(2048);                      // combine

    // ---- a = x + attn(rmsnorm(x), causal=false)
    rmsnorm_kernel<true><<<MR, blk, 0, stream>>>(x, gamma, nrmH, nrmL);
    concat_bias_kernel<<<12, blk, 0, stream>>>(bq, bk, bv, bias3);
    convw_kernel<true><<<gcvD, blk, 0, stream>>>(Wq, wqkvH,          wqkvL,          D, D);
    convw_kernel<true><<<gcvD, blk, 0, stream>>>(Wk, wqkvH + DD,     wqkvL + DD,     D, D);
    convw_kernel<true><<<gcvD, blk, 0, stream>>>(Wv, wqkvH + 2 * DD, wqkvL + 2 * DD, D, D);
    convw_kernel<true><<<gcvD, blk, 0, stream>>>(Wp, wpH,            wpL,            D, D);
    gemm_kernel<128, false, true, true, 3, false, false><<<gQKV, blk, 0, stream>>>(nrmH, nrmL, wqkvH, wqkvL, bias3, nullptr, nullptr, qkvH, qkvL, 3 * D, D);
    attn_kernel<false><<<gA, blk, 0, stream>>>(qkvH, qkvL, opart, lse);
    combine_kernel<<<gC, blk, 0, stream>>>(opart, lse, aoH);
    gemm_kernel<64, false, false, true, 0, false, true><<<gP, blk, 0, stream>>>(aoH, nullptr, wpH, wpL, bp, x, abuf, nullptr, nullptr, D, D);

    // ---- b = x + ffwd(rmsnorm(a))
    rmsnorm_kernel<false><<<MR, blk, 0, stream>>>(abuf, gamma, nrmH, nullptr);
    convw_kernel<true><<<gcv1, blk, 0, stream>>>(W1, w1sl, w1sl + (size_t)HF * D, D, HF);
    gemm_kernel<128, true, false, true, 2, true, false><<<gF, blk, 0, stream>>>(nrmH, nullptr, w1sl, w1sl + (size_t)HF * D, b1, nullptr, nullptr, h1H, nullptr, HF, D);
    convw_kernel<false><<<gcv2, blk, 0, stream>>>(W2, w2sl, nullptr, HF, D);
    gemm_kernel<64, false, false, false, 0, false, true><<<gP, blk, 0, stream>>>(h1H, nullptr, w2sl, nullptr, b2, x, bbuf, nullptr, nullptr, D, HF);

    // ---- c = b + attn(rmsnorm(b), causal=true)  (attn weights still resident)
    rmsnorm_kernel<true><<<MR, blk, 0, stream>>>(bbuf, gamma, nrmH, nrmL);
    concat_bias_kernel<<<12, blk, 0, stream>>>(bq, bk, bv, bias3);
    gemm_kernel<128, false, true, true, 3, false, false><<<gQKV, blk, 0, stream>>>(nrmH, nrmL, wqkvH, wqkvL, bias3, nullptr, nullptr, qkvH, qkvL, 3 * D, D);
    attn_kernel<true><<<gA, blk, 0, stream>>>(qkvH, qkvL, opart, lse);
    combine_kernel<<<gC, blk, 0, stream>>>(opart, lse, aoH);
    gemm_kernel<64, false, false, true, 0, false, true><<<gP, blk, 0, stream>>>(aoH, nullptr, wpH, wpL, bp, bbuf, out, nullptr, nullptr, D, D);
}

// Round 16
// 522.726 us; speedup vs baseline: 1.0796x; 1.0796x over previous
//
#include <hip/hip_runtime.h>
#include <cstdint>
#include <cstddef>

typedef __bf16 bf16_t;
typedef __attribute__((ext_vector_type(8))) __bf16 bf16x8;
typedef __attribute__((ext_vector_type(4))) __bf16 bf16x4;
typedef __attribute__((ext_vector_type(4))) float f32x4;

constexpr int D  = 1024;   // d_model
constexpr int TT = 1024;   // seq len
constexpr int BB = 4;      // batch
constexpr int NH = 16;     // heads
constexpr int HS = 64;     // head size
constexpr int MR = BB * TT; // 4096 rows
constexpr int HF = 4096;   // ffn hidden

__device__ inline void gload_lds16(const bf16_t* g, bf16_t* l)
{
    __builtin_amdgcn_global_load_lds(
        (const __attribute__((address_space(1))) void*)g,
        (__attribute__((address_space(3))) void*)l, 16, 0, 0);
}

// ---------------------------------------------------------------------------
// RMSNorm: f32 in -> bf16 hi (+ optional lo) planes. One block per row.
// ---------------------------------------------------------------------------
template<bool LO>
__global__ __launch_bounds__(256) void rmsnorm_kernel(const float* __restrict__ x,
                                                      const float* __restrict__ gamma,
                                                      bf16_t* __restrict__ oh,
                                                      bf16_t* __restrict__ ol)
{
    int row = blockIdx.x;
    int t   = threadIdx.x;
    const float* xr = x + (size_t)row * D;
    float4 xv = *(const float4*)(xr + t * 4);
    float ss = xv.x * xv.x + xv.y * xv.y + xv.z * xv.z + xv.w * xv.w;
#pragma unroll
    for (int m = 1; m < 64; m <<= 1) ss += __shfl_xor(ss, m, 64);
    __shared__ float part[4];
    if ((t & 63) == 0) part[t >> 6] = ss;
    __syncthreads();
    float tot   = part[0] + part[1] + part[2] + part[3];
    float scale = rsqrtf(tot * (1.0f / D) + 1e-6f);
    float4 gv = *(const float4*)(gamma + t * 4);
    float vals[4] = {xv.x * scale * gv.x, xv.y * scale * gv.y,
                     xv.z * scale * gv.z, xv.w * scale * gv.w};
    bf16x4 vh, vl;
#pragma unroll
    for (int j = 0; j < 4; ++j) {
        bf16_t h = (bf16_t)vals[j];
        vh[j] = h;
        vl[j] = (bf16_t)(vals[j] - (float)h);
    }
    *(bf16x4*)(oh + (size_t)row * D + t * 4) = vh;
    if (LO) *(bf16x4*)(ol + (size_t)row * D + t * 4) = vl;
}

// ---------------------------------------------------------------------------
// concat 3x [1024] f32 biases into one [3072] buffer
// ---------------------------------------------------------------------------
__global__ __launch_bounds__(256) void concat_bias_kernel(const float* __restrict__ a,
                                                          const float* __restrict__ b,
                                                          const float* __restrict__ c,
                                                          float* __restrict__ o)
{
    int i = blockIdx.x * 256 + threadIdx.x;
    o[i] = i < 1024 ? a[i] : (i < 2048 ? b[i - 1024] : c[i - 2048]);
}

// ---------------------------------------------------------------------------
// Weight convert: W f32 [K][N] -> dH (+ optional dL) bf16 [N][K] (transposed).
// 64x64 tile via padded LDS transpose. Grid (K/64, N/64), 256 thr.
// ---------------------------------------------------------------------------
template<bool LO>
__global__ __launch_bounds__(256) void convw_kernel(const float* __restrict__ W,
                                                    bf16_t* __restrict__ dH,
                                                    bf16_t* __restrict__ dL,
                                                    int K, int N)
{
    __shared__ float sld[64][65];
    int t = threadIdx.x;
    int k0 = blockIdx.x * 64, n0 = blockIdx.y * 64;
    int kr = t >> 4, nc = (t & 15) * 4;
#pragma unroll
    for (int p = 0; p < 4; ++p) {
        int k = p * 16 + kr;
        float4 v = *(const float4*)(W + (size_t)(k0 + k) * N + n0 + nc);
        sld[k][nc] = v.x; sld[k][nc + 1] = v.y; sld[k][nc + 2] = v.z; sld[k][nc + 3] = v.w;
    }
    __syncthreads();
    int n = t >> 2, kh = (t & 3) * 16;
    bf16x8 h0, l0, h1, l1;
#pragma unroll
    for (int j = 0; j < 8; ++j) {
        float v = sld[kh + j][n];
        bf16_t h = (bf16_t)v;
        h0[j] = h; l0[j] = (bf16_t)(v - (float)h);
    }
#pragma unroll
    for (int j = 0; j < 8; ++j) {
        float v = sld[kh + 8 + j][n];
        bf16_t h = (bf16_t)v;
        h1[j] = h; l1[j] = (bf16_t)(v - (float)h);
    }
    size_t o = (size_t)(n0 + n) * K + k0 + kh;
    *(bf16x8*)(dH + o)     = h0;
    *(bf16x8*)(dH + o + 8) = h1;
    if (LO) {
        *(bf16x8*)(dL + o)     = l0;
        *(bf16x8*)(dL + o + 8) = l1;
    }
}

// ---------------------------------------------------------------------------
// Split-precision GEMM, 128xTN tile (TN = 64 or 128), BK=32, 4 waves.
// A bf16 [M][K] hi (+ lo if ALO); W bf16 [N][K] hi (+ lo if WLO).
// MFMA passes: hh, + hl (if WLO), + lh (if ALO).
// global_load_lds(16B) staging into linear LDS, XOR-swizzled source+read.
// XCD swizzle: CM=false -> A-chunk resident per XCD (stream B); CM=true ->
// B-chunk resident (stream A; W1's shape prefers it, r13 validated).
// OUTM: 0 = f32 out, 1 = bf16 hi/lo planes, 2 = bf16 hi only,
//       3 = bf16 hi always + lo only for cols < 2048 (QKV: V-lo is dead).
// ---------------------------------------------------------------------------
template<int TN, bool CM, bool ALO, bool WLO, int OUTM, bool RELU, bool RESID>
__global__ __launch_bounds__(256, 2) void gemm_kernel(
    const bf16_t* __restrict__ Ahp, const bf16_t* __restrict__ Alp,
    const bf16_t* __restrict__ Whp, const bf16_t* __restrict__ Wlp,
    const float* __restrict__ bias, const float* resid,
    float* outf, bf16_t* __restrict__ outh, bf16_t* __restrict__ outl,
    int N, int K)
{
    constexpr int NF = TN / 32;          // n-frags per wave
    constexpr int AP = ALO ? 2 : 1;      // A planes
    constexpr int WP = WLO ? 2 : 1;      // W planes
    __shared__ bf16_t sA[AP][128][32];   // [plane][m][k], linear (gload_lds dest)
    __shared__ bf16_t sW[WP][TN][32];    // [plane][n][k]

    int t = threadIdx.x;
    int l = t & 63, w = t >> 6;
    int lr = l & 15, lg = l >> 4;

    int gx  = gridDim.x;
    int gy  = gridDim.y;
    int nwg = gx * gy;
    int bid = blockIdx.y * gx + blockIdx.x;
    int xcd = bid & 7, idx = bid >> 3;
    int nb, mb;
    if (CM) {
        // B-chunk resident: XCD owns nb in [xcd*gx/8, (xcd+1)*gx/8), mb fast
        int cw = gx >> 3;
        mb = idx % gy;
        nb = xcd * cw + idx / gy;
    } else {
        // A-chunk resident: XCD owns contiguous s-range (nb fast)
        int s = xcd * (nwg >> 3) + idx;
        nb = s % gx; mb = s / gx;
    }
    int m0 = mb * 128, n0 = nb * TN;
    int wr = (w >> 1) * 64, wc = (w & 1) * (TN / 2);

    f32x4 acc[4][NF] = {};

    int srow = (l >> 2);      // 0..15 within chunk
    int sch  = l & 3;         // 16B slot within 64B row

    for (int kk = 0; kk < K; kk += 32) {
        __syncthreads();
        // A planes: 128 rows = 4 waves x 2 chunks x 16
#pragma unroll
        for (int c = 0; c < 2; ++c) {
            int rbase = w * 32 + c * 16;
            int row = rbase + srow;
            int f = (row >> 1) & 3;
            size_t goff = (size_t)row * K + kk + (size_t)((sch ^ f)) * 8;
            gload_lds16(Ahp + (size_t)m0 * K + goff, &sA[0][rbase][0]);
            if (ALO) gload_lds16(Alp + (size_t)m0 * K + goff, &sA[AP - 1][rbase][0]);
        }
        // W planes: TN rows = 4 waves x (TN/64) chunks x 16
#pragma unroll
        for (int c = 0; c < TN / 64; ++c) {
            int rbase = w * (TN / 4) + c * 16;
            int row = rbase + srow;
            int f = (row >> 1) & 3;
            size_t goff = (size_t)row * K + kk + (size_t)((sch ^ f)) * 8;
            gload_lds16(Whp + (size_t)n0 * K + goff, &sW[0][rbase][0]);
            if (WLO) gload_lds16(Wlp + (size_t)n0 * K + goff, &sW[WP - 1][rbase][0]);
        }
        __syncthreads();

        bf16x8 a0[4], a1[4], b0[NF], b1[NF];
#pragma unroll
        for (int m = 0; m < 4; ++m) {
            int row = wr + m * 16 + lr;
            int sl = lg ^ ((row >> 1) & 3);
            a0[m] = *(const bf16x8*)&sA[0][row][sl * 8];
            if (ALO) a1[m] = *(const bf16x8*)&sA[AP - 1][row][sl * 8];
        }
#pragma unroll
        for (int n = 0; n < NF; ++n) {
            int row = wc + n * 16 + lr;
            int sl = lg ^ ((row >> 1) & 3);
            b0[n] = *(const bf16x8*)&sW[0][row][sl * 8];
            if (WLO) b1[n] = *(const bf16x8*)&sW[WP - 1][row][sl * 8];
        }
        // hh pass, then (if WLO) hl, then (if ALO) lh
#pragma unroll
        for (int m = 0; m < 4; ++m)
#pragma unroll
            for (int n = 0; n < NF; ++n)
                acc[m][n] = __builtin_amdgcn_mfma_f32_16x16x32_bf16(a0[m], b0[n], acc[m][n], 0, 0, 0);
        if (WLO) {
#pragma unroll
            for (int m = 0; m < 4; ++m)
#pragma unroll
                for (int n = 0; n < NF; ++n)
                    acc[m][n] = __builtin_amdgcn_mfma_f32_16x16x32_bf16(a0[m], b1[n], acc[m][n], 0, 0, 0);
        }
        if (ALO) {
#pragma unroll
            for (int m = 0; m < 4; ++m)
#pragma unroll
                for (int n = 0; n < NF; ++n)
                    acc[m][n] = __builtin_amdgcn_mfma_f32_16x16x32_bf16(a1[m], b0[n], acc[m][n], 0, 0, 0);
        }
    }

#pragma unroll
    for (int m = 0; m < 4; ++m) {
#pragma unroll
        for (int n = 0; n < NF; ++n) {
            int col = n0 + wc + n * 16 + lr;
            float bv = bias[col];
#pragma unroll
            for (int r = 0; r < 4; ++r) {
                int row = m0 + wr + m * 16 + lg * 4 + r;
                float v = acc[m][n][r] + bv;
                if (RELU)  v = (v >= 0.0f) ? v : 0.1f * v;
                if (RESID) v += resid[(size_t)row * N + col];
                if (OUTM == 0) {
                    outf[(size_t)row * N + col] = v;
                } else if (OUTM == 2) {
                    outh[(size_t)row * N + col] = (bf16_t)v;
                } else {
                    bf16_t h = (bf16_t)v;
                    outh[(size_t)row * N + col] = h;
                    if (OUTM == 1 || col < 2048)
                        outl[(size_t)row * N + col] = (bf16_t)(v - (float)h);
                }
            }
        }
    }
}

// ---------------------------------------------------------------------------
// Flash attention from fused QKV planes (row stride 3D; q/k/v at col 0/D/2D).
// Block = 256 thr (4 waves), 128 q-rows per block (32/wave) -- r13 geometry
// (proven local optimum: r12 128-thr and r14 k-split both regressed).
// XCD locality: h from blockIdx.x -> head's K/V pinned to one XCD L2
// (FETCH 106->20 MB, r11). Causal balance: qb from blockIdx.y, co-CU blocks
// complementary (r10). K(t+1) reg prefetch + single-barrier V dbuf (r9).
// QK^T split-precision (3 MFMA/pair); PV pure bf16-hi. O stored hi-only.
// ---------------------------------------------------------------------------
template<bool CAUSAL>
__global__ __launch_bounds__(256, 2) void attn_kernel(
    const bf16_t* __restrict__ qkvH, const bf16_t* __restrict__ qkvL,
    bf16_t* __restrict__ oh)
{
    __shared__ bf16_t Vth[2][64][70];  // double-buffered V^T (hi), pad 70
    __shared__ bf16_t Ph[4][32][70];   // per-wave P tile (hi)

    int tid = threadIdx.x;
    int b = blockIdx.z;
    int qb, h;
    if (CAUSAL) {
        int y = blockIdx.y;
        qb = (blockIdx.z & 2) ? (7 - (y & 7)) : (y & 7);
        h  = (blockIdx.x << 1) | (y >> 3);
    } else {
        h  = blockIdx.x;       // grid (NH, TT/128, BB): head pinned to XCD
        qb = blockIdx.y;
    }
    int l = tid & 63, w = tid >> 6;
    int lr = l & 15, lg = l >> 4;
    int qbase = qb * 128;
    const int QS = 3 * D;

    // Q frags: 32 rows per wave (2 x 16-row frags), hi/lo, both k-halves
    bf16x8 aqh[2][2], aql[2][2];
#pragma unroll
    for (int m = 0; m < 2; ++m) {
        size_t qoff = (size_t)(b * TT + qbase + w * 32 + m * 16 + lr) * QS + h * HS;
#pragma unroll
        for (int c = 0; c < 2; ++c) {
            aqh[m][c] = *(const bf16x8*)(qkvH + qoff + c * 32 + lg * 8);
            aql[m][c] = *(const bf16x8*)(qkvL + qoff + c * 32 + lg * 8);
        }
    }

    float mrow[2][4], lsum[2][4];
    f32x4 acc_o[2][4] = {};
#pragma unroll
    for (int m = 0; m < 2; ++m)
#pragma unroll
        for (int r = 0; r < 4; ++r) { mrow[m][r] = -1e30f; lsum[m][r] = 0.0f; }

    int ktmax = CAUSAL ? (2 * qb + 1) : (TT / 64 - 1);

    int vrow = tid >> 3;          // 0..31 (2 rows per thread, +32 apart)
    int vcol = (tid & 7) * 8;

    // prologue: V(0) -> LDS buf0; K(0) -> regs
    bf16x8 vreg[2];
#pragma unroll
    for (int rr = 0; rr < 2; ++rr)
        vreg[rr] = *(const bf16x8*)(qkvH + (size_t)(b * TT + vrow + rr * 32) * QS + 2 * D + h * HS + vcol);
#pragma unroll
    for (int rr = 0; rr < 2; ++rr)
#pragma unroll
        for (int j = 0; j < 8; ++j) Vth[0][vcol + j][vrow + rr * 32] = vreg[rr][j];

    bf16x8 kh0[4], kl0[4], kh1[4], kl1[4];
    {
        size_t koff = (size_t)(b * TT + lr) * QS + D + h * HS;
#pragma unroll
        for (int nt = 0; nt < 4; ++nt) {
            size_t ko = koff + (size_t)(nt * 16) * QS;
            kh0[nt] = *(const bf16x8*)(qkvH + ko + lg * 8);
            kl0[nt] = *(const bf16x8*)(qkvL + ko + lg * 8);
            kh1[nt] = *(const bf16x8*)(qkvH + ko + 32 + lg * 8);
            kl1[nt] = *(const bf16x8*)(qkvL + ko + 32 + lg * 8);
        }
    }
    __syncthreads();
    int cur = 0;

    for (int kt = 0; kt <= ktmax; ++kt) {
        int kbase = kt * 64;
        int ktn = kt < ktmax ? kt + 1 : ktmax;

        // issue V(t+1) loads (hide under QK^T + softmax + PV)
#pragma unroll
        for (int rr = 0; rr < 2; ++rr)
            vreg[rr] = *(const bf16x8*)(qkvH + (size_t)(b * TT + ktn * 64 + vrow + rr * 32) * QS + 2 * D + h * HS + vcol);

        // S = Q K^T  (32 q-rows x 64 k-cols per wave), split 3-MFMA, K from regs
        f32x4 accs[2][4];
#pragma unroll
        for (int nt = 0; nt < 4; ++nt) {
            __builtin_amdgcn_s_setprio(1);
#pragma unroll
            for (int m = 0; m < 2; ++m) {
                f32x4 s = {};
                s = __builtin_amdgcn_mfma_f32_16x16x32_bf16(aqh[m][0], kh0[nt], s, 0, 0, 0);
                s = __builtin_amdgcn_mfma_f32_16x16x32_bf16(aqh[m][0], kl0[nt], s, 0, 0, 0);
                s = __builtin_amdgcn_mfma_f32_16x16x32_bf16(aql[m][0], kh0[nt], s, 0, 0, 0);
                s = __builtin_amdgcn_mfma_f32_16x16x32_bf16(aqh[m][1], kh1[nt], s, 0, 0, 0);
                s = __builtin_amdgcn_mfma_f32_16x16x32_bf16(aqh[m][1], kl1[nt], s, 0, 0, 0);
                s = __builtin_amdgcn_mfma_f32_16x16x32_bf16(aql[m][1], kh1[nt], s, 0, 0, 0);
                accs[m][nt] = s * 8.0f;   // * sqrt(head_size), faithful to reference
            }
            __builtin_amdgcn_s_setprio(0);
        }

        // prefetch K(t+1) fragments (old K regs dead; softmax+PV hide latency)
        {
            size_t koffn = (size_t)(b * TT + ktn * 64 + lr) * QS + D + h * HS;
#pragma unroll
            for (int nt = 0; nt < 4; ++nt) {
                size_t ko = koffn + (size_t)(nt * 16) * QS;
                kh0[nt] = *(const bf16x8*)(qkvH + ko + lg * 8);
                kl0[nt] = *(const bf16x8*)(qkvL + ko + lg * 8);
                kh1[nt] = *(const bf16x8*)(qkvH + ko + 32 + lg * 8);
                kl1[nt] = *(const bf16x8*)(qkvL + ko + 32 + lg * 8);
            }
        }

        if (CAUSAL && kt >= 2 * qb) {
#pragma unroll
            for (int m = 0; m < 2; ++m)
#pragma unroll
                for (int nt = 0; nt < 4; ++nt)
#pragma unroll
                    for (int r = 0; r < 4; ++r) {
                        int qrow = qbase + w * 32 + m * 16 + lg * 4 + r;
                        int kcol = kbase + nt * 16 + lr;
                        if (kcol > qrow) accs[m][nt][r] = -1e30f;
                    }
        }

        // online softmax (row-wise over the 16 lanes holding this row)
#pragma unroll
        for (int m = 0; m < 2; ++m) {
            float alpha[4];
#pragma unroll
            for (int r = 0; r < 4; ++r) {
                float mx = fmaxf(fmaxf(accs[m][0][r], accs[m][1][r]),
                                 fmaxf(accs[m][2][r], accs[m][3][r]));
#pragma unroll
                for (int msk = 1; msk < 16; msk <<= 1) mx = fmaxf(mx, __shfl_xor(mx, msk, 64));
                float mnew = fmaxf(mrow[m][r], mx);
                float sum = 0.0f;
#pragma unroll
                for (int nt = 0; nt < 4; ++nt) {
                    float p = __expf(accs[m][nt][r] - mnew);
                    accs[m][nt][r] = p;
                    sum += p;
                }
#pragma unroll
                for (int msk = 1; msk < 16; msk <<= 1) sum += __shfl_xor(sum, msk, 64);
                alpha[r] = __expf(mrow[m][r] - mnew);
                lsum[m][r] = lsum[m][r] * alpha[r] + sum;
                mrow[m][r] = mnew;
            }
#pragma unroll
            for (int et = 0; et < 4; ++et)
#pragma unroll
                for (int r = 0; r < 4; ++r) acc_o[m][et][r] *= alpha[r];

            // P -> LDS (bf16 hi only; wave-private, no barrier needed)
#pragma unroll
            for (int nt = 0; nt < 4; ++nt)
#pragma unroll
                for (int r = 0; r < 4; ++r)
                    Ph[w][m * 16 + lg * 4 + r][nt * 16 + lr] = (bf16_t)accs[m][nt][r];
        }

        // O += P @ V  (pure bf16) from current V buffer
#pragma unroll
        for (int m = 0; m < 2; ++m) {
            bf16x8 ap0 = *(const bf16x8*)&Ph[w][m * 16 + lr][lg * 8];
            bf16x8 ap1 = *(const bf16x8*)&Ph[w][m * 16 + lr][32 + lg * 8];
            __builtin_amdgcn_s_setprio(1);
#pragma unroll
            for (int et = 0; et < 4; ++et) {
                bf16x8 bv0 = *(const bf16x8*)&Vth[cur][et * 16 + lr][lg * 8];
                bf16x8 bv1 = *(const bf16x8*)&Vth[cur][et * 16 + lr][32 + lg * 8];
                acc_o[m][et] = __builtin_amdgcn_mfma_f32_16x16x32_bf16(ap0, bv0, acc_o[m][et], 0, 0, 0);
                acc_o[m][et] = __builtin_amdgcn_mfma_f32_16x16x32_bf16(ap1, bv1, acc_o[m][et], 0, 0, 0);
            }
            __builtin_amdgcn_s_setprio(0);
        }

        // stage V(t+1) into the other buffer, then the single barrier
#pragma unroll
        for (int rr = 0; rr < 2; ++rr)
#pragma unroll
            for (int j = 0; j < 8; ++j) Vth[cur ^ 1][vcol + j][vrow + rr * 32] = vreg[rr][j];
        __syncthreads();
        cur ^= 1;
    }

#pragma unroll
    for (int m = 0; m < 2; ++m) {
        size_t obase = (size_t)(b * TT + qbase + w * 32 + m * 16) * D + h * HS;
#pragma unroll
        for (int r = 0; r < 4; ++r) {
            float inv = 1.0f / lsum[m][r];
#pragma unroll
            for (int et = 0; et < 4; ++et) {
                float v = acc_o[m][et][r] * inv;
                size_t idx = obase + (size_t)(lg * 4 + r) * D + et * 16 + lr;
                oh[idx] = (bf16_t)v;
            }
        }
    }
}

// ---------------------------------------------------------------------------
extern "C" void kernel_launch(void* const* d_in, const int* in_sizes, int n_in,
                              void* d_out, int out_size, void* d_ws, size_t ws_size,
                              hipStream_t stream)
{
    const float* x     = (const float*)d_in[0];
    const float* Wq    = (const float*)d_in[1];
    const float* bq    = (const float*)d_in[2];
    const float* Wk    = (const float*)d_in[3];
    const float* bk    = (const float*)d_in[4];
    const float* Wv    = (const float*)d_in[5];
    const float* bv    = (const float*)d_in[6];
    const float* Wp    = (const float*)d_in[7];
    const float* bp    = (const float*)d_in[8];
    const float* gamma = (const float*)d_in[9];
    const float* W1    = (const float*)d_in[10];
    const float* b1    = (const float*)d_in[11];
    const float* W2    = (const float*)d_in[12];
    const float* b2    = (const float*)d_in[13];
    float* out = (float*)d_out;

    // workspace layout (96 MB):
    //  0..16  : nrm hi/lo (8 MB each); ao hi (aliased)
    // 16..64  : qkv hi (24) + qkv lo (24); h1 bf16-hi (32) aliases 16..48
    // 48..64  : W1 conv slot (8 MB used, hi only, ffn phase)
    // 64..80  : bias3072 (attn phases) / W2 conv slot (8 MB used, ffn phase)
    // 80..96  : persistent attn weights: wqkv hi 6, wqkv lo 6, wp hi 2, wp lo 2
    char* base = (char*)d_ws;
    bf16_t* nrmH  = (bf16_t*)(base);
    bf16_t* nrmL  = (bf16_t*)(base + (8u  << 20));
    bf16_t* qkvH  = (bf16_t*)(base + (16u << 20));
    bf16_t* qkvL  = (bf16_t*)(base + (40u << 20));
    bf16_t* h1H   = (bf16_t*)(base + (16u << 20));   // 32 MB, hi only
    bf16_t* w1sl  = (bf16_t*)(base + (48u << 20));   // 8 MB (hi only)
    float*  bias3 = (float*)(base + (64u << 20));
    bf16_t* w2sl  = (bf16_t*)(base + (64u << 20));   // 8 MB (hi only)
    bf16_t* wsl   = (bf16_t*)(base + (80u << 20));   // 16 MB persistent
    bf16_t* aoH = nrmH;
    float* abuf = out;   // 'a' lives in d_out, dead before final write
    float* bbuf = out;   // 'b' overwrites 'a' in d_out (a unused after rmsnorm)

    // persistent attn weights: wqkv hi [3072][1024], wqkv lo, wp hi, wp lo
    size_t DD = (size_t)D * D;
    bf16_t* wqkvH = wsl;
    bf16_t* wqkvL = wsl + 3 * DD;
    bf16_t* wpH   = wsl + 6 * DD;
    bf16_t* wpL   = wsl + 7 * DD;

    dim3 blk(256);
    dim3 gcvD(D / 64, D / 64);
    dim3 gcv1(D / 64, HF / 64);
    dim3 gcv2(HF / 64, D / 64);
    dim3 gQKV(3 * D / 128, MR / 128);   // 24 x 32 = 768 blocks, TN=128
    dim3 gP(D / 64, MR / 128);          // 16 x 32 = 512 blocks, TN=64
    dim3 gF(HF / 128, MR / 128);        // 32 x 32 = 1024 blocks, TN=128
    dim3 gAnc(NH, TT / 128, BB);        // non-causal: head pinned to XCD
    dim3 gAc(TT / 128, NH, BB);         // causal: r10 balanced mapping

    // ---- a = x + attn(rmsnorm(x), causal=false)
    rmsnorm_kernel<true><<<MR, blk, 0, stream>>>(x, gamma, nrmH, nrmL);
    concat_bias_kernel<<<12, blk, 0, stream>>>(bq, bk, bv, bias3);
    convw_kernel<true><<<gcvD, blk, 0, stream>>>(Wq, wqkvH,          wqkvL,          D, D);
    convw_kernel<true><<<gcvD, blk, 0, stream>>>(Wk, wqkvH + DD,     wqkvL + DD,     D, D);
    convw_kernel<true><<<gcvD, blk, 0, stream>>>(Wv, wqkvH + 2 * DD, wqkvL + 2 * DD, D, D);
    convw_kernel<true><<<gcvD, blk, 0, stream>>>(Wp, wpH,            wpL,            D, D);
    gemm_kernel<128, false, true, true, 3, false, false><<<gQKV, blk, 0, stream>>>(nrmH, nrmL, wqkvH, wqkvL, bias3, nullptr, nullptr, qkvH, qkvL, 3 * D, D);
    attn_kernel<false><<<gAnc, blk, 0, stream>>>(qkvH, qkvL, aoH);
    gemm_kernel<64, false, false, true, 0, false, true><<<gP, blk, 0, stream>>>(aoH, nullptr, wpH, wpL, bp, x, abuf, nullptr, nullptr, D, D);

    // ---- b = x + ffwd(rmsnorm(a))
    rmsnorm_kernel<false><<<MR, blk, 0, stream>>>(abuf, gamma, nrmH, nullptr);
    convw_kernel<false><<<gcv1, blk, 0, stream>>>(W1, w1sl, nullptr, D, HF);
    gemm_kernel<128, true, false, false, 2, true, false><<<gF, blk, 0, stream>>>(nrmH, nullptr, w1sl, nullptr, b1, nullptr, nullptr, h1H, nullptr, HF, D);
    convw_kernel<false><<<gcv2, blk, 0, stream>>>(W2, w2sl, nullptr, HF, D);
    gemm_kernel<64, false, false, false, 0, false, true><<<gP, blk, 0, stream>>>(h1H, nullptr, w2sl, nullptr, b2, x, bbuf, nullptr, nullptr, D, HF);

    // ---- c = b + attn(rmsnorm(b), causal=true)  (attn weights still resident)
    rmsnorm_kernel<true><<<MR, blk, 0, stream>>>(bbuf, gamma, nrmH, nrmL);
    concat_bias_kernel<<<12, blk, 0, stream>>>(bq, bk, bv, bias3);
    gemm_kernel<128, false, true, true, 3, false, false><<<gQKV, blk, 0, stream>>>(nrmH, nrmL, wqkvH, wqkvL, bias3, nullptr, nullptr, qkvH, qkvL, 3 * D, D);
    attn_kernel<true><<<gAc, blk, 0, stream>>>(qkvH, qkvL, aoH);
    gemm_kernel<64, false, false, true, 0, false, true><<<gP, blk, 0, stream>>>(aoH, nullptr, wpH, wpL, bp, bbuf, out, nullptr, nullptr, D, D);
}

// Round 17
// 500.955 us; speedup vs baseline: 1.1265x; 1.0435x over previous
//
#include <hip/hip_runtime.h>
#include <cstdint>
#include <cstddef>

typedef __bf16 bf16_t;
typedef __attribute__((ext_vector_type(8))) __bf16 bf16x8;
typedef __attribute__((ext_vector_type(4))) __bf16 bf16x4;
typedef __attribute__((ext_vector_type(4))) float f32x4;

constexpr int D  = 1024;   // d_model
constexpr int TT = 1024;   // seq len
constexpr int BB = 4;      // batch
constexpr int NH = 16;     // heads
constexpr int HS = 64;     // head size
constexpr int MR = BB * TT; // 4096 rows
constexpr int HF = 4096;   // ffn hidden

__device__ inline void gload_lds16(const bf16_t* g, bf16_t* l)
{
    __builtin_amdgcn_global_load_lds(
        (const __attribute__((address_space(1))) void*)g,
        (__attribute__((address_space(3))) void*)l, 16, 0, 0);
}

// ---------------------------------------------------------------------------
// RMSNorm: f32 in -> bf16 hi (+ optional lo) planes. One block per row.
// ---------------------------------------------------------------------------
template<bool LO>
__global__ __launch_bounds__(256) void rmsnorm_kernel(const float* __restrict__ x,
                                                      const float* __restrict__ gamma,
                                                      bf16_t* __restrict__ oh,
                                                      bf16_t* __restrict__ ol)
{
    int row = blockIdx.x;
    int t   = threadIdx.x;
    const float* xr = x + (size_t)row * D;
    float4 xv = *(const float4*)(xr + t * 4);
    float ss = xv.x * xv.x + xv.y * xv.y + xv.z * xv.z + xv.w * xv.w;
#pragma unroll
    for (int m = 1; m < 64; m <<= 1) ss += __shfl_xor(ss, m, 64);
    __shared__ float part[4];
    if ((t & 63) == 0) part[t >> 6] = ss;
    __syncthreads();
    float tot   = part[0] + part[1] + part[2] + part[3];
    float scale = rsqrtf(tot * (1.0f / D) + 1e-6f);
    float4 gv = *(const float4*)(gamma + t * 4);
    float vals[4] = {xv.x * scale * gv.x, xv.y * scale * gv.y,
                     xv.z * scale * gv.z, xv.w * scale * gv.w};
    bf16x4 vh, vl;
#pragma unroll
    for (int j = 0; j < 4; ++j) {
        bf16_t h = (bf16_t)vals[j];
        vh[j] = h;
        vl[j] = (bf16_t)(vals[j] - (float)h);
    }
    *(bf16x4*)(oh + (size_t)row * D + t * 4) = vh;
    if (LO) *(bf16x4*)(ol + (size_t)row * D + t * 4) = vl;
}

// ---------------------------------------------------------------------------
// concat 2x [1024] f32 biases into one [2048] buffer (bq|bk)
// ---------------------------------------------------------------------------
__global__ __launch_bounds__(256) void concat_bias_kernel(const float* __restrict__ a,
                                                          const float* __restrict__ b,
                                                          float* __restrict__ o)
{
    int i = blockIdx.x * 256 + threadIdx.x;
    o[i] = i < 1024 ? a[i] : b[i - 1024];
}

// ---------------------------------------------------------------------------
// Weight convert: W f32 [K][N] -> dH (+ optional dL) bf16 [N][K] (transposed).
// 64x64 tile via padded LDS transpose. Grid (K/64, N/64), 256 thr.
// ---------------------------------------------------------------------------
template<bool LO>
__global__ __launch_bounds__(256) void convw_kernel(const float* __restrict__ W,
                                                    bf16_t* __restrict__ dH,
                                                    bf16_t* __restrict__ dL,
                                                    int K, int N)
{
    __shared__ float sld[64][65];
    int t = threadIdx.x;
    int k0 = blockIdx.x * 64, n0 = blockIdx.y * 64;
    int kr = t >> 4, nc = (t & 15) * 4;
#pragma unroll
    for (int p = 0; p < 4; ++p) {
        int k = p * 16 + kr;
        float4 v = *(const float4*)(W + (size_t)(k0 + k) * N + n0 + nc);
        sld[k][nc] = v.x; sld[k][nc + 1] = v.y; sld[k][nc + 2] = v.z; sld[k][nc + 3] = v.w;
    }
    __syncthreads();
    int n = t >> 2, kh = (t & 3) * 16;
    bf16x8 h0, l0, h1, l1;
#pragma unroll
    for (int j = 0; j < 8; ++j) {
        float v = sld[kh + j][n];
        bf16_t h = (bf16_t)v;
        h0[j] = h; l0[j] = (bf16_t)(v - (float)h);
    }
#pragma unroll
    for (int j = 0; j < 8; ++j) {
        float v = sld[kh + 8 + j][n];
        bf16_t h = (bf16_t)v;
        h1[j] = h; l1[j] = (bf16_t)(v - (float)h);
    }
    size_t o = (size_t)(n0 + n) * K + k0 + kh;
    *(bf16x8*)(dH + o)     = h0;
    *(bf16x8*)(dH + o + 8) = h1;
    if (LO) {
        *(bf16x8*)(dL + o)     = l0;
        *(bf16x8*)(dL + o + 8) = l1;
    }
}

// ---------------------------------------------------------------------------
// Split-precision GEMM, 128xTN tile (TN = 64 or 128), BK=32, 4 waves.
// A bf16 [M][K] hi (+ lo if ALO); W bf16 [N][K] hi (+ lo if WLO).
// MFMA passes: hh, + hl (if WLO), + lh (if ALO).
// XCD swizzle: CM=false -> A-chunk resident; CM=true -> B-chunk resident.
// OUTM: 0 = f32 out, 1 = bf16 hi/lo planes, 2 = bf16 hi only.
// ---------------------------------------------------------------------------
template<int TN, bool CM, bool ALO, bool WLO, int OUTM, bool RELU, bool RESID>
__global__ __launch_bounds__(256, 2) void gemm_kernel(
    const bf16_t* __restrict__ Ahp, const bf16_t* __restrict__ Alp,
    const bf16_t* __restrict__ Whp, const bf16_t* __restrict__ Wlp,
    const float* __restrict__ bias, const float* resid,
    float* outf, bf16_t* __restrict__ outh, bf16_t* __restrict__ outl,
    int N, int K)
{
    constexpr int NF = TN / 32;          // n-frags per wave
    constexpr int AP = ALO ? 2 : 1;      // A planes
    constexpr int WP = WLO ? 2 : 1;      // W planes
    __shared__ bf16_t sA[AP][128][32];   // [plane][m][k], linear (gload_lds dest)
    __shared__ bf16_t sW[WP][TN][32];    // [plane][n][k]

    int t = threadIdx.x;
    int l = t & 63, w = t >> 6;
    int lr = l & 15, lg = l >> 4;

    int gx  = gridDim.x;
    int gy  = gridDim.y;
    int nwg = gx * gy;
    int bid = blockIdx.y * gx + blockIdx.x;
    int xcd = bid & 7, idx = bid >> 3;
    int nb, mb;
    if (CM) {
        int cw = gx >> 3;
        mb = idx % gy;
        nb = xcd * cw + idx / gy;
    } else {
        int s = xcd * (nwg >> 3) + idx;
        nb = s % gx; mb = s / gx;
    }
    int m0 = mb * 128, n0 = nb * TN;
    int wr = (w >> 1) * 64, wc = (w & 1) * (TN / 2);

    f32x4 acc[4][NF] = {};

    int srow = (l >> 2);      // 0..15 within chunk
    int sch  = l & 3;         // 16B slot within 64B row

    for (int kk = 0; kk < K; kk += 32) {
        __syncthreads();
        // A planes: 128 rows = 4 waves x 2 chunks x 16
#pragma unroll
        for (int c = 0; c < 2; ++c) {
            int rbase = w * 32 + c * 16;
            int row = rbase + srow;
            int f = (row >> 1) & 3;
            size_t goff = (size_t)row * K + kk + (size_t)((sch ^ f)) * 8;
            gload_lds16(Ahp + (size_t)m0 * K + goff, &sA[0][rbase][0]);
            if (ALO) gload_lds16(Alp + (size_t)m0 * K + goff, &sA[AP - 1][rbase][0]);
        }
        // W planes: TN rows = 4 waves x (TN/64) chunks x 16
#pragma unroll
        for (int c = 0; c < TN / 64; ++c) {
            int rbase = w * (TN / 4) + c * 16;
            int row = rbase + srow;
            int f = (row >> 1) & 3;
            size_t goff = (size_t)row * K + kk + (size_t)((sch ^ f)) * 8;
            gload_lds16(Whp + (size_t)n0 * K + goff, &sW[0][rbase][0]);
            if (WLO) gload_lds16(Wlp + (size_t)n0 * K + goff, &sW[WP - 1][rbase][0]);
        }
        __syncthreads();

        bf16x8 a0[4], a1[4], b0[NF], b1[NF];
#pragma unroll
        for (int m = 0; m < 4; ++m) {
            int row = wr + m * 16 + lr;
            int sl = lg ^ ((row >> 1) & 3);
            a0[m] = *(const bf16x8*)&sA[0][row][sl * 8];
            if (ALO) a1[m] = *(const bf16x8*)&sA[AP - 1][row][sl * 8];
        }
#pragma unroll
        for (int n = 0; n < NF; ++n) {
            int row = wc + n * 16 + lr;
            int sl = lg ^ ((row >> 1) & 3);
            b0[n] = *(const bf16x8*)&sW[0][row][sl * 8];
            if (WLO) b1[n] = *(const bf16x8*)&sW[WP - 1][row][sl * 8];
        }
        // hh pass, then (if WLO) hl, then (if ALO) lh
#pragma unroll
        for (int m = 0; m < 4; ++m)
#pragma unroll
            for (int n = 0; n < NF; ++n)
                acc[m][n] = __builtin_amdgcn_mfma_f32_16x16x32_bf16(a0[m], b0[n], acc[m][n], 0, 0, 0);
        if (WLO) {
#pragma unroll
            for (int m = 0; m < 4; ++m)
#pragma unroll
                for (int n = 0; n < NF; ++n)
                    acc[m][n] = __builtin_amdgcn_mfma_f32_16x16x32_bf16(a0[m], b1[n], acc[m][n], 0, 0, 0);
        }
        if (ALO) {
#pragma unroll
            for (int m = 0; m < 4; ++m)
#pragma unroll
                for (int n = 0; n < NF; ++n)
                    acc[m][n] = __builtin_amdgcn_mfma_f32_16x16x32_bf16(a1[m], b0[n], acc[m][n], 0, 0, 0);
        }
    }

#pragma unroll
    for (int m = 0; m < 4; ++m) {
#pragma unroll
        for (int n = 0; n < NF; ++n) {
            int col = n0 + wc + n * 16 + lr;
            float bv = bias[col];
#pragma unroll
            for (int r = 0; r < 4; ++r) {
                int row = m0 + wr + m * 16 + lg * 4 + r;
                float v = acc[m][n][r] + bv;
                if (RELU)  v = (v >= 0.0f) ? v : 0.1f * v;
                if (RESID) v += resid[(size_t)row * N + col];
                if (OUTM == 0) {
                    outf[(size_t)row * N + col] = v;
                } else if (OUTM == 2) {
                    outh[(size_t)row * N + col] = (bf16_t)v;
                } else {
                    bf16_t h = (bf16_t)v;
                    outh[(size_t)row * N + col] = h;
                    outl[(size_t)row * N + col] = (bf16_t)(v - (float)h);
                }
            }
        }
    }
}

// ---------------------------------------------------------------------------
// Flash attention. Q/K from qk planes (row stride 2D; q at col 0, k at D);
// V from v plane (row stride D, bf16-hi). r13 geometry (proven optimum).
// XCD locality: h from blockIdx.x -> head's K/V pinned to one XCD L2.
// Causal balance: qb from blockIdx.y, co-CU blocks complementary (r10).
// K(t+1) reg prefetch + single-barrier V dbuf (r9). QK^T split (3 MFMA/
// pair); PV pure bf16-hi. O stored hi-only.
// ---------------------------------------------------------------------------
template<bool CAUSAL>
__global__ __launch_bounds__(256, 2) void attn_kernel(
    const bf16_t* __restrict__ qkH, const bf16_t* __restrict__ qkL,
    const bf16_t* __restrict__ vP, bf16_t* __restrict__ oh)
{
    __shared__ bf16_t Vth[2][64][70];  // double-buffered V^T (hi), pad 70
    __shared__ bf16_t Ph[4][32][70];   // per-wave P tile (hi)

    int tid = threadIdx.x;
    int b = blockIdx.z;
    int qb, h;
    if (CAUSAL) {
        int y = blockIdx.y;
        qb = (blockIdx.z & 2) ? (7 - (y & 7)) : (y & 7);
        h  = (blockIdx.x << 1) | (y >> 3);
    } else {
        h  = blockIdx.x;       // grid (NH, TT/128, BB): head pinned to XCD
        qb = blockIdx.y;
    }
    int l = tid & 63, w = tid >> 6;
    int lr = l & 15, lg = l >> 4;
    int qbase = qb * 128;
    const int QKS = 2 * D;

    // Q frags: 32 rows per wave (2 x 16-row frags), hi/lo, both k-halves
    bf16x8 aqh[2][2], aql[2][2];
#pragma unroll
    for (int m = 0; m < 2; ++m) {
        size_t qoff = (size_t)(b * TT + qbase + w * 32 + m * 16 + lr) * QKS + h * HS;
#pragma unroll
        for (int c = 0; c < 2; ++c) {
            aqh[m][c] = *(const bf16x8*)(qkH + qoff + c * 32 + lg * 8);
            aql[m][c] = *(const bf16x8*)(qkL + qoff + c * 32 + lg * 8);
        }
    }

    float mrow[2][4], lsum[2][4];
    f32x4 acc_o[2][4] = {};
#pragma unroll
    for (int m = 0; m < 2; ++m)
#pragma unroll
        for (int r = 0; r < 4; ++r) { mrow[m][r] = -1e30f; lsum[m][r] = 0.0f; }

    int ktmax = CAUSAL ? (2 * qb + 1) : (TT / 64 - 1);

    int vrow = tid >> 3;          // 0..31 (2 rows per thread, +32 apart)
    int vcol = (tid & 7) * 8;

    // prologue: V(0) -> LDS buf0; K(0) -> regs
    bf16x8 vreg[2];
#pragma unroll
    for (int rr = 0; rr < 2; ++rr)
        vreg[rr] = *(const bf16x8*)(vP + (size_t)(b * TT + vrow + rr * 32) * D + h * HS + vcol);
#pragma unroll
    for (int rr = 0; rr < 2; ++rr)
#pragma unroll
        for (int j = 0; j < 8; ++j) Vth[0][vcol + j][vrow + rr * 32] = vreg[rr][j];

    bf16x8 kh0[4], kl0[4], kh1[4], kl1[4];
    {
        size_t koff = (size_t)(b * TT + lr) * QKS + D + h * HS;
#pragma unroll
        for (int nt = 0; nt < 4; ++nt) {
            size_t ko = koff + (size_t)(nt * 16) * QKS;
            kh0[nt] = *(const bf16x8*)(qkH + ko + lg * 8);
            kl0[nt] = *(const bf16x8*)(qkL + ko + lg * 8);
            kh1[nt] = *(const bf16x8*)(qkH + ko + 32 + lg * 8);
            kl1[nt] = *(const bf16x8*)(qkL + ko + 32 + lg * 8);
        }
    }
    __syncthreads();
    int cur = 0;

    for (int kt = 0; kt <= ktmax; ++kt) {
        int kbase = kt * 64;
        int ktn = kt < ktmax ? kt + 1 : ktmax;

        // issue V(t+1) loads (hide under QK^T + softmax + PV)
#pragma unroll
        for (int rr = 0; rr < 2; ++rr)
            vreg[rr] = *(const bf16x8*)(vP + (size_t)(b * TT + ktn * 64 + vrow + rr * 32) * D + h * HS + vcol);

        // S = Q K^T  (32 q-rows x 64 k-cols per wave), split 3-MFMA, K from regs
        f32x4 accs[2][4];
#pragma unroll
        for (int nt = 0; nt < 4; ++nt) {
            __builtin_amdgcn_s_setprio(1);
#pragma unroll
            for (int m = 0; m < 2; ++m) {
                f32x4 s = {};
                s = __builtin_amdgcn_mfma_f32_16x16x32_bf16(aqh[m][0], kh0[nt], s, 0, 0, 0);
                s = __builtin_amdgcn_mfma_f32_16x16x32_bf16(aqh[m][0], kl0[nt], s, 0, 0, 0);
                s = __builtin_amdgcn_mfma_f32_16x16x32_bf16(aql[m][0], kh0[nt], s, 0, 0, 0);
                s = __builtin_amdgcn_mfma_f32_16x16x32_bf16(aqh[m][1], kh1[nt], s, 0, 0, 0);
                s = __builtin_amdgcn_mfma_f32_16x16x32_bf16(aqh[m][1], kl1[nt], s, 0, 0, 0);
                s = __builtin_amdgcn_mfma_f32_16x16x32_bf16(aql[m][1], kh1[nt], s, 0, 0, 0);
                accs[m][nt] = s * 8.0f;   // * sqrt(head_size), faithful to reference
            }
            __builtin_amdgcn_s_setprio(0);
        }

        // prefetch K(t+1) fragments (old K regs dead; softmax+PV hide latency)
        {
            size_t koffn = (size_t)(b * TT + ktn * 64 + lr) * QKS + D + h * HS;
#pragma unroll
            for (int nt = 0; nt < 4; ++nt) {
                size_t ko = koffn + (size_t)(nt * 16) * QKS;
                kh0[nt] = *(const bf16x8*)(qkH + ko + lg * 8);
                kl0[nt] = *(const bf16x8*)(qkL + ko + lg * 8);
                kh1[nt] = *(const bf16x8*)(qkH + ko + 32 + lg * 8);
                kl1[nt] = *(const bf16x8*)(qkL + ko + 32 + lg * 8);
            }
        }

        if (CAUSAL && kt >= 2 * qb) {
#pragma unroll
            for (int m = 0; m < 2; ++m)
#pragma unroll
                for (int nt = 0; nt < 4; ++nt)
#pragma unroll
                    for (int r = 0; r < 4; ++r) {
                        int qrow = qbase + w * 32 + m * 16 + lg * 4 + r;
                        int kcol = kbase + nt * 16 + lr;
                        if (kcol > qrow) accs[m][nt][r] = -1e30f;
                    }
        }

        // online softmax (row-wise over the 16 lanes holding this row)
#pragma unroll
        for (int m = 0; m < 2; ++m) {
            float alpha[4];
#pragma unroll
            for (int r = 0; r < 4; ++r) {
                float mx = fmaxf(fmaxf(accs[m][0][r], accs[m][1][r]),
                                 fmaxf(accs[m][2][r], accs[m][3][r]));
#pragma unroll
                for (int msk = 1; msk < 16; msk <<= 1) mx = fmaxf(mx, __shfl_xor(mx, msk, 64));
                float mnew = fmaxf(mrow[m][r], mx);
                float sum = 0.0f;
#pragma unroll
                for (int nt = 0; nt < 4; ++nt) {
                    float p = __expf(accs[m][nt][r] - mnew);
                    accs[m][nt][r] = p;
                    sum += p;
                }
#pragma unroll
                for (int msk = 1; msk < 16; msk <<= 1) sum += __shfl_xor(sum, msk, 64);
                alpha[r] = __expf(mrow[m][r] - mnew);
                lsum[m][r] = lsum[m][r] * alpha[r] + sum;
                mrow[m][r] = mnew;
            }
#pragma unroll
            for (int et = 0; et < 4; ++et)
#pragma unroll
                for (int r = 0; r < 4; ++r) acc_o[m][et][r] *= alpha[r];

            // P -> LDS (bf16 hi only; wave-private, no barrier needed)
#pragma unroll
            for (int nt = 0; nt < 4; ++nt)
#pragma unroll
                for (int r = 0; r < 4; ++r)
                    Ph[w][m * 16 + lg * 4 + r][nt * 16 + lr] = (bf16_t)accs[m][nt][r];
        }

        // O += P @ V  (pure bf16) from current V buffer
#pragma unroll
        for (int m = 0; m < 2; ++m) {
            bf16x8 ap0 = *(const bf16x8*)&Ph[w][m * 16 + lr][lg * 8];
            bf16x8 ap1 = *(const bf16x8*)&Ph[w][m * 16 + lr][32 + lg * 8];
            __builtin_amdgcn_s_setprio(1);
#pragma unroll
            for (int et = 0; et < 4; ++et) {
                bf16x8 bv0 = *(const bf16x8*)&Vth[cur][et * 16 + lr][lg * 8];
                bf16x8 bv1 = *(const bf16x8*)&Vth[cur][et * 16 + lr][32 + lg * 8];
                acc_o[m][et] = __builtin_amdgcn_mfma_f32_16x16x32_bf16(ap0, bv0, acc_o[m][et], 0, 0, 0);
                acc_o[m][et] = __builtin_amdgcn_mfma_f32_16x16x32_bf16(ap1, bv1, acc_o[m][et], 0, 0, 0);
            }
            __builtin_amdgcn_s_setprio(0);
        }

        // stage V(t+1) into the other buffer, then the single barrier
#pragma unroll
        for (int rr = 0; rr < 2; ++rr)
#pragma unroll
            for (int j = 0; j < 8; ++j) Vth[cur ^ 1][vcol + j][vrow + rr * 32] = vreg[rr][j];
        __syncthreads();
        cur ^= 1;
    }

#pragma unroll
    for (int m = 0; m < 2; ++m) {
        size_t obase = (size_t)(b * TT + qbase + w * 32 + m * 16) * D + h * HS;
#pragma unroll
        for (int r = 0; r < 4; ++r) {
            float inv = 1.0f / lsum[m][r];
#pragma unroll
            for (int et = 0; et < 4; ++et) {
                float v = acc_o[m][et][r] * inv;
                size_t idx = obase + (size_t)(lg * 4 + r) * D + et * 16 + lr;
                oh[idx] = (bf16_t)v;
            }
        }
    }
}

// ---------------------------------------------------------------------------
extern "C" void kernel_launch(void* const* d_in, const int* in_sizes, int n_in,
                              void* d_out, int out_size, void* d_ws, size_t ws_size,
                              hipStream_t stream)
{
    const float* x     = (const float*)d_in[0];
    const float* Wq    = (const float*)d_in[1];
    const float* bq    = (const float*)d_in[2];
    const float* Wk    = (const float*)d_in[3];
    const float* bk    = (const float*)d_in[4];
    const float* Wv    = (const float*)d_in[5];
    const float* bv    = (const float*)d_in[6];
    const float* Wp    = (const float*)d_in[7];
    const float* bp    = (const float*)d_in[8];
    const float* gamma = (const float*)d_in[9];
    const float* W1    = (const float*)d_in[10];
    const float* b1    = (const float*)d_in[11];
    const float* W2    = (const float*)d_in[12];
    const float* b2    = (const float*)d_in[13];
    float* out = (float*)d_out;

    // workspace layout (96 MB):
    //  0..16  : nrm hi/lo (8 MB each); ao hi (aliased)
    // 16..48  : qk hi (16) + qk lo (16); h1 bf16-hi (32) aliases (ffn phase)
    // 48..56  : v hi (8); W1 conv slot (8, ffn phase, v dead)
    // 64..72  : bias2048 (attn phases) / W2 conv slot (8, ffn phase)
    // 80..96  : persistent weights: wqk hi 4, wqk lo 4, wv hi 2, wp hi 2
    char* base = (char*)d_ws;
    bf16_t* nrmH  = (bf16_t*)(base);
    bf16_t* nrmL  = (bf16_t*)(base + (8u  << 20));
    bf16_t* qkH   = (bf16_t*)(base + (16u << 20));
    bf16_t* qkL   = (bf16_t*)(base + (32u << 20));
    bf16_t* vH    = (bf16_t*)(base + (48u << 20));
    bf16_t* h1H   = (bf16_t*)(base + (16u << 20));   // 32 MB, hi only
    bf16_t* w1sl  = (bf16_t*)(base + (48u << 20));   // 8 MB (hi only)
    float*  bias2 = (float*)(base + (64u << 20));
    bf16_t* w2sl  = (bf16_t*)(base + (64u << 20));   // 8 MB (hi only)
    bf16_t* wsl   = (bf16_t*)(base + (80u << 20));   // persistent
    bf16_t* aoH = nrmH;
    float* abuf = out;   // 'a' lives in d_out, dead before final write
    float* bbuf = out;   // 'b' overwrites 'a' in d_out (a unused after rmsnorm)

    // persistent weights: wqk hi [2048][1024], wqk lo, wv hi, wp hi
    size_t DD = (size_t)D * D;
    bf16_t* wqkH = wsl;
    bf16_t* wqkL = wsl + 2 * DD;
    bf16_t* wvH  = wsl + 4 * DD;
    bf16_t* wpH  = wsl + 5 * DD;

    dim3 blk(256);
    dim3 gcvD(D / 64, D / 64);
    dim3 gcv1(D / 64, HF / 64);
    dim3 gcv2(HF / 64, D / 64);
    dim3 gQK(2 * D / 128, MR / 128);    // 16 x 32 = 512 blocks, TN=128
    dim3 gP(D / 64, MR / 128);          // 16 x 32 = 512 blocks, TN=64
    dim3 gF(HF / 128, MR / 128);        // 32 x 32 = 1024 blocks, TN=128
    dim3 gAnc(NH, TT / 128, BB);        // non-causal: head pinned to XCD
    dim3 gAc(TT / 128, NH, BB);         // causal: r10 balanced mapping

    // ---- a = x + attn(rmsnorm(x), causal=false)
    rmsnorm_kernel<true><<<MR, blk, 0, stream>>>(x, gamma, nrmH, nrmL);
    concat_bias_kernel<<<8, blk, 0, stream>>>(bq, bk, bias2);
    convw_kernel<true><<<gcvD, blk, 0, stream>>>(Wq, wqkH,      wqkL,      D, D);
    convw_kernel<true><<<gcvD, blk, 0, stream>>>(Wk, wqkH + DD, wqkL + DD, D, D);
    convw_kernel<false><<<gcvD, blk, 0, stream>>>(Wv, wvH, nullptr, D, D);
    convw_kernel<false><<<gcvD, blk, 0, stream>>>(Wp, wpH, nullptr, D, D);
    gemm_kernel<128, false, true, true, 1, false, false><<<gQK, blk, 0, stream>>>(nrmH, nrmL, wqkH, wqkL, bias2, nullptr, nullptr, qkH, qkL, 2 * D, D);
    gemm_kernel<64, false, false, false, 2, false, false><<<gP, blk, 0, stream>>>(nrmH, nullptr, wvH, nullptr, bv, nullptr, nullptr, vH, nullptr, D, D);
    attn_kernel<false><<<gAnc, blk, 0, stream>>>(qkH, qkL, vH, aoH);
    gemm_kernel<64, false, false, false, 0, false, true><<<gP, blk, 0, stream>>>(aoH, nullptr, wpH, nullptr, bp, x, abuf, nullptr, nullptr, D, D);

    // ---- b = x + ffwd(rmsnorm(a))
    rmsnorm_kernel<false><<<MR, blk, 0, stream>>>(abuf, gamma, nrmH, nullptr);
    convw_kernel<false><<<gcv1, blk, 0, stream>>>(W1, w1sl, nullptr, D, HF);
    gemm_kernel<128, true, false, false, 2, true, false><<<gF, blk, 0, stream>>>(nrmH, nullptr, w1sl, nullptr, b1, nullptr, nullptr, h1H, nullptr, HF, D);
    convw_kernel<false><<<gcv2, blk, 0, stream>>>(W2, w2sl, nullptr, HF, D);
    gemm_kernel<64, false, false, false, 0, false, true><<<gP, blk, 0, stream>>>(h1H, nullptr, w2sl, nullptr, b2, x, bbuf, nullptr, nullptr, D, HF);

    // ---- c = b + attn(rmsnorm(b), causal=true)  (attn weights still resident)
    rmsnorm_kernel<true><<<MR, blk, 0, stream>>>(bbuf, gamma, nrmH, nrmL);
    concat_bias_kernel<<<8, blk, 0, stream>>>(bq, bk, bias2);
    gemm_kernel<128, false, true, true, 1, false, false><<<gQK, blk, 0, stream>>>(nrmH, nrmL, wqkH, wqkL, bias2, nullptr, nullptr, qkH, qkL, 2 * D, D);
    gemm_kernel<64, false, false, false, 2, false, false><<<gP, blk, 0, stream>>>(nrmH, nullptr, wvH, nullptr, bv, nullptr, nullptr, vH, nullptr, D, D);
    attn_kernel<true><<<gAc, blk, 0, stream>>>(qkH, qkL, vH, aoH);
    gemm_kernel<64, false, false, false, 0, false, true><<<gP, blk, 0, stream>>>(aoH, nullptr, wpH, nullptr, bp, bbuf, out, nullptr, nullptr, D, D);
}

// Round 18
// 500.112 us; speedup vs baseline: 1.1284x; 1.0017x over previous
//
#include <hip/hip_runtime.h>
#include <cstdint>
#include <cstddef>

typedef __bf16 bf16_t;
typedef __attribute__((ext_vector_type(8))) __bf16 bf16x8;
typedef __attribute__((ext_vector_type(4))) __bf16 bf16x4;
typedef __attribute__((ext_vector_type(4))) float f32x4;

constexpr int D  = 1024;   // d_model
constexpr int TT = 1024;   // seq len
constexpr int BB = 4;      // batch
constexpr int NH = 16;     // heads
constexpr int HS = 64;     // head size
constexpr int MR = BB * TT; // 4096 rows
constexpr int HF = 4096;   // ffn hidden

__device__ inline void gload_lds16(const bf16_t* g, bf16_t* l)
{
    __builtin_amdgcn_global_load_lds(
        (const __attribute__((address_space(1))) void*)g,
        (__attribute__((address_space(3))) void*)l, 16, 0, 0);
}

// ---------------------------------------------------------------------------
// RMSNorm: f32 in -> bf16 hi (+ optional lo) planes. One block per row.
// ---------------------------------------------------------------------------
template<bool LO>
__global__ __launch_bounds__(256) void rmsnorm_kernel(const float* __restrict__ x,
                                                      const float* __restrict__ gamma,
                                                      bf16_t* __restrict__ oh,
                                                      bf16_t* __restrict__ ol)
{
    int row = blockIdx.x;
    int t   = threadIdx.x;
    const float* xr = x + (size_t)row * D;
    float4 xv = *(const float4*)(xr + t * 4);
    float ss = xv.x * xv.x + xv.y * xv.y + xv.z * xv.z + xv.w * xv.w;
#pragma unroll
    for (int m = 1; m < 64; m <<= 1) ss += __shfl_xor(ss, m, 64);
    __shared__ float part[4];
    if ((t & 63) == 0) part[t >> 6] = ss;
    __syncthreads();
    float tot   = part[0] + part[1] + part[2] + part[3];
    float scale = rsqrtf(tot * (1.0f / D) + 1e-6f);
    float4 gv = *(const float4*)(gamma + t * 4);
    float vals[4] = {xv.x * scale * gv.x, xv.y * scale * gv.y,
                     xv.z * scale * gv.z, xv.w * scale * gv.w};
    bf16x4 vh, vl;
#pragma unroll
    for (int j = 0; j < 4; ++j) {
        bf16_t h = (bf16_t)vals[j];
        vh[j] = h;
        vl[j] = (bf16_t)(vals[j] - (float)h);
    }
    *(bf16x4*)(oh + (size_t)row * D + t * 4) = vh;
    if (LO) *(bf16x4*)(ol + (size_t)row * D + t * 4) = vl;
}

// ---------------------------------------------------------------------------
// concat 2x [1024] f32 biases into one [2048] buffer (bq|bk)
// ---------------------------------------------------------------------------
__global__ __launch_bounds__(256) void concat_bias_kernel(const float* __restrict__ a,
                                                          const float* __restrict__ b,
                                                          float* __restrict__ o)
{
    int i = blockIdx.x * 256 + threadIdx.x;
    o[i] = i < 1024 ? a[i] : b[i - 1024];
}

// ---------------------------------------------------------------------------
// Weight convert: W f32 [K][N] -> dH (+ optional dL) bf16 [N][K] (transposed).
// 64x64 tile via padded LDS transpose. Grid (K/64, N/64), 256 thr.
// ---------------------------------------------------------------------------
template<bool LO>
__global__ __launch_bounds__(256) void convw_kernel(const float* __restrict__ W,
                                                    bf16_t* __restrict__ dH,
                                                    bf16_t* __restrict__ dL,
                                                    int K, int N)
{
    __shared__ float sld[64][65];
    int t = threadIdx.x;
    int k0 = blockIdx.x * 64, n0 = blockIdx.y * 64;
    int kr = t >> 4, nc = (t & 15) * 4;
#pragma unroll
    for (int p = 0; p < 4; ++p) {
        int k = p * 16 + kr;
        float4 v = *(const float4*)(W + (size_t)(k0 + k) * N + n0 + nc);
        sld[k][nc] = v.x; sld[k][nc + 1] = v.y; sld[k][nc + 2] = v.z; sld[k][nc + 3] = v.w;
    }
    __syncthreads();
    int n = t >> 2, kh = (t & 3) * 16;
    bf16x8 h0, l0, h1, l1;
#pragma unroll
    for (int j = 0; j < 8; ++j) {
        float v = sld[kh + j][n];
        bf16_t h = (bf16_t)v;
        h0[j] = h; l0[j] = (bf16_t)(v - (float)h);
    }
#pragma unroll
    for (int j = 0; j < 8; ++j) {
        float v = sld[kh + 8 + j][n];
        bf16_t h = (bf16_t)v;
        h1[j] = h; l1[j] = (bf16_t)(v - (float)h);
    }
    size_t o = (size_t)(n0 + n) * K + k0 + kh;
    *(bf16x8*)(dH + o)     = h0;
    *(bf16x8*)(dH + o + 8) = h1;
    if (LO) {
        *(bf16x8*)(dL + o)     = l0;
        *(bf16x8*)(dL + o + 8) = l1;
    }
}

// ---------------------------------------------------------------------------
// Split-precision GEMM, 128xTN tile (TN = 64 or 128), BK=32, 4 waves.
// A bf16 [M][K] hi (+ lo if ALO); W bf16 [N][K] hi (+ lo if WLO).
// MFMA passes: hh, + hl (if WLO), + lh (if ALO).
// XCD swizzle: CM=false -> A-chunk resident; CM=true -> B-chunk resident.
// OUTM: 0 = f32 out, 1 = bf16 hi/lo planes, 2 = bf16 hi only.
// ---------------------------------------------------------------------------
template<int TN, bool CM, bool ALO, bool WLO, int OUTM, bool RELU, bool RESID>
__global__ __launch_bounds__(256, 2) void gemm_kernel(
    const bf16_t* __restrict__ Ahp, const bf16_t* __restrict__ Alp,
    const bf16_t* __restrict__ Whp, const bf16_t* __restrict__ Wlp,
    const float* __restrict__ bias, const float* resid,
    float* outf, bf16_t* __restrict__ outh, bf16_t* __restrict__ outl,
    int N, int K)
{
    constexpr int NF = TN / 32;          // n-frags per wave
    constexpr int AP = ALO ? 2 : 1;      // A planes
    constexpr int WP = WLO ? 2 : 1;      // W planes
    __shared__ bf16_t sA[AP][128][32];   // [plane][m][k], linear (gload_lds dest)
    __shared__ bf16_t sW[WP][TN][32];    // [plane][n][k]

    int t = threadIdx.x;
    int l = t & 63, w = t >> 6;
    int lr = l & 15, lg = l >> 4;

    int gx  = gridDim.x;
    int gy  = gridDim.y;
    int nwg = gx * gy;
    int bid = blockIdx.y * gx + blockIdx.x;
    int xcd = bid & 7, idx = bid >> 3;
    int nb, mb;
    if (CM) {
        int cw = gx >> 3;
        mb = idx % gy;
        nb = xcd * cw + idx / gy;
    } else {
        int s = xcd * (nwg >> 3) + idx;
        nb = s % gx; mb = s / gx;
    }
    int m0 = mb * 128, n0 = nb * TN;
    int wr = (w >> 1) * 64, wc = (w & 1) * (TN / 2);

    f32x4 acc[4][NF] = {};

    int srow = (l >> 2);      // 0..15 within chunk
    int sch  = l & 3;         // 16B slot within 64B row

    for (int kk = 0; kk < K; kk += 32) {
        __syncthreads();
        // A planes: 128 rows = 4 waves x 2 chunks x 16
#pragma unroll
        for (int c = 0; c < 2; ++c) {
            int rbase = w * 32 + c * 16;
            int row = rbase + srow;
            int f = (row >> 1) & 3;
            size_t goff = (size_t)row * K + kk + (size_t)((sch ^ f)) * 8;
            gload_lds16(Ahp + (size_t)m0 * K + goff, &sA[0][rbase][0]);
            if (ALO) gload_lds16(Alp + (size_t)m0 * K + goff, &sA[AP - 1][rbase][0]);
        }
        // W planes: TN rows = 4 waves x (TN/64) chunks x 16
#pragma unroll
        for (int c = 0; c < TN / 64; ++c) {
            int rbase = w * (TN / 4) + c * 16;
            int row = rbase + srow;
            int f = (row >> 1) & 3;
            size_t goff = (size_t)row * K + kk + (size_t)((sch ^ f)) * 8;
            gload_lds16(Whp + (size_t)n0 * K + goff, &sW[0][rbase][0]);
            if (WLO) gload_lds16(Wlp + (size_t)n0 * K + goff, &sW[WP - 1][rbase][0]);
        }
        __syncthreads();

        bf16x8 a0[4], a1[4], b0[NF], b1[NF];
#pragma unroll
        for (int m = 0; m < 4; ++m) {
            int row = wr + m * 16 + lr;
            int sl = lg ^ ((row >> 1) & 3);
            a0[m] = *(const bf16x8*)&sA[0][row][sl * 8];
            if (ALO) a1[m] = *(const bf16x8*)&sA[AP - 1][row][sl * 8];
        }
#pragma unroll
        for (int n = 0; n < NF; ++n) {
            int row = wc + n * 16 + lr;
            int sl = lg ^ ((row >> 1) & 3);
            b0[n] = *(const bf16x8*)&sW[0][row][sl * 8];
            if (WLO) b1[n] = *(const bf16x8*)&sW[WP - 1][row][sl * 8];
        }
        // hh pass, then (if WLO) hl, then (if ALO) lh
#pragma unroll
        for (int m = 0; m < 4; ++m)
#pragma unroll
            for (int n = 0; n < NF; ++n)
                acc[m][n] = __builtin_amdgcn_mfma_f32_16x16x32_bf16(a0[m], b0[n], acc[m][n], 0, 0, 0);
        if (WLO) {
#pragma unroll
            for (int m = 0; m < 4; ++m)
#pragma unroll
                for (int n = 0; n < NF; ++n)
                    acc[m][n] = __builtin_amdgcn_mfma_f32_16x16x32_bf16(a0[m], b1[n], acc[m][n], 0, 0, 0);
        }
        if (ALO) {
#pragma unroll
            for (int m = 0; m < 4; ++m)
#pragma unroll
                for (int n = 0; n < NF; ++n)
                    acc[m][n] = __builtin_amdgcn_mfma_f32_16x16x32_bf16(a1[m], b0[n], acc[m][n], 0, 0, 0);
        }
    }

#pragma unroll
    for (int m = 0; m < 4; ++m) {
#pragma unroll
        for (int n = 0; n < NF; ++n) {
            int col = n0 + wc + n * 16 + lr;
            float bv = bias[col];
#pragma unroll
            for (int r = 0; r < 4; ++r) {
                int row = m0 + wr + m * 16 + lg * 4 + r;
                float v = acc[m][n][r] + bv;
                if (RELU)  v = (v >= 0.0f) ? v : 0.1f * v;
                if (RESID) v += resid[(size_t)row * N + col];
                if (OUTM == 0) {
                    outf[(size_t)row * N + col] = v;
                } else if (OUTM == 2) {
                    outh[(size_t)row * N + col] = (bf16_t)v;
                } else {
                    bf16_t h = (bf16_t)v;
                    outh[(size_t)row * N + col] = h;
                    outl[(size_t)row * N + col] = (bf16_t)(v - (float)h);
                }
            }
        }
    }
}

// ---------------------------------------------------------------------------
// Flash attention. Q/K from qk planes (row stride 2D; q at col 0, k at D);
// V from v plane (row stride D, bf16-hi). r13 geometry (proven optimum).
// XCD locality: h from blockIdx.x -> head's K/V pinned to one XCD L2.
// Causal balance: qb from blockIdx.y, co-CU blocks complementary (r10).
// K(t+1) reg prefetch + single-barrier V dbuf (r9). QK^T split (3 MFMA/
// pair); PV pure bf16-hi. O stored hi-only.
// ---------------------------------------------------------------------------
template<bool CAUSAL>
__global__ __launch_bounds__(256, 2) void attn_kernel(
    const bf16_t* __restrict__ qkH, const bf16_t* __restrict__ qkL,
    const bf16_t* __restrict__ vP, bf16_t* __restrict__ oh)
{
    __shared__ bf16_t Vth[2][64][70];  // double-buffered V^T (hi), pad 70
    __shared__ bf16_t Ph[4][32][70];   // per-wave P tile (hi)

    int tid = threadIdx.x;
    int b = blockIdx.z;
    int qb, h;
    if (CAUSAL) {
        int y = blockIdx.y;
        qb = (blockIdx.z & 2) ? (7 - (y & 7)) : (y & 7);
        h  = (blockIdx.x << 1) | (y >> 3);
    } else {
        h  = blockIdx.x;       // grid (NH, TT/128, BB): head pinned to XCD
        qb = blockIdx.y;
    }
    int l = tid & 63, w = tid >> 6;
    int lr = l & 15, lg = l >> 4;
    int qbase = qb * 128;
    const int QKS = 2 * D;

    // Q frags: 32 rows per wave (2 x 16-row frags), hi/lo, both k-halves
    bf16x8 aqh[2][2], aql[2][2];
#pragma unroll
    for (int m = 0; m < 2; ++m) {
        size_t qoff = (size_t)(b * TT + qbase + w * 32 + m * 16 + lr) * QKS + h * HS;
#pragma unroll
        for (int c = 0; c < 2; ++c) {
            aqh[m][c] = *(const bf16x8*)(qkH + qoff + c * 32 + lg * 8);
            aql[m][c] = *(const bf16x8*)(qkL + qoff + c * 32 + lg * 8);
        }
    }

    float mrow[2][4], lsum[2][4];
    f32x4 acc_o[2][4] = {};
#pragma unroll
    for (int m = 0; m < 2; ++m)
#pragma unroll
        for (int r = 0; r < 4; ++r) { mrow[m][r] = -1e30f; lsum[m][r] = 0.0f; }

    int ktmax = CAUSAL ? (2 * qb + 1) : (TT / 64 - 1);

    int vrow = tid >> 3;          // 0..31 (2 rows per thread, +32 apart)
    int vcol = (tid & 7) * 8;

    // prologue: V(0) -> LDS buf0; K(0) -> regs
    bf16x8 vreg[2];
#pragma unroll
    for (int rr = 0; rr < 2; ++rr)
        vreg[rr] = *(const bf16x8*)(vP + (size_t)(b * TT + vrow + rr * 32) * D + h * HS + vcol);
#pragma unroll
    for (int rr = 0; rr < 2; ++rr)
#pragma unroll
        for (int j = 0; j < 8; ++j) Vth[0][vcol + j][vrow + rr * 32] = vreg[rr][j];

    bf16x8 kh0[4], kl0[4], kh1[4], kl1[4];
    {
        size_t koff = (size_t)(b * TT + lr) * QKS + D + h * HS;
#pragma unroll
        for (int nt = 0; nt < 4; ++nt) {
            size_t ko = koff + (size_t)(nt * 16) * QKS;
            kh0[nt] = *(const bf16x8*)(qkH + ko + lg * 8);
            kl0[nt] = *(const bf16x8*)(qkL + ko + lg * 8);
            kh1[nt] = *(const bf16x8*)(qkH + ko + 32 + lg * 8);
            kl1[nt] = *(const bf16x8*)(qkL + ko + 32 + lg * 8);
        }
    }
    __syncthreads();
    int cur = 0;

    for (int kt = 0; kt <= ktmax; ++kt) {
        int kbase = kt * 64;
        int ktn = kt < ktmax ? kt + 1 : ktmax;

        // issue V(t+1) loads (hide under QK^T + softmax + PV)
#pragma unroll
        for (int rr = 0; rr < 2; ++rr)
            vreg[rr] = *(const bf16x8*)(vP + (size_t)(b * TT + ktn * 64 + vrow + rr * 32) * D + h * HS + vcol);

        // S = Q K^T  (32 q-rows x 64 k-cols per wave), split 3-MFMA, K from regs
        f32x4 accs[2][4];
#pragma unroll
        for (int nt = 0; nt < 4; ++nt) {
            __builtin_amdgcn_s_setprio(1);
#pragma unroll
            for (int m = 0; m < 2; ++m) {
                f32x4 s = {};
                s = __builtin_amdgcn_mfma_f32_16x16x32_bf16(aqh[m][0], kh0[nt], s, 0, 0, 0);
                s = __builtin_amdgcn_mfma_f32_16x16x32_bf16(aqh[m][0], kl0[nt], s, 0, 0, 0);
                s = __builtin_amdgcn_mfma_f32_16x16x32_bf16(aql[m][0], kh0[nt], s, 0, 0, 0);
                s = __builtin_amdgcn_mfma_f32_16x16x32_bf16(aqh[m][1], kh1[nt], s, 0, 0, 0);
                s = __builtin_amdgcn_mfma_f32_16x16x32_bf16(aqh[m][1], kl1[nt], s, 0, 0, 0);
                s = __builtin_amdgcn_mfma_f32_16x16x32_bf16(aql[m][1], kh1[nt], s, 0, 0, 0);
                accs[m][nt] = s * 8.0f;   // * sqrt(head_size), faithful to reference
            }
            __builtin_amdgcn_s_setprio(0);
        }

        // prefetch K(t+1) fragments (old K regs dead; softmax+PV hide latency)
        {
            size_t koffn = (size_t)(b * TT + ktn * 64 + lr) * QKS + D + h * HS;
#pragma unroll
            for (int nt = 0; nt < 4; ++nt) {
                size_t ko = koffn + (size_t)(nt * 16) * QKS;
                kh0[nt] = *(const bf16x8*)(qkH + ko + lg * 8);
                kl0[nt] = *(const bf16x8*)(qkL + ko + lg * 8);
                kh1[nt] = *(const bf16x8*)(qkH + ko + 32 + lg * 8);
                kl1[nt] = *(const bf16x8*)(qkL + ko + 32 + lg * 8);
            }
        }

        if (CAUSAL && kt >= 2 * qb) {
#pragma unroll
            for (int m = 0; m < 2; ++m)
#pragma unroll
                for (int nt = 0; nt < 4; ++nt)
#pragma unroll
                    for (int r = 0; r < 4; ++r) {
                        int qrow = qbase + w * 32 + m * 16 + lg * 4 + r;
                        int kcol = kbase + nt * 16 + lr;
                        if (kcol > qrow) accs[m][nt][r] = -1e30f;
                    }
        }

        // online softmax (row-wise over the 16 lanes holding this row)
#pragma unroll
        for (int m = 0; m < 2; ++m) {
            float alpha[4];
#pragma unroll
            for (int r = 0; r < 4; ++r) {
                float mx = fmaxf(fmaxf(accs[m][0][r], accs[m][1][r]),
                                 fmaxf(accs[m][2][r], accs[m][3][r]));
#pragma unroll
                for (int msk = 1; msk < 16; msk <<= 1) mx = fmaxf(mx, __shfl_xor(mx, msk, 64));
                float mnew = fmaxf(mrow[m][r], mx);
                float sum = 0.0f;
#pragma unroll
                for (int nt = 0; nt < 4; ++nt) {
                    float p = __expf(accs[m][nt][r] - mnew);
                    accs[m][nt][r] = p;
                    sum += p;
                }
#pragma unroll
                for (int msk = 1; msk < 16; msk <<= 1) sum += __shfl_xor(sum, msk, 64);
                alpha[r] = __expf(mrow[m][r] - mnew);
                lsum[m][r] = lsum[m][r] * alpha[r] + sum;
                mrow[m][r] = mnew;
            }
#pragma unroll
            for (int et = 0; et < 4; ++et)
#pragma unroll
                for (int r = 0; r < 4; ++r) acc_o[m][et][r] *= alpha[r];

            // P -> LDS (bf16 hi only; wave-private, no barrier needed)
#pragma unroll
            for (int nt = 0; nt < 4; ++nt)
#pragma unroll
                for (int r = 0; r < 4; ++r)
                    Ph[w][m * 16 + lg * 4 + r][nt * 16 + lr] = (bf16_t)accs[m][nt][r];
        }

        // O += P @ V  (pure bf16) from current V buffer
#pragma unroll
        for (int m = 0; m < 2; ++m) {
            bf16x8 ap0 = *(const bf16x8*)&Ph[w][m * 16 + lr][lg * 8];
            bf16x8 ap1 = *(const bf16x8*)&Ph[w][m * 16 + lr][32 + lg * 8];
            __builtin_amdgcn_s_setprio(1);
#pragma unroll
            for (int et = 0; et < 4; ++et) {
                bf16x8 bv0 = *(const bf16x8*)&Vth[cur][et * 16 + lr][lg * 8];
                bf16x8 bv1 = *(const bf16x8*)&Vth[cur][et * 16 + lr][32 + lg * 8];
                acc_o[m][et] = __builtin_amdgcn_mfma_f32_16x16x32_bf16(ap0, bv0, acc_o[m][et], 0, 0, 0);
                acc_o[m][et] = __builtin_amdgcn_mfma_f32_16x16x32_bf16(ap1, bv1, acc_o[m][et], 0, 0, 0);
            }
            __builtin_amdgcn_s_setprio(0);
        }

        // stage V(t+1) into the other buffer, then the single barrier
#pragma unroll
        for (int rr = 0; rr < 2; ++rr)
#pragma unroll
            for (int j = 0; j < 8; ++j) Vth[cur ^ 1][vcol + j][vrow + rr * 32] = vreg[rr][j];
        __syncthreads();
        cur ^= 1;
    }

#pragma unroll
    for (int m = 0; m < 2; ++m) {
        size_t obase = (size_t)(b * TT + qbase + w * 32 + m * 16) * D + h * HS;
#pragma unroll
        for (int r = 0; r < 4; ++r) {
            float inv = 1.0f / lsum[m][r];
#pragma unroll
            for (int et = 0; et < 4; ++et) {
                float v = acc_o[m][et][r] * inv;
                size_t idx = obase + (size_t)(lg * 4 + r) * D + et * 16 + lr;
                oh[idx] = (bf16_t)v;
            }
        }
    }
}

// ---------------------------------------------------------------------------
extern "C" void kernel_launch(void* const* d_in, const int* in_sizes, int n_in,
                              void* d_out, int out_size, void* d_ws, size_t ws_size,
                              hipStream_t stream)
{
    const float* x     = (const float*)d_in[0];
    const float* Wq    = (const float*)d_in[1];
    const float* bq    = (const float*)d_in[2];
    const float* Wk    = (const float*)d_in[3];
    const float* bk    = (const float*)d_in[4];
    const float* Wv    = (const float*)d_in[5];
    const float* bv    = (const float*)d_in[6];
    const float* Wp    = (const float*)d_in[7];
    const float* bp    = (const float*)d_in[8];
    const float* gamma = (const float*)d_in[9];
    const float* W1    = (const float*)d_in[10];
    const float* b1    = (const float*)d_in[11];
    const float* W2    = (const float*)d_in[12];
    const float* b2    = (const float*)d_in[13];
    float* out = (float*)d_out;

    // workspace layout (96 MB):
    //  0..16  : nrm hi/lo (8 MB each); ao hi (aliased)
    // 16..48  : qk hi (16) + qk lo (16); h1 bf16-hi (32) aliases (ffn phase)
    // 48..56  : v hi (8); W1 conv slot (8, ffn phase, v dead)
    // 64..72  : bias2048 (attn phases) / W2 conv slot (8, ffn phase)
    // 80..96  : persistent weights: wqk hi 4, wqk lo 4, wv hi 2, wp hi 2
    char* base = (char*)d_ws;
    bf16_t* nrmH  = (bf16_t*)(base);
    bf16_t* nrmL  = (bf16_t*)(base + (8u  << 20));
    bf16_t* qkH   = (bf16_t*)(base + (16u << 20));
    bf16_t* qkL   = (bf16_t*)(base + (32u << 20));
    bf16_t* vH    = (bf16_t*)(base + (48u << 20));
    bf16_t* h1H   = (bf16_t*)(base + (16u << 20));   // 32 MB, hi only
    bf16_t* w1sl  = (bf16_t*)(base + (48u << 20));   // 8 MB (hi only)
    float*  bias2 = (float*)(base + (64u << 20));
    bf16_t* w2sl  = (bf16_t*)(base + (64u << 20));   // 8 MB (hi only)
    bf16_t* wsl   = (bf16_t*)(base + (80u << 20));   // persistent
    bf16_t* aoH = nrmH;
    float* abuf = out;   // 'a' lives in d_out, dead before final write
    float* bbuf = out;   // 'b' overwrites 'a' in d_out (a unused after rmsnorm)

    // persistent weights: wqk hi [2048][1024], wqk lo, wv hi, wp hi
    size_t DD = (size_t)D * D;
    bf16_t* wqkH = wsl;
    bf16_t* wqkL = wsl + 2 * DD;
    bf16_t* wvH  = wsl + 4 * DD;
    bf16_t* wpH  = wsl + 5 * DD;

    dim3 blk(256);
    dim3 gcvD(D / 64, D / 64);
    dim3 gcv1(D / 64, HF / 64);
    dim3 gcv2(HF / 64, D / 64);
    dim3 gQK(2 * D / 128, MR / 128);    // 16 x 32 = 512 blocks, TN=128
    dim3 gP(D / 64, MR / 128);          // 16 x 32 = 512 blocks, TN=64
    dim3 gF(HF / 128, MR / 128);        // 32 x 32 = 1024 blocks, TN=128
    dim3 gAnc(NH, TT / 128, BB);        // non-causal: head pinned to XCD
    dim3 gAc(TT / 128, NH, BB);         // causal: r10 balanced mapping

    // ---- a = x + attn(rmsnorm(x), causal=false)
    rmsnorm_kernel<true><<<MR, blk, 0, stream>>>(x, gamma, nrmH, nrmL);
    concat_bias_kernel<<<8, blk, 0, stream>>>(bq, bk, bias2);
    convw_kernel<true><<<gcvD, blk, 0, stream>>>(Wq, wqkH,      wqkL,      D, D);
    convw_kernel<true><<<gcvD, blk, 0, stream>>>(Wk, wqkH + DD, wqkL + DD, D, D);
    convw_kernel<false><<<gcvD, blk, 0, stream>>>(Wv, wvH, nullptr, D, D);
    convw_kernel<false><<<gcvD, blk, 0, stream>>>(Wp, wpH, nullptr, D, D);
    gemm_kernel<128, false, true, true, 1, false, false><<<gQK, blk, 0, stream>>>(nrmH, nrmL, wqkH, wqkL, bias2, nullptr, nullptr, qkH, qkL, 2 * D, D);
    gemm_kernel<64, false, false, false, 2, false, false><<<gP, blk, 0, stream>>>(nrmH, nullptr, wvH, nullptr, bv, nullptr, nullptr, vH, nullptr, D, D);
    attn_kernel<false><<<gAnc, blk, 0, stream>>>(qkH, qkL, vH, aoH);
    gemm_kernel<64, false, false, false, 0, false, true><<<gP, blk, 0, stream>>>(aoH, nullptr, wpH, nullptr, bp, x, abuf, nullptr, nullptr, D, D);

    // ---- b = x + ffwd(rmsnorm(a))
    rmsnorm_kernel<false><<<MR, blk, 0, stream>>>(abuf, gamma, nrmH, nullptr);
    convw_kernel<false><<<gcv1, blk, 0, stream>>>(W1, w1sl, nullptr, D, HF);
    gemm_kernel<128, true, false, false, 2, true, false><<<gF, blk, 0, stream>>>(nrmH, nullptr, w1sl, nullptr, b1, nullptr, nullptr, h1H, nullptr, HF, D);
    convw_kernel<false><<<gcv2, blk, 0, stream>>>(W2, w2sl, nullptr, HF, D);
    gemm_kernel<64, false, false, false, 0, false, true><<<gP, blk, 0, stream>>>(h1H, nullptr, w2sl, nullptr, b2, x, bbuf, nullptr, nullptr, D, HF);

    // ---- c = b + attn(rmsnorm(b), causal=true)  (attn weights still resident)
    rmsnorm_kernel<true><<<MR, blk, 0, stream>>>(bbuf, gamma, nrmH, nrmL);
    concat_bias_kernel<<<8, blk, 0, stream>>>(bq, bk, bias2);
    gemm_kernel<128, false, true, true, 1, false, false><<<gQK, blk, 0, stream>>>(nrmH, nrmL, wqkH, wqkL, bias2, nullptr, nullptr, qkH, qkL, 2 * D, D);
    gemm_kernel<64, false, false, false, 2, false, false><<<gP, blk, 0, stream>>>(nrmH, nullptr, wvH, nullptr, bv, nullptr, nullptr, vH, nullptr, D, D);
    attn_kernel<true><<<gAc, blk, 0, stream>>>(qkH, qkL, vH, aoH);
    gemm_kernel<64, false, false, false, 0, false, true><<<gP, blk, 0, stream>>>(aoH, nullptr, wpH, nullptr, bp, bbuf, out, nullptr, nullptr, D, D);
}

// Round 21
// 480.826 us; speedup vs baseline: 1.1737x; 1.0401x over previous
//
#include <hip/hip_runtime.h>
#include <cstdint>
#include <cstddef>

typedef __bf16 bf16_t;
typedef __attribute__((ext_vector_type(8))) __bf16 bf16x8;
typedef __attribute__((ext_vector_type(4))) __bf16 bf16x4;
typedef __attribute__((ext_vector_type(4))) float f32x4;

constexpr int D  = 1024;   // d_model
constexpr int TT = 1024;   // seq len
constexpr int BB = 4;      // batch
constexpr int NH = 16;     // heads
constexpr int HS = 64;     // head size
constexpr int MR = BB * TT; // 4096 rows
constexpr int HF = 4096;   // ffn hidden

__device__ inline void gload_lds16(const bf16_t* g, bf16_t* l)
{
    __builtin_amdgcn_global_load_lds(
        (const __attribute__((address_space(1))) void*)g,
        (__attribute__((address_space(3))) void*)l, 16, 0, 0);
}

// DPP row-rotate (within 16-lane DPP row): pure-VALU cross-lane, no LDS pipe.
// dpp_ctrl must be a compile-time constant -> template parameter.
template<int N>
__device__ inline float dpp_ror(float x)
{
    int v = __builtin_amdgcn_update_dpp(0, __float_as_int(x),
                                        0x120 | N, 0xf, 0xf, false);
    return __int_as_float(v);
}

// ---------------------------------------------------------------------------
// RMSNorm: f32 in -> bf16 hi (+ optional lo) planes. One block per row.
// ---------------------------------------------------------------------------
template<bool LO>
__global__ __launch_bounds__(256) void rmsnorm_kernel(const float* __restrict__ x,
                                                      const float* __restrict__ gamma,
                                                      bf16_t* __restrict__ oh,
                                                      bf16_t* __restrict__ ol)
{
    int row = blockIdx.x;
    int t   = threadIdx.x;
    const float* xr = x + (size_t)row * D;
    float4 xv = *(const float4*)(xr + t * 4);
    float ss = xv.x * xv.x + xv.y * xv.y + xv.z * xv.z + xv.w * xv.w;
#pragma unroll
    for (int m = 1; m < 64; m <<= 1) ss += __shfl_xor(ss, m, 64);
    __shared__ float part[4];
    if ((t & 63) == 0) part[t >> 6] = ss;
    __syncthreads();
    float tot   = part[0] + part[1] + part[2] + part[3];
    float scale = rsqrtf(tot * (1.0f / D) + 1e-6f);
    float4 gv = *(const float4*)(gamma + t * 4);
    float vals[4] = {xv.x * scale * gv.x, xv.y * scale * gv.y,
                     xv.z * scale * gv.z, xv.w * scale * gv.w};
    bf16x4 vh, vl;
#pragma unroll
    for (int j = 0; j < 4; ++j) {
        bf16_t h = (bf16_t)vals[j];
        vh[j] = h;
        vl[j] = (bf16_t)(vals[j] - (float)h);
    }
    *(bf16x4*)(oh + (size_t)row * D + t * 4) = vh;
    if (LO) *(bf16x4*)(ol + (size_t)row * D + t * 4) = vl;
}

// ---------------------------------------------------------------------------
// concat 2x [1024] f32 biases into one [2048] buffer (bq|bk)
// ---------------------------------------------------------------------------
__global__ __launch_bounds__(256) void concat_bias_kernel(const float* __restrict__ a,
                                                          const float* __restrict__ b,
                                                          float* __restrict__ o)
{
    int i = blockIdx.x * 256 + threadIdx.x;
    o[i] = i < 1024 ? a[i] : b[i - 1024];
}

// ---------------------------------------------------------------------------
// Weight convert: W f32 [K][N] -> dH (+ optional dL) bf16 [N][K] (transposed).
// 64x64 tile via padded LDS transpose. Grid (K/64, N/64), 256 thr.
// ---------------------------------------------------------------------------
template<bool LO>
__global__ __launch_bounds__(256) void convw_kernel(const float* __restrict__ W,
                                                    bf16_t* __restrict__ dH,
                                                    bf16_t* __restrict__ dL,
                                                    int K, int N)
{
    __shared__ float sld[64][65];
    int t = threadIdx.x;
    int k0 = blockIdx.x * 64, n0 = blockIdx.y * 64;
    int kr = t >> 4, nc = (t & 15) * 4;
#pragma unroll
    for (int p = 0; p < 4; ++p) {
        int k = p * 16 + kr;
        float4 v = *(const float4*)(W + (size_t)(k0 + k) * N + n0 + nc);
        sld[k][nc] = v.x; sld[k][nc + 1] = v.y; sld[k][nc + 2] = v.z; sld[k][nc + 3] = v.w;
    }
    __syncthreads();
    int n = t >> 2, kh = (t & 3) * 16;
    bf16x8 h0, l0, h1, l1;
#pragma unroll
    for (int j = 0; j < 8; ++j) {
        float v = sld[kh + j][n];
        bf16_t h = (bf16_t)v;
        h0[j] = h; l0[j] = (bf16_t)(v - (float)h);
    }
#pragma unroll
    for (int j = 0; j < 8; ++j) {
        float v = sld[kh + 8 + j][n];
        bf16_t h = (bf16_t)v;
        h1[j] = h; l1[j] = (bf16_t)(v - (float)h);
    }
    size_t o = (size_t)(n0 + n) * K + k0 + kh;
    *(bf16x8*)(dH + o)     = h0;
    *(bf16x8*)(dH + o + 8) = h1;
    if (LO) {
        *(bf16x8*)(dL + o)     = l0;
        *(bf16x8*)(dL + o + 8) = l1;
    }
}

// ---------------------------------------------------------------------------
// Batched convert of the 4 attention weights (all D x D):
// z=0: Wq -> wqkH/wqkL; z=1: Wk -> wqkH+DD/wqkL+DD; z=2: Wv -> wvH;
// z=3: Wp -> wpH. Saves 3 kernel launches.
// ---------------------------------------------------------------------------
__global__ __launch_bounds__(256) void convw4_kernel(
    const float* __restrict__ Wq, const float* __restrict__ Wk,
    const float* __restrict__ Wv, const float* __restrict__ Wp,
    bf16_t* __restrict__ wqkH, bf16_t* __restrict__ wqkL,
    bf16_t* __restrict__ wvH, bf16_t* __restrict__ wpH)
{
    __shared__ float sld[64][65];
    int z = blockIdx.z;
    size_t DD = (size_t)D * D;
    const float* W = (z == 0) ? Wq : (z == 1) ? Wk : (z == 2) ? Wv : Wp;
    bf16_t* dH = (z == 0) ? wqkH : (z == 1) ? (wqkH + DD) : (z == 2) ? wvH : wpH;
    bf16_t* dL = (z == 0) ? wqkL : (z == 1) ? (wqkL + DD) : nullptr;
    bool LO = (z < 2);

    int t = threadIdx.x;
    int k0 = blockIdx.x * 64, n0 = blockIdx.y * 64;
    int kr = t >> 4, nc = (t & 15) * 4;
#pragma unroll
    for (int p = 0; p < 4; ++p) {
        int k = p * 16 + kr;
        float4 v = *(const float4*)(W + (size_t)(k0 + k) * D + n0 + nc);
        sld[k][nc] = v.x; sld[k][nc + 1] = v.y; sld[k][nc + 2] = v.z; sld[k][nc + 3] = v.w;
    }
    __syncthreads();
    int n = t >> 2, kh = (t & 3) * 16;
    bf16x8 h0, l0, h1, l1;
#pragma unroll
    for (int j = 0; j < 8; ++j) {
        float v = sld[kh + j][n];
        bf16_t h = (bf16_t)v;
        h0[j] = h; l0[j] = (bf16_t)(v - (float)h);
    }
#pragma unroll
    for (int j = 0; j < 8; ++j) {
        float v = sld[kh + 8 + j][n];
        bf16_t h = (bf16_t)v;
        h1[j] = h; l1[j] = (bf16_t)(v - (float)h);
    }
    size_t o = (size_t)(n0 + n) * D + k0 + kh;
    *(bf16x8*)(dH + o)     = h0;
    *(bf16x8*)(dH + o + 8) = h1;
    if (LO) {
        *(bf16x8*)(dL + o)     = l0;
        *(bf16x8*)(dL + o + 8) = l1;
    }
}

// ---------------------------------------------------------------------------
// Split-precision GEMM, 128xTN tile (TN = 64 or 128), BK=32, 4 waves.
// A bf16 [M][K] hi (+ lo if ALO); W bf16 [N][K] hi (+ lo if WLO).
// MFMA passes: hh, + hl (if WLO), + lh (if ALO).
// XCD swizzle: CM=false -> A-chunk resident; CM=true -> B-chunk resident.
// OUTM: 0 = f32 out, 1 = bf16 hi/lo planes, 2 = bf16 hi only.
// ---------------------------------------------------------------------------
template<int TN, bool CM, bool ALO, bool WLO, int OUTM, bool RELU, bool RESID>
__global__ __launch_bounds__(256, 2) void gemm_kernel(
    const bf16_t* __restrict__ Ahp, const bf16_t* __restrict__ Alp,
    const bf16_t* __restrict__ Whp, const bf16_t* __restrict__ Wlp,
    const float* __restrict__ bias, const float* resid,
    float* outf, bf16_t* __restrict__ outh, bf16_t* __restrict__ outl,
    int N, int K)
{
    constexpr int NF = TN / 32;          // n-frags per wave
    constexpr int AP = ALO ? 2 : 1;      // A planes
    constexpr int WP = WLO ? 2 : 1;      // W planes
    __shared__ bf16_t sA[AP][128][32];   // [plane][m][k], linear (gload_lds dest)
    __shared__ bf16_t sW[WP][TN][32];    // [plane][n][k]

    int t = threadIdx.x;
    int l = t & 63, w = t >> 6;
    int lr = l & 15, lg = l >> 4;

    int gx  = gridDim.x;
    int gy  = gridDim.y;
    int nwg = gx * gy;
    int bid = blockIdx.y * gx + blockIdx.x;
    int xcd = bid & 7, idx = bid >> 3;
    int nb, mb;
    if (CM) {
        int cw = gx >> 3;
        mb = idx % gy;
        nb = xcd * cw + idx / gy;
    } else {
        int s = xcd * (nwg >> 3) + idx;
        nb = s % gx; mb = s / gx;
    }
    int m0 = mb * 128, n0 = nb * TN;
    int wr = (w >> 1) * 64, wc = (w & 1) * (TN / 2);

    f32x4 acc[4][NF] = {};

    int srow = (l >> 2);      // 0..15 within chunk
    int sch  = l & 3;         // 16B slot within 64B row

    for (int kk = 0; kk < K; kk += 32) {
        __syncthreads();
        // A planes: 128 rows = 4 waves x 2 chunks x 16
#pragma unroll
        for (int c = 0; c < 2; ++c) {
            int rbase = w * 32 + c * 16;
            int row = rbase + srow;
            int f = (row >> 1) & 3;
            size_t goff = (size_t)row * K + kk + (size_t)((sch ^ f)) * 8;
            gload_lds16(Ahp + (size_t)m0 * K + goff, &sA[0][rbase][0]);
            if (ALO) gload_lds16(Alp + (size_t)m0 * K + goff, &sA[AP - 1][rbase][0]);
        }
        // W planes: TN rows = 4 waves x (TN/64) chunks x 16
#pragma unroll
        for (int c = 0; c < TN / 64; ++c) {
            int rbase = w * (TN / 4) + c * 16;
            int row = rbase + srow;
            int f = (row >> 1) & 3;
            size_t goff = (size_t)row * K + kk + (size_t)((sch ^ f)) * 8;
            gload_lds16(Whp + (size_t)n0 * K + goff, &sW[0][rbase][0]);
            if (WLO) gload_lds16(Wlp + (size_t)n0 * K + goff, &sW[WP - 1][rbase][0]);
        }
        __syncthreads();

        bf16x8 a0[4], a1[4], b0[NF], b1[NF];
#pragma unroll
        for (int m = 0; m < 4; ++m) {
            int row = wr + m * 16 + lr;
            int sl = lg ^ ((row >> 1) & 3);
            a0[m] = *(const bf16x8*)&sA[0][row][sl * 8];
            if (ALO) a1[m] = *(const bf16x8*)&sA[AP - 1][row][sl * 8];
        }
#pragma unroll
        for (int n = 0; n < NF; ++n) {
            int row = wc + n * 16 + lr;
            int sl = lg ^ ((row >> 1) & 3);
            b0[n] = *(const bf16x8*)&sW[0][row][sl * 8];
            if (WLO) b1[n] = *(const bf16x8*)&sW[WP - 1][row][sl * 8];
        }
        // hh pass, then (if WLO) hl, then (if ALO) lh
#pragma unroll
        for (int m = 0; m < 4; ++m)
#pragma unroll
            for (int n = 0; n < NF; ++n)
                acc[m][n] = __builtin_amdgcn_mfma_f32_16x16x32_bf16(a0[m], b0[n], acc[m][n], 0, 0, 0);
        if (WLO) {
#pragma unroll
            for (int m = 0; m < 4; ++m)
#pragma unroll
                for (int n = 0; n < NF; ++n)
                    acc[m][n] = __builtin_amdgcn_mfma_f32_16x16x32_bf16(a0[m], b1[n], acc[m][n], 0, 0, 0);
        }
        if (ALO) {
#pragma unroll
            for (int m = 0; m < 4; ++m)
#pragma unroll
                for (int n = 0; n < NF; ++n)
                    acc[m][n] = __builtin_amdgcn_mfma_f32_16x16x32_bf16(a1[m], b0[n], acc[m][n], 0, 0, 0);
        }
    }

#pragma unroll
    for (int m = 0; m < 4; ++m) {
#pragma unroll
        for (int n = 0; n < NF; ++n) {
            int col = n0 + wc + n * 16 + lr;
            float bv = bias[col];
#pragma unroll
            for (int r = 0; r < 4; ++r) {
                int row = m0 + wr + m * 16 + lg * 4 + r;
                float v = acc[m][n][r] + bv;
                if (RELU)  v = (v >= 0.0f) ? v : 0.1f * v;
                if (RESID) v += resid[(size_t)row * N + col];
                if (OUTM == 0) {
                    outf[(size_t)row * N + col] = v;
                } else if (OUTM == 2) {
                    outh[(size_t)row * N + col] = (bf16_t)v;
                } else {
                    bf16_t h = (bf16_t)v;
                    outh[(size_t)row * N + col] = h;
                    outl[(size_t)row * N + col] = (bf16_t)(v - (float)h);
                }
            }
        }
    }
}

// ---------------------------------------------------------------------------
// Flash attention. Q/K from qk planes (row stride 2D; q at col 0, k at D);
// V from v plane (row stride D, bf16-hi). r13 geometry (proven optimum).
// XCD locality: h from blockIdx.x -> head's K/V pinned to one XCD L2.
// Causal balance: qb from blockIdx.y, co-CU blocks complementary (r10).
// K(t+1) reg prefetch + single-barrier V dbuf (r9).
// Softmax reductions via DPP row_ror (each q-row's 16 lanes = one DPP row):
// pure VALU, replaces 64 ds_bpermute+lgkm-wait chains per thread per tile.
// Score scale 8 folded into Q at load (exact in bf16: exponent shift).
// QK^T split (3 MFMA/pair); PV pure bf16-hi. O stored hi-only.
// ---------------------------------------------------------------------------
template<bool CAUSAL>
__global__ __launch_bounds__(256, 2) void attn_kernel(
    const bf16_t* __restrict__ qkH, const bf16_t* __restrict__ qkL,
    const bf16_t* __restrict__ vP, bf16_t* __restrict__ oh)
{
    __shared__ bf16_t Vth[2][64][70];  // double-buffered V^T (hi), pad 70
    __shared__ bf16_t Ph[4][32][70];   // per-wave P tile (hi)

    int tid = threadIdx.x;
    int b = blockIdx.z;
    int qb, h;
    if (CAUSAL) {
        int y = blockIdx.y;
        qb = (blockIdx.z & 2) ? (7 - (y & 7)) : (y & 7);
        h  = (blockIdx.x << 1) | (y >> 3);
    } else {
        h  = blockIdx.x;       // grid (NH, TT/128, BB): head pinned to XCD
        qb = blockIdx.y;
    }
    int l = tid & 63, w = tid >> 6;
    int lr = l & 15, lg = l >> 4;
    int qbase = qb * 128;
    const int QKS = 2 * D;

    // Q frags: 32 rows per wave (2 x 16-row frags), hi/lo, both k-halves.
    // Pre-scale by 8 (sqrt(head_size) factor): exact in bf16.
    bf16x8 aqh[2][2], aql[2][2];
#pragma unroll
    for (int m = 0; m < 2; ++m) {
        size_t qoff = (size_t)(b * TT + qbase + w * 32 + m * 16 + lr) * QKS + h * HS;
#pragma unroll
        for (int c = 0; c < 2; ++c) {
            bf16x8 qh = *(const bf16x8*)(qkH + qoff + c * 32 + lg * 8);
            bf16x8 ql = *(const bf16x8*)(qkL + qoff + c * 32 + lg * 8);
#pragma unroll
            for (int j = 0; j < 8; ++j) {
                qh[j] = (bf16_t)((float)qh[j] * 8.0f);
                ql[j] = (bf16_t)((float)ql[j] * 8.0f);
            }
            aqh[m][c] = qh;
            aql[m][c] = ql;
        }
    }

    float mrow[2][4], lsum[2][4];
    f32x4 acc_o[2][4] = {};
#pragma unroll
    for (int m = 0; m < 2; ++m)
#pragma unroll
        for (int r = 0; r < 4; ++r) { mrow[m][r] = -1e30f; lsum[m][r] = 0.0f; }

    int ktmax = CAUSAL ? (2 * qb + 1) : (TT / 64 - 1);

    int vrow = tid >> 3;          // 0..31 (2 rows per thread, +32 apart)
    int vcol = (tid & 7) * 8;

    // prologue: V(0) -> LDS buf0; K(0) -> regs
    bf16x8 vreg[2];
#pragma unroll
    for (int rr = 0; rr < 2; ++rr)
        vreg[rr] = *(const bf16x8*)(vP + (size_t)(b * TT + vrow + rr * 32) * D + h * HS + vcol);
#pragma unroll
    for (int rr = 0; rr < 2; ++rr)
#pragma unroll
        for (int j = 0; j < 8; ++j) Vth[0][vcol + j][vrow + rr * 32] = vreg[rr][j];

    bf16x8 kh0[4], kl0[4], kh1[4], kl1[4];
    {
        size_t koff = (size_t)(b * TT + lr) * QKS + D + h * HS;
#pragma unroll
        for (int nt = 0; nt < 4; ++nt) {
            size_t ko = koff + (size_t)(nt * 16) * QKS;
            kh0[nt] = *(const bf16x8*)(qkH + ko + lg * 8);
            kl0[nt] = *(const bf16x8*)(qkL + ko + lg * 8);
            kh1[nt] = *(const bf16x8*)(qkH + ko + 32 + lg * 8);
            kl1[nt] = *(const bf16x8*)(qkL + ko + 32 + lg * 8);
        }
    }
    __syncthreads();
    int cur = 0;

    for (int kt = 0; kt <= ktmax; ++kt) {
        int kbase = kt * 64;
        int ktn = kt < ktmax ? kt + 1 : ktmax;

        // issue V(t+1) loads (hide under QK^T + softmax + PV)
#pragma unroll
        for (int rr = 0; rr < 2; ++rr)
            vreg[rr] = *(const bf16x8*)(vP + (size_t)(b * TT + ktn * 64 + vrow + rr * 32) * D + h * HS + vcol);

        // S = (8Q) K^T  (32 q-rows x 64 k-cols per wave), split 3-MFMA
        f32x4 accs[2][4];
#pragma unroll
        for (int nt = 0; nt < 4; ++nt) {
            __builtin_amdgcn_s_setprio(1);
#pragma unroll
            for (int m = 0; m < 2; ++m) {
                f32x4 s = {};
                s = __builtin_amdgcn_mfma_f32_16x16x32_bf16(aqh[m][0], kh0[nt], s, 0, 0, 0);
                s = __builtin_amdgcn_mfma_f32_16x16x32_bf16(aqh[m][0], kl0[nt], s, 0, 0, 0);
                s = __builtin_amdgcn_mfma_f32_16x16x32_bf16(aql[m][0], kh0[nt], s, 0, 0, 0);
                s = __builtin_amdgcn_mfma_f32_16x16x32_bf16(aqh[m][1], kh1[nt], s, 0, 0, 0);
                s = __builtin_amdgcn_mfma_f32_16x16x32_bf16(aqh[m][1], kl1[nt], s, 0, 0, 0);
                s = __builtin_amdgcn_mfma_f32_16x16x32_bf16(aql[m][1], kh1[nt], s, 0, 0, 0);
                accs[m][nt] = s;
            }
            __builtin_amdgcn_s_setprio(0);
        }

        // prefetch K(t+1) fragments (old K regs dead; softmax+PV hide latency)
        {
            size_t koffn = (size_t)(b * TT + ktn * 64 + lr) * QKS + D + h * HS;
#pragma unroll
            for (int nt = 0; nt < 4; ++nt) {
                size_t ko = koffn + (size_t)(nt * 16) * QKS;
                kh0[nt] = *(const bf16x8*)(qkH + ko + lg * 8);
                kl0[nt] = *(const bf16x8*)(qkL + ko + lg * 8);
                kh1[nt] = *(const bf16x8*)(qkH + ko + 32 + lg * 8);
                kl1[nt] = *(const bf16x8*)(qkL + ko + 32 + lg * 8);
            }
        }

        if (CAUSAL && kt >= 2 * qb) {
#pragma unroll
            for (int m = 0; m < 2; ++m)
#pragma unroll
                for (int nt = 0; nt < 4; ++nt)
#pragma unroll
                    for (int r = 0; r < 4; ++r) {
                        int qrow = qbase + w * 32 + m * 16 + lg * 4 + r;
                        int kcol = kbase + nt * 16 + lr;
                        if (kcol > qrow) accs[m][nt][r] = -1e30f;
                    }
        }

        // online softmax; row reductions via DPP row_ror (pure VALU)
#pragma unroll
        for (int m = 0; m < 2; ++m) {
            float alpha[4];
#pragma unroll
            for (int r = 0; r < 4; ++r) {
                float mx = fmaxf(fmaxf(accs[m][0][r], accs[m][1][r]),
                                 fmaxf(accs[m][2][r], accs[m][3][r]));
                mx = fmaxf(mx, dpp_ror<1>(mx));
                mx = fmaxf(mx, dpp_ror<2>(mx));
                mx = fmaxf(mx, dpp_ror<4>(mx));
                mx = fmaxf(mx, dpp_ror<8>(mx));
                float mnew = fmaxf(mrow[m][r], mx);
                float sum = 0.0f;
#pragma unroll
                for (int nt = 0; nt < 4; ++nt) {
                    float p = __expf(accs[m][nt][r] - mnew);
                    accs[m][nt][r] = p;
                    sum += p;
                }
                sum += dpp_ror<1>(sum);
                sum += dpp_ror<2>(sum);
                sum += dpp_ror<4>(sum);
                sum += dpp_ror<8>(sum);
                alpha[r] = __expf(mrow[m][r] - mnew);
                lsum[m][r] = lsum[m][r] * alpha[r] + sum;
                mrow[m][r] = mnew;
            }
#pragma unroll
            for (int et = 0; et < 4; ++et)
#pragma unroll
                for (int r = 0; r < 4; ++r) acc_o[m][et][r] *= alpha[r];

            // P -> LDS (bf16 hi only; wave-private, no barrier needed)
#pragma unroll
            for (int nt = 0; nt < 4; ++nt)
#pragma unroll
                for (int r = 0; r < 4; ++r)
                    Ph[w][m * 16 + lg * 4 + r][nt * 16 + lr] = (bf16_t)accs[m][nt][r];
        }

        // O += P @ V  (pure bf16) from current V buffer
#pragma unroll
        for (int m = 0; m < 2; ++m) {
            bf16x8 ap0 = *(const bf16x8*)&Ph[w][m * 16 + lr][lg * 8];
            bf16x8 ap1 = *(const bf16x8*)&Ph[w][m * 16 + lr][32 + lg * 8];
            __builtin_amdgcn_s_setprio(1);
#pragma unroll
            for (int et = 0; et < 4; ++et) {
                bf16x8 bv0 = *(const bf16x8*)&Vth[cur][et * 16 + lr][lg * 8];
                bf16x8 bv1 = *(const bf16x8*)&Vth[cur][et * 16 + lr][32 + lg * 8];
                acc_o[m][et] = __builtin_amdgcn_mfma_f32_16x16x32_bf16(ap0, bv0, acc_o[m][et], 0, 0, 0);
                acc_o[m][et] = __builtin_amdgcn_mfma_f32_16x16x32_bf16(ap1, bv1, acc_o[m][et], 0, 0, 0);
            }
            __builtin_amdgcn_s_setprio(0);
        }

        // stage V(t+1) into the other buffer, then the single barrier
#pragma unroll
        for (int rr = 0; rr < 2; ++rr)
#pragma unroll
            for (int j = 0; j < 8; ++j) Vth[cur ^ 1][vcol + j][vrow + rr * 32] = vreg[rr][j];
        __syncthreads();
        cur ^= 1;
    }

#pragma unroll
    for (int m = 0; m < 2; ++m) {
        size_t obase = (size_t)(b * TT + qbase + w * 32 + m * 16) * D + h * HS;
#pragma unroll
        for (int r = 0; r < 4; ++r) {
            float inv = 1.0f / lsum[m][r];
#pragma unroll
            for (int et = 0; et < 4; ++et) {
                float v = acc_o[m][et][r] * inv;
                size_t idx = obase + (size_t)(lg * 4 + r) * D + et * 16 + lr;
                oh[idx] = (bf16_t)v;
            }
        }
    }
}

// ---------------------------------------------------------------------------
extern "C" void kernel_launch(void* const* d_in, const int* in_sizes, int n_in,
                              void* d_out, int out_size, void* d_ws, size_t ws_size,
                              hipStream_t stream)
{
    const float* x     = (const float*)d_in[0];
    const float* Wq    = (const float*)d_in[1];
    const float* bq    = (const float*)d_in[2];
    const float* Wk    = (const float*)d_in[3];
    const float* bk    = (const float*)d_in[4];
    const float* Wv    = (const float*)d_in[5];
    const float* bv    = (const float*)d_in[6];
    const float* Wp    = (const float*)d_in[7];
    const float* bp    = (const float*)d_in[8];
    const float* gamma = (const float*)d_in[9];
    const float* W1    = (const float*)d_in[10];
    const float* b1    = (const float*)d_in[11];
    const float* W2    = (const float*)d_in[12];
    const float* b2    = (const float*)d_in[13];
    float* out = (float*)d_out;

    // workspace layout (96 MB):
    //  0..16  : nrm hi/lo (8 MB each); ao hi (aliased)
    // 16..48  : qk hi (16) + qk lo (16); h1 bf16-hi (32) aliases (ffn phase)
    // 48..56  : v hi (8); W1 conv slot (8, ffn phase, v dead)
    // 64..72  : bias2048 (attn phases) / W2 conv slot (8, ffn phase)
    // 80..96  : persistent weights: wqk hi 4, wqk lo 4, wv hi 2, wp hi 2
    char* base = (char*)d_ws;
    bf16_t* nrmH  = (bf16_t*)(base);
    bf16_t* nrmL  = (bf16_t*)(base + (8u  << 20));
    bf16_t* qkH   = (bf16_t*)(base + (16u << 20));
    bf16_t* qkL   = (bf16_t*)(base + (32u << 20));
    bf16_t* vH    = (bf16_t*)(base + (48u << 20));
    bf16_t* h1H   = (bf16_t*)(base + (16u << 20));   // 32 MB, hi only
    bf16_t* w1sl  = (bf16_t*)(base + (48u << 20));   // 8 MB (hi only)
    float*  bias2 = (float*)(base + (64u << 20));
    bf16_t* w2sl  = (bf16_t*)(base + (64u << 20));   // 8 MB (hi only)
    bf16_t* wsl   = (bf16_t*)(base + (80u << 20));   // persistent
    bf16_t* aoH = nrmH;
    float* abuf = out;   // 'a' lives in d_out, dead before final write
    float* bbuf = out;   // 'b' overwrites 'a' in d_out (a unused after rmsnorm)

    // persistent weights: wqk hi [2048][1024], wqk lo, wv hi, wp hi
    size_t DD = (size_t)D * D;
    bf16_t* wqkH = wsl;
    bf16_t* wqkL = wsl + 2 * DD;
    bf16_t* wvH  = wsl + 4 * DD;
    bf16_t* wpH  = wsl + 5 * DD;

    dim3 blk(256);
    dim3 gcv4(D / 64, D / 64, 4);
    dim3 gcv1(D / 64, HF / 64);
    dim3 gcv2(HF / 64, D / 64);
    dim3 gQK(2 * D / 128, MR / 128);    // 16 x 32 = 512 blocks, TN=128
    dim3 gP(D / 64, MR / 128);          // 16 x 32 = 512 blocks, TN=64
    dim3 gF(HF / 128, MR / 128);        // 32 x 32 = 1024 blocks, TN=128
    dim3 gAnc(NH, TT / 128, BB);        // non-causal: head pinned to XCD
    dim3 gAc(TT / 128, NH, BB);         // causal: r10 balanced mapping

    // ---- a = x + attn(rmsnorm(x), causal=false)
    rmsnorm_kernel<true><<<MR, blk, 0, stream>>>(x, gamma, nrmH, nrmL);
    concat_bias_kernel<<<8, blk, 0, stream>>>(bq, bk, bias2);
    convw4_kernel<<<gcv4, blk, 0, stream>>>(Wq, Wk, Wv, Wp, wqkH, wqkL, wvH, wpH);
    gemm_kernel<128, false, true, true, 1, false, false><<<gQK, blk, 0, stream>>>(nrmH, nrmL, wqkH, wqkL, bias2, nullptr, nullptr, qkH, qkL, 2 * D, D);
    gemm_kernel<64, false, false, false, 2, false, false><<<gP, blk, 0, stream>>>(nrmH, nullptr, wvH, nullptr, bv, nullptr, nullptr, vH, nullptr, D, D);
    attn_kernel<false><<<gAnc, blk, 0, stream>>>(qkH, qkL, vH, aoH);
    gemm_kernel<64, false, false, false, 0, false, true><<<gP, blk, 0, stream>>>(aoH, nullptr, wpH, nullptr, bp, x, abuf, nullptr, nullptr, D, D);

    // ---- b = x + ffwd(rmsnorm(a))
    rmsnorm_kernel<false><<<MR, blk, 0, stream>>>(abuf, gamma, nrmH, nullptr);
    convw_kernel<false><<<gcv1, blk, 0, stream>>>(W1, w1sl, nullptr, D, HF);
    gemm_kernel<128, true, false, false, 2, true, false><<<gF, blk, 0, stream>>>(nrmH, nullptr, w1sl, nullptr, b1, nullptr, nullptr, h1H, nullptr, HF, D);
    convw_kernel<false><<<gcv2, blk, 0, stream>>>(W2, w2sl, nullptr, HF, D);
    gemm_kernel<64, false, false, false, 0, false, true><<<gP, blk, 0, stream>>>(h1H, nullptr, w2sl, nullptr, b2, x, bbuf, nullptr, nullptr, D, HF);

    // ---- c = b + attn(rmsnorm(b), causal=true)  (attn weights still resident)
    rmsnorm_kernel<true><<<MR, blk, 0, stream>>>(bbuf, gamma, nrmH, nrmL);
    concat_bias_kernel<<<8, blk, 0, stream>>>(bq, bk, bias2);
    gemm_kernel<128, false, true, true, 1, false, false><<<gQK, blk, 0, stream>>>(nrmH, nrmL, wqkH, wqkL, bias2, nullptr, nullptr, qkH, qkL, 2 * D, D);
    gemm_kernel<64, false, false, false, 2, false, false><<<gP, blk, 0, stream>>>(nrmH, nullptr, wvH, nullptr, bv, nullptr, nullptr, vH, nullptr, D, D);
    attn_kernel<true><<<gAc, blk, 0, stream>>>(qkH, qkL, vH, aoH);
    gemm_kernel<64, false, false, false, 0, false, true><<<gP, blk, 0, stream>>>(aoH, nullptr, wpH, nullptr, bp, bbuf, out, nullptr, nullptr, D, D);
}

// Round 22
// 458.251 us; speedup vs baseline: 1.2315x; 1.0493x over previous
//
#include <hip/hip_runtime.h>
#include <cstdint>
#include <cstddef>

typedef __bf16 bf16_t;
typedef __attribute__((ext_vector_type(8))) __bf16 bf16x8;
typedef __attribute__((ext_vector_type(4))) __bf16 bf16x4;
typedef __attribute__((ext_vector_type(4))) float f32x4;

constexpr int D  = 1024;   // d_model
constexpr int TT = 1024;   // seq len
constexpr int BB = 4;      // batch
constexpr int NH = 16;     // heads
constexpr int HS = 64;     // head size
constexpr int MR = BB * TT; // 4096 rows
constexpr int HF = 4096;   // ffn hidden

__device__ inline void gload_lds16(const bf16_t* g, bf16_t* l)
{
    __builtin_amdgcn_global_load_lds(
        (const __attribute__((address_space(1))) void*)g,
        (__attribute__((address_space(3))) void*)l, 16, 0, 0);
}

// DPP row-rotate (within 16-lane DPP row): pure-VALU cross-lane, no LDS pipe.
template<int N>
__device__ inline float dpp_ror(float x)
{
    int v = __builtin_amdgcn_update_dpp(0, __float_as_int(x),
                                        0x120 | N, 0xf, 0xf, false);
    return __int_as_float(v);
}

// ---------------------------------------------------------------------------
// RMSNorm: f32 in -> bf16 hi (+ optional lo) planes. One block per row.
// ---------------------------------------------------------------------------
template<bool LO>
__global__ __launch_bounds__(256) void rmsnorm_kernel(const float* __restrict__ x,
                                                      const float* __restrict__ gamma,
                                                      bf16_t* __restrict__ oh,
                                                      bf16_t* __restrict__ ol)
{
    int row = blockIdx.x;
    int t   = threadIdx.x;
    const float* xr = x + (size_t)row * D;
    float4 xv = *(const float4*)(xr + t * 4);
    float ss = xv.x * xv.x + xv.y * xv.y + xv.z * xv.z + xv.w * xv.w;
#pragma unroll
    for (int m = 1; m < 64; m <<= 1) ss += __shfl_xor(ss, m, 64);
    __shared__ float part[4];
    if ((t & 63) == 0) part[t >> 6] = ss;
    __syncthreads();
    float tot   = part[0] + part[1] + part[2] + part[3];
    float scale = rsqrtf(tot * (1.0f / D) + 1e-6f);
    float4 gv = *(const float4*)(gamma + t * 4);
    float vals[4] = {xv.x * scale * gv.x, xv.y * scale * gv.y,
                     xv.z * scale * gv.z, xv.w * scale * gv.w};
    bf16x4 vh, vl;
#pragma unroll
    for (int j = 0; j < 4; ++j) {
        bf16_t h = (bf16_t)vals[j];
        vh[j] = h;
        vl[j] = (bf16_t)(vals[j] - (float)h);
    }
    *(bf16x4*)(oh + (size_t)row * D + t * 4) = vh;
    if (LO) *(bf16x4*)(ol + (size_t)row * D + t * 4) = vl;
}

// ---------------------------------------------------------------------------
// concat 3x [1024] f32 biases into one [3072] buffer (bq|bk|bv)
// ---------------------------------------------------------------------------
__global__ __launch_bounds__(256) void concat_bias_kernel(const float* __restrict__ a,
                                                          const float* __restrict__ b,
                                                          const float* __restrict__ c,
                                                          float* __restrict__ o)
{
    int i = blockIdx.x * 256 + threadIdx.x;
    o[i] = i < 1024 ? a[i] : (i < 2048 ? b[i - 1024] : c[i - 2048]);
}

// ---------------------------------------------------------------------------
// Weight convert: W f32 [K][N] -> dH (+ optional dL) bf16 [N][K] (transposed).
// 64x64 tile via padded LDS transpose. Grid (K/64, N/64), 256 thr.
// ---------------------------------------------------------------------------
template<bool LO>
__global__ __launch_bounds__(256) void convw_kernel(const float* __restrict__ W,
                                                    bf16_t* __restrict__ dH,
                                                    bf16_t* __restrict__ dL,
                                                    int K, int N)
{
    __shared__ float sld[64][65];
    int t = threadIdx.x;
    int k0 = blockIdx.x * 64, n0 = blockIdx.y * 64;
    int kr = t >> 4, nc = (t & 15) * 4;
#pragma unroll
    for (int p = 0; p < 4; ++p) {
        int k = p * 16 + kr;
        float4 v = *(const float4*)(W + (size_t)(k0 + k) * N + n0 + nc);
        sld[k][nc] = v.x; sld[k][nc + 1] = v.y; sld[k][nc + 2] = v.z; sld[k][nc + 3] = v.w;
    }
    __syncthreads();
    int n = t >> 2, kh = (t & 3) * 16;
    bf16x8 h0, l0, h1, l1;
#pragma unroll
    for (int j = 0; j < 8; ++j) {
        float v = sld[kh + j][n];
        bf16_t h = (bf16_t)v;
        h0[j] = h; l0[j] = (bf16_t)(v - (float)h);
    }
#pragma unroll
    for (int j = 0; j < 8; ++j) {
        float v = sld[kh + 8 + j][n];
        bf16_t h = (bf16_t)v;
        h1[j] = h; l1[j] = (bf16_t)(v - (float)h);
    }
    size_t o = (size_t)(n0 + n) * K + k0 + kh;
    *(bf16x8*)(dH + o)     = h0;
    *(bf16x8*)(dH + o + 8) = h1;
    if (LO) {
        *(bf16x8*)(dL + o)     = l0;
        *(bf16x8*)(dL + o + 8) = l1;
    }
}

// ---------------------------------------------------------------------------
// Batched convert of the 4 attention weights (all D x D):
// z=0: Wq -> wqkH/wqkL; z=1: Wk -> wqkH+DD/wqkL+DD; z=2: Wv -> wvH;
// z=3: Wp -> wpH.
// ---------------------------------------------------------------------------
__global__ __launch_bounds__(256) void convw4_kernel(
    const float* __restrict__ Wq, const float* __restrict__ Wk,
    const float* __restrict__ Wv, const float* __restrict__ Wp,
    bf16_t* __restrict__ wqkH, bf16_t* __restrict__ wqkL,
    bf16_t* __restrict__ wvH, bf16_t* __restrict__ wpH)
{
    __shared__ float sld[64][65];
    int z = blockIdx.z;
    size_t DD = (size_t)D * D;
    const float* W = (z == 0) ? Wq : (z == 1) ? Wk : (z == 2) ? Wv : Wp;
    bf16_t* dH = (z == 0) ? wqkH : (z == 1) ? (wqkH + DD) : (z == 2) ? wvH : wpH;
    bf16_t* dL = (z == 0) ? wqkL : (z == 1) ? (wqkL + DD) : nullptr;
    bool LO = (z < 2);

    int t = threadIdx.x;
    int k0 = blockIdx.x * 64, n0 = blockIdx.y * 64;
    int kr = t >> 4, nc = (t & 15) * 4;
#pragma unroll
    for (int p = 0; p < 4; ++p) {
        int k = p * 16 + kr;
        float4 v = *(const float4*)(W + (size_t)(k0 + k) * D + n0 + nc);
        sld[k][nc] = v.x; sld[k][nc + 1] = v.y; sld[k][nc + 2] = v.z; sld[k][nc + 3] = v.w;
    }
    __syncthreads();
    int n = t >> 2, kh = (t & 3) * 16;
    bf16x8 h0, l0, h1, l1;
#pragma unroll
    for (int j = 0; j < 8; ++j) {
        float v = sld[kh + j][n];
        bf16_t h = (bf16_t)v;
        h0[j] = h; l0[j] = (bf16_t)(v - (float)h);
    }
#pragma unroll
    for (int j = 0; j < 8; ++j) {
        float v = sld[kh + 8 + j][n];
        bf16_t h = (bf16_t)v;
        h1[j] = h; l1[j] = (bf16_t)(v - (float)h);
    }
    size_t o = (size_t)(n0 + n) * D + k0 + kh;
    *(bf16x8*)(dH + o)     = h0;
    *(bf16x8*)(dH + o + 8) = h1;
    if (LO) {
        *(bf16x8*)(dL + o)     = l0;
        *(bf16x8*)(dL + o + 8) = l1;
    }
}

// ---------------------------------------------------------------------------
// Fused QKV GEMM: grid (24, 32), 768 blocks = 3/CU. Columns 0..2047 (QK):
// 3-pass split precision, hi/lo out. Columns 2048..3071 (V): 1-pass hh,
// hi out. Block-uniform runtime branch; light V blocks fill QK blocks'
// barrier stalls (r21: serial QK+V pair ran 2 blocks/CU each).
// ---------------------------------------------------------------------------
__global__ __launch_bounds__(256, 2) void qkv_kernel(
    const bf16_t* __restrict__ Ahp, const bf16_t* __restrict__ Alp,
    const bf16_t* __restrict__ Wh3, const bf16_t* __restrict__ WqkL,
    const float* __restrict__ bias3,
    bf16_t* __restrict__ qkH, bf16_t* __restrict__ qkL,
    bf16_t* __restrict__ vH)
{
    __shared__ bf16_t sA[2][128][32];
    __shared__ bf16_t sW[2][128][32];
    const int K = D;

    int t = threadIdx.x;
    int l = t & 63, w = t >> 6;
    int lr = l & 15, lg = l >> 4;

    int gx = 24, nwg = 768;
    int bid = blockIdx.y * gx + blockIdx.x;
    int xcd = bid & 7, idx = bid >> 3;
    int s = xcd * (nwg >> 3) + idx;
    int nb = s % gx, mb = s / gx;
    int m0 = mb * 128, n0 = nb * 128;
    bool full = (n0 < 2048);
    int wr = (w >> 1) * 64, wc = (w & 1) * 64;

    f32x4 acc[4][4] = {};

    int srow = l >> 2, sch = l & 3;

    for (int kk = 0; kk < K; kk += 32) {
        __syncthreads();
#pragma unroll
        for (int c = 0; c < 2; ++c) {
            int rbase = w * 32 + c * 16;
            int row = rbase + srow;
            int f = (row >> 1) & 3;
            size_t goff = (size_t)row * K + kk + (size_t)(sch ^ f) * 8;
            gload_lds16(Ahp + (size_t)m0 * K + goff, &sA[0][rbase][0]);
            if (full) gload_lds16(Alp + (size_t)m0 * K + goff, &sA[1][rbase][0]);
            gload_lds16(Wh3 + (size_t)n0 * K + goff, &sW[0][rbase][0]);
            if (full) gload_lds16(WqkL + (size_t)n0 * K + goff, &sW[1][rbase][0]);
        }
        __syncthreads();

        bf16x8 a0[4], a1[4], b0[4], b1[4];
#pragma unroll
        for (int m = 0; m < 4; ++m) {
            int row = wr + m * 16 + lr;
            int sl = lg ^ ((row >> 1) & 3);
            a0[m] = *(const bf16x8*)&sA[0][row][sl * 8];
            if (full) a1[m] = *(const bf16x8*)&sA[1][row][sl * 8];
        }
#pragma unroll
        for (int n = 0; n < 4; ++n) {
            int row = wc + n * 16 + lr;
            int sl = lg ^ ((row >> 1) & 3);
            b0[n] = *(const bf16x8*)&sW[0][row][sl * 8];
            if (full) b1[n] = *(const bf16x8*)&sW[1][row][sl * 8];
        }
#pragma unroll
        for (int m = 0; m < 4; ++m)
#pragma unroll
            for (int n = 0; n < 4; ++n)
                acc[m][n] = __builtin_amdgcn_mfma_f32_16x16x32_bf16(a0[m], b0[n], acc[m][n], 0, 0, 0);
        if (full) {
#pragma unroll
            for (int m = 0; m < 4; ++m)
#pragma unroll
                for (int n = 0; n < 4; ++n)
                    acc[m][n] = __builtin_amdgcn_mfma_f32_16x16x32_bf16(a0[m], b1[n], acc[m][n], 0, 0, 0);
#pragma unroll
            for (int m = 0; m < 4; ++m)
#pragma unroll
                for (int n = 0; n < 4; ++n)
                    acc[m][n] = __builtin_amdgcn_mfma_f32_16x16x32_bf16(a1[m], b0[n], acc[m][n], 0, 0, 0);
        }
    }

#pragma unroll
    for (int m = 0; m < 4; ++m) {
#pragma unroll
        for (int n = 0; n < 4; ++n) {
            int col = n0 + wc + n * 16 + lr;
            float bv = bias3[col];
#pragma unroll
            for (int r = 0; r < 4; ++r) {
                int row = m0 + wr + m * 16 + lg * 4 + r;
                float v = acc[m][n][r] + bv;
                if (full) {
                    bf16_t h = (bf16_t)v;
                    qkH[(size_t)row * 2048 + col] = h;
                    qkL[(size_t)row * 2048 + col] = (bf16_t)(v - (float)h);
                } else {
                    vH[(size_t)row * 1024 + (col - 2048)] = (bf16_t)v;
                }
            }
        }
    }
}

// ---------------------------------------------------------------------------
// Split-precision GEMM, 128xTN tile (TN = 64 or 128), BK=32, 4 waves.
// (used for proj / W1 / W2)
// ---------------------------------------------------------------------------
template<int TN, bool CM, bool ALO, bool WLO, int OUTM, bool RELU, bool RESID>
__global__ __launch_bounds__(256, 2) void gemm_kernel(
    const bf16_t* __restrict__ Ahp, const bf16_t* __restrict__ Alp,
    const bf16_t* __restrict__ Whp, const bf16_t* __restrict__ Wlp,
    const float* __restrict__ bias, const float* resid,
    float* outf, bf16_t* __restrict__ outh, bf16_t* __restrict__ outl,
    int N, int K)
{
    constexpr int NF = TN / 32;
    constexpr int AP = ALO ? 2 : 1;
    constexpr int WP = WLO ? 2 : 1;
    __shared__ bf16_t sA[AP][128][32];
    __shared__ bf16_t sW[WP][TN][32];

    int t = threadIdx.x;
    int l = t & 63, w = t >> 6;
    int lr = l & 15, lg = l >> 4;

    int gx  = gridDim.x;
    int gy  = gridDim.y;
    int nwg = gx * gy;
    int bid = blockIdx.y * gx + blockIdx.x;
    int xcd = bid & 7, idx = bid >> 3;
    int nb, mb;
    if (CM) {
        int cw = gx >> 3;
        mb = idx % gy;
        nb = xcd * cw + idx / gy;
    } else {
        int s = xcd * (nwg >> 3) + idx;
        nb = s % gx; mb = s / gx;
    }
    int m0 = mb * 128, n0 = nb * TN;
    int wr = (w >> 1) * 64, wc = (w & 1) * (TN / 2);

    f32x4 acc[4][NF] = {};

    int srow = (l >> 2);
    int sch  = l & 3;

    for (int kk = 0; kk < K; kk += 32) {
        __syncthreads();
#pragma unroll
        for (int c = 0; c < 2; ++c) {
            int rbase = w * 32 + c * 16;
            int row = rbase + srow;
            int f = (row >> 1) & 3;
            size_t goff = (size_t)row * K + kk + (size_t)((sch ^ f)) * 8;
            gload_lds16(Ahp + (size_t)m0 * K + goff, &sA[0][rbase][0]);
            if (ALO) gload_lds16(Alp + (size_t)m0 * K + goff, &sA[AP - 1][rbase][0]);
        }
#pragma unroll
        for (int c = 0; c < TN / 64; ++c) {
            int rbase = w * (TN / 4) + c * 16;
            int row = rbase + srow;
            int f = (row >> 1) & 3;
            size_t goff = (size_t)row * K + kk + (size_t)((sch ^ f)) * 8;
            gload_lds16(Whp + (size_t)n0 * K + goff, &sW[0][rbase][0]);
            if (WLO) gload_lds16(Wlp + (size_t)n0 * K + goff, &sW[WP - 1][rbase][0]);
        }
        __syncthreads();

        bf16x8 a0[4], a1[4], b0[NF], b1[NF];
#pragma unroll
        for (int m = 0; m < 4; ++m) {
            int row = wr + m * 16 + lr;
            int sl = lg ^ ((row >> 1) & 3);
            a0[m] = *(const bf16x8*)&sA[0][row][sl * 8];
            if (ALO) a1[m] = *(const bf16x8*)&sA[AP - 1][row][sl * 8];
        }
#pragma unroll
        for (int n = 0; n < NF; ++n) {
            int row = wc + n * 16 + lr;
            int sl = lg ^ ((row >> 1) & 3);
            b0[n] = *(const bf16x8*)&sW[0][row][sl * 8];
            if (WLO) b1[n] = *(const bf16x8*)&sW[WP - 1][row][sl * 8];
        }
#pragma unroll
        for (int m = 0; m < 4; ++m)
#pragma unroll
            for (int n = 0; n < NF; ++n)
                acc[m][n] = __builtin_amdgcn_mfma_f32_16x16x32_bf16(a0[m], b0[n], acc[m][n], 0, 0, 0);
        if (WLO) {
#pragma unroll
            for (int m = 0; m < 4; ++m)
#pragma unroll
                for (int n = 0; n < NF; ++n)
                    acc[m][n] = __builtin_amdgcn_mfma_f32_16x16x32_bf16(a0[m], b1[n], acc[m][n], 0, 0, 0);
        }
        if (ALO) {
#pragma unroll
            for (int m = 0; m < 4; ++m)
#pragma unroll
                for (int n = 0; n < NF; ++n)
                    acc[m][n] = __builtin_amdgcn_mfma_f32_16x16x32_bf16(a1[m], b0[n], acc[m][n], 0, 0, 0);
        }
    }

#pragma unroll
    for (int m = 0; m < 4; ++m) {
#pragma unroll
        for (int n = 0; n < NF; ++n) {
            int col = n0 + wc + n * 16 + lr;
            float bv = bias[col];
#pragma unroll
            for (int r = 0; r < 4; ++r) {
                int row = m0 + wr + m * 16 + lg * 4 + r;
                float v = acc[m][n][r] + bv;
                if (RELU)  v = (v >= 0.0f) ? v : 0.1f * v;
                if (RESID) v += resid[(size_t)row * N + col];
                if (OUTM == 0) {
                    outf[(size_t)row * N + col] = v;
                } else if (OUTM == 2) {
                    outh[(size_t)row * N + col] = (bf16_t)v;
                } else {
                    bf16_t h = (bf16_t)v;
                    outh[(size_t)row * N + col] = h;
                    outl[(size_t)row * N + col] = (bf16_t)(v - (float)h);
                }
            }
        }
    }
}

// ---------------------------------------------------------------------------
// Flash attention. Q/K from qk planes (row stride 2D; q at col 0, k at D);
// V from v plane (row stride D, bf16-hi). r13 geometry.
// XCD locality: h from blockIdx.x. K(t+1) reg prefetch + single-barrier
// V dbuf (r9). DPP row_ror softmax reductions (r21: 91->85us). Score scale
// 8 folded into Q. QK^T split (3 MFMA/pair); PV pure bf16-hi.
// ---------------------------------------------------------------------------
template<bool CAUSAL>
__global__ __launch_bounds__(256, 2) void attn_kernel(
    const bf16_t* __restrict__ qkH, const bf16_t* __restrict__ qkL,
    const bf16_t* __restrict__ vP, bf16_t* __restrict__ oh)
{
    __shared__ bf16_t Vth[2][64][70];
    __shared__ bf16_t Ph[4][32][70];

    int tid = threadIdx.x;
    int b = blockIdx.z;
    int qb, h;
    if (CAUSAL) {
        int y = blockIdx.y;
        qb = (blockIdx.z & 2) ? (7 - (y & 7)) : (y & 7);
        h  = (blockIdx.x << 1) | (y >> 3);
    } else {
        h  = blockIdx.x;
        qb = blockIdx.y;
    }
    int l = tid & 63, w = tid >> 6;
    int lr = l & 15, lg = l >> 4;
    int qbase = qb * 128;
    const int QKS = 2 * D;

    bf16x8 aqh[2][2], aql[2][2];
#pragma unroll
    for (int m = 0; m < 2; ++m) {
        size_t qoff = (size_t)(b * TT + qbase + w * 32 + m * 16 + lr) * QKS + h * HS;
#pragma unroll
        for (int c = 0; c < 2; ++c) {
            bf16x8 qh = *(const bf16x8*)(qkH + qoff + c * 32 + lg * 8);
            bf16x8 ql = *(const bf16x8*)(qkL + qoff + c * 32 + lg * 8);
#pragma unroll
            for (int j = 0; j < 8; ++j) {
                qh[j] = (bf16_t)((float)qh[j] * 8.0f);
                ql[j] = (bf16_t)((float)ql[j] * 8.0f);
            }
            aqh[m][c] = qh;
            aql[m][c] = ql;
        }
    }

    float mrow[2][4], lsum[2][4];
    f32x4 acc_o[2][4] = {};
#pragma unroll
    for (int m = 0; m < 2; ++m)
#pragma unroll
        for (int r = 0; r < 4; ++r) { mrow[m][r] = -1e30f; lsum[m][r] = 0.0f; }

    int ktmax = CAUSAL ? (2 * qb + 1) : (TT / 64 - 1);

    int vrow = tid >> 3;
    int vcol = (tid & 7) * 8;

    bf16x8 vreg[2];
#pragma unroll
    for (int rr = 0; rr < 2; ++rr)
        vreg[rr] = *(const bf16x8*)(vP + (size_t)(b * TT + vrow + rr * 32) * D + h * HS + vcol);
#pragma unroll
    for (int rr = 0; rr < 2; ++rr)
#pragma unroll
        for (int j = 0; j < 8; ++j) Vth[0][vcol + j][vrow + rr * 32] = vreg[rr][j];

    bf16x8 kh0[4], kl0[4], kh1[4], kl1[4];
    {
        size_t koff = (size_t)(b * TT + lr) * QKS + D + h * HS;
#pragma unroll
        for (int nt = 0; nt < 4; ++nt) {
            size_t ko = koff + (size_t)(nt * 16) * QKS;
            kh0[nt] = *(const bf16x8*)(qkH + ko + lg * 8);
            kl0[nt] = *(const bf16x8*)(qkL + ko + lg * 8);
            kh1[nt] = *(const bf16x8*)(qkH + ko + 32 + lg * 8);
            kl1[nt] = *(const bf16x8*)(qkL + ko + 32 + lg * 8);
        }
    }
    __syncthreads();
    int cur = 0;

    for (int kt = 0; kt <= ktmax; ++kt) {
        int kbase = kt * 64;
        int ktn = kt < ktmax ? kt + 1 : ktmax;

#pragma unroll
        for (int rr = 0; rr < 2; ++rr)
            vreg[rr] = *(const bf16x8*)(vP + (size_t)(b * TT + ktn * 64 + vrow + rr * 32) * D + h * HS + vcol);

        f32x4 accs[2][4];
#pragma unroll
        for (int nt = 0; nt < 4; ++nt) {
            __builtin_amdgcn_s_setprio(1);
#pragma unroll
            for (int m = 0; m < 2; ++m) {
                f32x4 s = {};
                s = __builtin_amdgcn_mfma_f32_16x16x32_bf16(aqh[m][0], kh0[nt], s, 0, 0, 0);
                s = __builtin_amdgcn_mfma_f32_16x16x32_bf16(aqh[m][0], kl0[nt], s, 0, 0, 0);
                s = __builtin_amdgcn_mfma_f32_16x16x32_bf16(aql[m][0], kh0[nt], s, 0, 0, 0);
                s = __builtin_amdgcn_mfma_f32_16x16x32_bf16(aqh[m][1], kh1[nt], s, 0, 0, 0);
                s = __builtin_amdgcn_mfma_f32_16x16x32_bf16(aqh[m][1], kl1[nt], s, 0, 0, 0);
                s = __builtin_amdgcn_mfma_f32_16x16x32_bf16(aql[m][1], kh1[nt], s, 0, 0, 0);
                accs[m][nt] = s;
            }
            __builtin_amdgcn_s_setprio(0);
        }

        {
            size_t koffn = (size_t)(b * TT + ktn * 64 + lr) * QKS + D + h * HS;
#pragma unroll
            for (int nt = 0; nt < 4; ++nt) {
                size_t ko = koffn + (size_t)(nt * 16) * QKS;
                kh0[nt] = *(const bf16x8*)(qkH + ko + lg * 8);
                kl0[nt] = *(const bf16x8*)(qkL + ko + lg * 8);
                kh1[nt] = *(const bf16x8*)(qkH + ko + 32 + lg * 8);
                kl1[nt] = *(const bf16x8*)(qkL + ko + 32 + lg * 8);
            }
        }

        if (CAUSAL && kt >= 2 * qb) {
#pragma unroll
            for (int m = 0; m < 2; ++m)
#pragma unroll
                for (int nt = 0; nt < 4; ++nt)
#pragma unroll
                    for (int r = 0; r < 4; ++r) {
                        int qrow = qbase + w * 32 + m * 16 + lg * 4 + r;
                        int kcol = kbase + nt * 16 + lr;
                        if (kcol > qrow) accs[m][nt][r] = -1e30f;
                    }
        }

#pragma unroll
        for (int m = 0; m < 2; ++m) {
            float alpha[4];
#pragma unroll
            for (int r = 0; r < 4; ++r) {
                float mx = fmaxf(fmaxf(accs[m][0][r], accs[m][1][r]),
                                 fmaxf(accs[m][2][r], accs[m][3][r]));
                mx = fmaxf(mx, dpp_ror<1>(mx));
                mx = fmaxf(mx, dpp_ror<2>(mx));
                mx = fmaxf(mx, dpp_ror<4>(mx));
                mx = fmaxf(mx, dpp_ror<8>(mx));
                float mnew = fmaxf(mrow[m][r], mx);
                float sum = 0.0f;
#pragma unroll
                for (int nt = 0; nt < 4; ++nt) {
                    float p = __expf(accs[m][nt][r] - mnew);
                    accs[m][nt][r] = p;
                    sum += p;
                }
                sum += dpp_ror<1>(sum);
                sum += dpp_ror<2>(sum);
                sum += dpp_ror<4>(sum);
                sum += dpp_ror<8>(sum);
                alpha[r] = __expf(mrow[m][r] - mnew);
                lsum[m][r] = lsum[m][r] * alpha[r] + sum;
                mrow[m][r] = mnew;
            }
#pragma unroll
            for (int et = 0; et < 4; ++et)
#pragma unroll
                for (int r = 0; r < 4; ++r) acc_o[m][et][r] *= alpha[r];

#pragma unroll
            for (int nt = 0; nt < 4; ++nt)
#pragma unroll
                for (int r = 0; r < 4; ++r)
                    Ph[w][m * 16 + lg * 4 + r][nt * 16 + lr] = (bf16_t)accs[m][nt][r];
        }

#pragma unroll
        for (int m = 0; m < 2; ++m) {
            bf16x8 ap0 = *(const bf16x8*)&Ph[w][m * 16 + lr][lg * 8];
            bf16x8 ap1 = *(const bf16x8*)&Ph[w][m * 16 + lr][32 + lg * 8];
            __builtin_amdgcn_s_setprio(1);
#pragma unroll
            for (int et = 0; et < 4; ++et) {
                bf16x8 bv0 = *(const bf16x8*)&Vth[cur][et * 16 + lr][lg * 8];
                bf16x8 bv1 = *(const bf16x8*)&Vth[cur][et * 16 + lr][32 + lg * 8];
                acc_o[m][et] = __builtin_amdgcn_mfma_f32_16x16x32_bf16(ap0, bv0, acc_o[m][et], 0, 0, 0);
                acc_o[m][et] = __builtin_amdgcn_mfma_f32_16x16x32_bf16(ap1, bv1, acc_o[m][et], 0, 0, 0);
            }
            __builtin_amdgcn_s_setprio(0);
        }

#pragma unroll
        for (int rr = 0; rr < 2; ++rr)
#pragma unroll
            for (int j = 0; j < 8; ++j) Vth[cur ^ 1][vcol + j][vrow + rr * 32] = vreg[rr][j];
        __syncthreads();
        cur ^= 1;
    }

#pragma unroll
    for (int m = 0; m < 2; ++m) {
        size_t obase = (size_t)(b * TT + qbase + w * 32 + m * 16) * D + h * HS;
#pragma unroll
        for (int r = 0; r < 4; ++r) {
            float inv = 1.0f / lsum[m][r];
#pragma unroll
            for (int et = 0; et < 4; ++et) {
                float v = acc_o[m][et][r] * inv;
                size_t idx = obase + (size_t)(lg * 4 + r) * D + et * 16 + lr;
                oh[idx] = (bf16_t)v;
            }
        }
    }
}

// ---------------------------------------------------------------------------
extern "C" void kernel_launch(void* const* d_in, const int* in_sizes, int n_in,
                              void* d_out, int out_size, void* d_ws, size_t ws_size,
                              hipStream_t stream)
{
    const float* x     = (const float*)d_in[0];
    const float* Wq    = (const float*)d_in[1];
    const float* bq    = (const float*)d_in[2];
    const float* Wk    = (const float*)d_in[3];
    const float* bk    = (const float*)d_in[4];
    const float* Wv    = (const float*)d_in[5];
    const float* bv    = (const float*)d_in[6];
    const float* Wp    = (const float*)d_in[7];
    const float* bp    = (const float*)d_in[8];
    const float* gamma = (const float*)d_in[9];
    const float* W1    = (const float*)d_in[10];
    const float* b1    = (const float*)d_in[11];
    const float* W2    = (const float*)d_in[12];
    const float* b2    = (const float*)d_in[13];
    float* out = (float*)d_out;

    // workspace layout (96 MB):
    //  0..16  : nrm hi/lo (8 MB each); ao hi (aliased)
    // 16..48  : qk hi (16) + qk lo (16); h1 bf16-hi (32) aliases (ffn phase)
    // 48..56  : v hi (8); W1 conv slot (8, ffn phase, v dead)
    // 64..72  : bias3072 (attn phases) / W2 conv slot (8, ffn phase)
    // 80..96  : persistent weights: wAll hi 6 (wq|wk|wv), wqk lo 4, wp hi 2
    char* base = (char*)d_ws;
    bf16_t* nrmH  = (bf16_t*)(base);
    bf16_t* nrmL  = (bf16_t*)(base + (8u  << 20));
    bf16_t* qkH   = (bf16_t*)(base + (16u << 20));
    bf16_t* qkL   = (bf16_t*)(base + (32u << 20));
    bf16_t* vH    = (bf16_t*)(base + (48u << 20));
    bf16_t* h1H   = (bf16_t*)(base + (16u << 20));   // 32 MB, hi only
    bf16_t* w1sl  = (bf16_t*)(base + (48u << 20));   // 8 MB (hi only)
    float*  bias3 = (float*)(base + (64u << 20));
    bf16_t* w2sl  = (bf16_t*)(base + (64u << 20));   // 8 MB (hi only)
    bf16_t* wsl   = (bf16_t*)(base + (80u << 20));   // persistent
    bf16_t* aoH = nrmH;
    float* abuf = out;
    float* bbuf = out;

    // persistent weights: wAll hi [3072][1024] (wq|wk|wv), wqk lo, wp hi
    size_t DD = (size_t)D * D;
    bf16_t* wAllH = wsl;              // 3*DD
    bf16_t* wqkL  = wsl + 3 * DD;     // 2*DD
    bf16_t* wpH   = wsl + 5 * DD;     // 1*DD

    dim3 blk(256);
    dim3 gcv4(D / 64, D / 64, 4);
    dim3 gcv1(D / 64, HF / 64);
    dim3 gcv2(HF / 64, D / 64);
    dim3 gQKV(3 * D / 128, MR / 128);   // 24 x 32 = 768 blocks
    dim3 gP(D / 64, MR / 128);          // 16 x 32 = 512 blocks, TN=64
    dim3 gF(HF / 128, MR / 128);        // 32 x 32 = 1024 blocks, TN=128
    dim3 gAnc(NH, TT / 128, BB);
    dim3 gAc(TT / 128, NH, BB);

    // ---- a = x + attn(rmsnorm(x), causal=false)
    rmsnorm_kernel<true><<<MR, blk, 0, stream>>>(x, gamma, nrmH, nrmL);
    concat_bias_kernel<<<12, blk, 0, stream>>>(bq, bk, bv, bias3);
    convw4_kernel<<<gcv4, blk, 0, stream>>>(Wq, Wk, Wv, Wp, wAllH, wqkL, wAllH + 2 * DD, wpH);
    qkv_kernel<<<gQKV, blk, 0, stream>>>(nrmH, nrmL, wAllH, wqkL, bias3, qkH, qkL, vH);
    attn_kernel<false><<<gAnc, blk, 0, stream>>>(qkH, qkL, vH, aoH);
    gemm_kernel<64, false, false, false, 0, false, true><<<gP, blk, 0, stream>>>(aoH, nullptr, wpH, nullptr, bp, x, abuf, nullptr, nullptr, D, D);

    // ---- b = x + ffwd(rmsnorm(a))
    rmsnorm_kernel<false><<<MR, blk, 0, stream>>>(abuf, gamma, nrmH, nullptr);
    convw_kernel<false><<<gcv1, blk, 0, stream>>>(W1, w1sl, nullptr, D, HF);
    gemm_kernel<128, true, false, false, 2, true, false><<<gF, blk, 0, stream>>>(nrmH, nullptr, w1sl, nullptr, b1, nullptr, nullptr, h1H, nullptr, HF, D);
    convw_kernel<false><<<gcv2, blk, 0, stream>>>(W2, w2sl, nullptr, HF, D);
    gemm_kernel<64, false, false, false, 0, false, true><<<gP, blk, 0, stream>>>(h1H, nullptr, w2sl, nullptr, b2, x, bbuf, nullptr, nullptr, D, HF);

    // ---- c = b + attn(rmsnorm(b), causal=true)  (attn weights still resident)
    rmsnorm_kernel<true><<<MR, blk, 0, stream>>>(bbuf, gamma, nrmH, nrmL);
    concat_bias_kernel<<<12, blk, 0, stream>>>(bq, bk, bv, bias3);
    qkv_kernel<<<gQKV, blk, 0, stream>>>(nrmH, nrmL, wAllH, wqkL, bias3, qkH, qkL, vH);
    attn_kernel<true><<<gAc, blk, 0, stream>>>(qkH, qkL, vH, aoH);
    gemm_kernel<64, false, false, false, 0, false, true><<<gP, blk, 0, stream>>>(aoH, nullptr, wpH, nullptr, bp, bbuf, out, nullptr, nullptr, D, D);
}

// Round 23
// 434.790 us; speedup vs baseline: 1.2980x; 1.0540x over previous
//
#include <hip/hip_runtime.h>
#include <cstdint>
#include <cstddef>

typedef __bf16 bf16_t;
typedef __attribute__((ext_vector_type(8))) __bf16 bf16x8;
typedef __attribute__((ext_vector_type(4))) __bf16 bf16x4;
typedef __attribute__((ext_vector_type(4))) float f32x4;

constexpr int D  = 1024;   // d_model
constexpr int TT = 1024;   // seq len
constexpr int BB = 4;      // batch
constexpr int NH = 16;     // heads
constexpr int HS = 64;     // head size
constexpr int MR = BB * TT; // 4096 rows
constexpr int HF = 4096;   // ffn hidden

__device__ inline void gload_lds16(const bf16_t* g, bf16_t* l)
{
    __builtin_amdgcn_global_load_lds(
        (const __attribute__((address_space(1))) void*)g,
        (__attribute__((address_space(3))) void*)l, 16, 0, 0);
}

// DPP row-rotate (within 16-lane DPP row): pure-VALU cross-lane, no LDS pipe.
template<int N>
__device__ inline float dpp_ror(float x)
{
    int v = __builtin_amdgcn_update_dpp(0, __float_as_int(x),
                                        0x120 | N, 0xf, 0xf, false);
    return __int_as_float(v);
}

// ---------------------------------------------------------------------------
// RMSNorm: f32 in -> bf16 hi (+ optional lo) planes. One block per row.
// ---------------------------------------------------------------------------
template<bool LO>
__global__ __launch_bounds__(256) void rmsnorm_kernel(const float* __restrict__ x,
                                                      const float* __restrict__ gamma,
                                                      bf16_t* __restrict__ oh,
                                                      bf16_t* __restrict__ ol)
{
    int row = blockIdx.x;
    int t   = threadIdx.x;
    const float* xr = x + (size_t)row * D;
    float4 xv = *(const float4*)(xr + t * 4);
    float ss = xv.x * xv.x + xv.y * xv.y + xv.z * xv.z + xv.w * xv.w;
#pragma unroll
    for (int m = 1; m < 64; m <<= 1) ss += __shfl_xor(ss, m, 64);
    __shared__ float part[4];
    if ((t & 63) == 0) part[t >> 6] = ss;
    __syncthreads();
    float tot   = part[0] + part[1] + part[2] + part[3];
    float scale = rsqrtf(tot * (1.0f / D) + 1e-6f);
    float4 gv = *(const float4*)(gamma + t * 4);
    float vals[4] = {xv.x * scale * gv.x, xv.y * scale * gv.y,
                     xv.z * scale * gv.z, xv.w * scale * gv.w};
    bf16x4 vh, vl;
#pragma unroll
    for (int j = 0; j < 4; ++j) {
        bf16_t h = (bf16_t)vals[j];
        vh[j] = h;
        vl[j] = (bf16_t)(vals[j] - (float)h);
    }
    *(bf16x4*)(oh + (size_t)row * D + t * 4) = vh;
    if (LO) *(bf16x4*)(ol + (size_t)row * D + t * 4) = vl;
}

// ---------------------------------------------------------------------------
// Weight convert: W f32 [K][N] -> dH (+ optional dL) bf16 [N][K] (transposed).
// ---------------------------------------------------------------------------
template<bool LO>
__global__ __launch_bounds__(256) void convw_kernel(const float* __restrict__ W,
                                                    bf16_t* __restrict__ dH,
                                                    bf16_t* __restrict__ dL,
                                                    int K, int N)
{
    __shared__ float sld[64][65];
    int t = threadIdx.x;
    int k0 = blockIdx.x * 64, n0 = blockIdx.y * 64;
    int kr = t >> 4, nc = (t & 15) * 4;
#pragma unroll
    for (int p = 0; p < 4; ++p) {
        int k = p * 16 + kr;
        float4 v = *(const float4*)(W + (size_t)(k0 + k) * N + n0 + nc);
        sld[k][nc] = v.x; sld[k][nc + 1] = v.y; sld[k][nc + 2] = v.z; sld[k][nc + 3] = v.w;
    }
    __syncthreads();
    int n = t >> 2, kh = (t & 3) * 16;
    bf16x8 h0, l0, h1, l1;
#pragma unroll
    for (int j = 0; j < 8; ++j) {
        float v = sld[kh + j][n];
        bf16_t h = (bf16_t)v;
        h0[j] = h; l0[j] = (bf16_t)(v - (float)h);
    }
#pragma unroll
    for (int j = 0; j < 8; ++j) {
        float v = sld[kh + 8 + j][n];
        bf16_t h = (bf16_t)v;
        h1[j] = h; l1[j] = (bf16_t)(v - (float)h);
    }
    size_t o = (size_t)(n0 + n) * K + k0 + kh;
    *(bf16x8*)(dH + o)     = h0;
    *(bf16x8*)(dH + o + 8) = h1;
    if (LO) {
        *(bf16x8*)(dL + o)     = l0;
        *(bf16x8*)(dL + o + 8) = l1;
    }
}

// ---------------------------------------------------------------------------
// Batched convert of the 4 attention weights (all D x D).
// ---------------------------------------------------------------------------
__global__ __launch_bounds__(256) void convw4_kernel(
    const float* __restrict__ Wq, const float* __restrict__ Wk,
    const float* __restrict__ Wv, const float* __restrict__ Wp,
    bf16_t* __restrict__ wqkH, bf16_t* __restrict__ wqkL,
    bf16_t* __restrict__ wvH, bf16_t* __restrict__ wpH)
{
    __shared__ float sld[64][65];
    int z = blockIdx.z;
    size_t DD = (size_t)D * D;
    const float* W = (z == 0) ? Wq : (z == 1) ? Wk : (z == 2) ? Wv : Wp;
    bf16_t* dH = (z == 0) ? wqkH : (z == 1) ? (wqkH + DD) : (z == 2) ? wvH : wpH;
    bf16_t* dL = (z == 0) ? wqkL : (z == 1) ? (wqkL + DD) : nullptr;
    bool LO = (z < 2);

    int t = threadIdx.x;
    int k0 = blockIdx.x * 64, n0 = blockIdx.y * 64;
    int kr = t >> 4, nc = (t & 15) * 4;
#pragma unroll
    for (int p = 0; p < 4; ++p) {
        int k = p * 16 + kr;
        float4 v = *(const float4*)(W + (size_t)(k0 + k) * D + n0 + nc);
        sld[k][nc] = v.x; sld[k][nc + 1] = v.y; sld[k][nc + 2] = v.z; sld[k][nc + 3] = v.w;
    }
    __syncthreads();
    int n = t >> 2, kh = (t & 3) * 16;
    bf16x8 h0, l0, h1, l1;
#pragma unroll
    for (int j = 0; j < 8; ++j) {
        float v = sld[kh + j][n];
        bf16_t h = (bf16_t)v;
        h0[j] = h; l0[j] = (bf16_t)(v - (float)h);
    }
#pragma unroll
    for (int j = 0; j < 8; ++j) {
        float v = sld[kh + 8 + j][n];
        bf16_t h = (bf16_t)v;
        h1[j] = h; l1[j] = (bf16_t)(v - (float)h);
    }
    size_t o = (size_t)(n0 + n) * D + k0 + kh;
    *(bf16x8*)(dH + o)     = h0;
    *(bf16x8*)(dH + o + 8) = h1;
    if (LO) {
        *(bf16x8*)(dL + o)     = l0;
        *(bf16x8*)(dL + o + 8) = l1;
    }
}

// ---------------------------------------------------------------------------
// Fused QKV GEMM: grid (24, 32), 768 blocks = 3/CU. Columns 0..2047 (QK):
// 3-pass split precision, hi/lo out. Columns 2048..3071 (V): 1-pass hh,
// hi out. Bias read directly from bq/bk/bv (tile never straddles a 1024
// boundary -> block-uniform pointer select; concat kernel removed, r22).
// ---------------------------------------------------------------------------
__global__ __launch_bounds__(256, 2) void qkv_kernel(
    const bf16_t* __restrict__ Ahp, const bf16_t* __restrict__ Alp,
    const bf16_t* __restrict__ Wh3, const bf16_t* __restrict__ WqkL,
    const float* __restrict__ bq, const float* __restrict__ bk,
    const float* __restrict__ bv,
    bf16_t* __restrict__ qkH, bf16_t* __restrict__ qkL,
    bf16_t* __restrict__ vH)
{
    __shared__ bf16_t sA[2][128][32];
    __shared__ bf16_t sW[2][128][32];
    const int K = D;

    int t = threadIdx.x;
    int l = t & 63, w = t >> 6;
    int lr = l & 15, lg = l >> 4;

    int gx = 24, nwg = 768;
    int bid = blockIdx.y * gx + blockIdx.x;
    int xcd = bid & 7, idx = bid >> 3;
    int s = xcd * (nwg >> 3) + idx;
    int nb = s % gx, mb = s / gx;
    int m0 = mb * 128, n0 = nb * 128;
    bool full = (n0 < 2048);
    int wr = (w >> 1) * 64, wc = (w & 1) * 64;

    const float* bptr = (n0 < 1024) ? bq : (n0 < 2048) ? bk : bv;
    int bbase = (n0 < 1024) ? 0 : (n0 < 2048) ? 1024 : 2048;

    f32x4 acc[4][4] = {};

    int srow = l >> 2, sch = l & 3;

    for (int kk = 0; kk < K; kk += 32) {
        __syncthreads();
#pragma unroll
        for (int c = 0; c < 2; ++c) {
            int rbase = w * 32 + c * 16;
            int row = rbase + srow;
            int f = (row >> 1) & 3;
            size_t goff = (size_t)row * K + kk + (size_t)(sch ^ f) * 8;
            gload_lds16(Ahp + (size_t)m0 * K + goff, &sA[0][rbase][0]);
            if (full) gload_lds16(Alp + (size_t)m0 * K + goff, &sA[1][rbase][0]);
            gload_lds16(Wh3 + (size_t)n0 * K + goff, &sW[0][rbase][0]);
            if (full) gload_lds16(WqkL + (size_t)n0 * K + goff, &sW[1][rbase][0]);
        }
        __syncthreads();

        bf16x8 a0[4], a1[4], b0[4], b1[4];
#pragma unroll
        for (int m = 0; m < 4; ++m) {
            int row = wr + m * 16 + lr;
            int sl = lg ^ ((row >> 1) & 3);
            a0[m] = *(const bf16x8*)&sA[0][row][sl * 8];
            if (full) a1[m] = *(const bf16x8*)&sA[1][row][sl * 8];
        }
#pragma unroll
        for (int n = 0; n < 4; ++n) {
            int row = wc + n * 16 + lr;
            int sl = lg ^ ((row >> 1) & 3);
            b0[n] = *(const bf16x8*)&sW[0][row][sl * 8];
            if (full) b1[n] = *(const bf16x8*)&sW[1][row][sl * 8];
        }
#pragma unroll
        for (int m = 0; m < 4; ++m)
#pragma unroll
            for (int n = 0; n < 4; ++n)
                acc[m][n] = __builtin_amdgcn_mfma_f32_16x16x32_bf16(a0[m], b0[n], acc[m][n], 0, 0, 0);
        if (full) {
#pragma unroll
            for (int m = 0; m < 4; ++m)
#pragma unroll
                for (int n = 0; n < 4; ++n)
                    acc[m][n] = __builtin_amdgcn_mfma_f32_16x16x32_bf16(a0[m], b1[n], acc[m][n], 0, 0, 0);
#pragma unroll
            for (int m = 0; m < 4; ++m)
#pragma unroll
                for (int n = 0; n < 4; ++n)
                    acc[m][n] = __builtin_amdgcn_mfma_f32_16x16x32_bf16(a1[m], b0[n], acc[m][n], 0, 0, 0);
        }
    }

#pragma unroll
    for (int m = 0; m < 4; ++m) {
#pragma unroll
        for (int n = 0; n < 4; ++n) {
            int col = n0 + wc + n * 16 + lr;
            float bval = bptr[col - bbase];
#pragma unroll
            for (int r = 0; r < 4; ++r) {
                int row = m0 + wr + m * 16 + lg * 4 + r;
                float v = acc[m][n][r] + bval;
                if (full) {
                    bf16_t h = (bf16_t)v;
                    qkH[(size_t)row * 2048 + col] = h;
                    qkL[(size_t)row * 2048 + col] = (bf16_t)(v - (float)h);
                } else {
                    vH[(size_t)row * 1024 + (col - 2048)] = (bf16_t)v;
                }
            }
        }
    }
}

// ---------------------------------------------------------------------------
// Split-precision GEMM, TMxTN tile (TM,TN in {64,128}), BK=32, 4 waves.
// TM=128: waves 2x2 of 64x(TN/2). TM=64: waves 2x2 of 32x(TN/2) -- used for
// N=1024 GEMMs (proj/W2) to reach 1024 blocks = 4/CU (r22: 512 blocks = 2/CU
// was the same grid starvation r5 fixed once).
// ---------------------------------------------------------------------------
template<int TM, int TN, bool CM, bool ALO, bool WLO, int OUTM, bool RELU, bool RESID>
__global__ __launch_bounds__(256, 2) void gemm_kernel(
    const bf16_t* __restrict__ Ahp, const bf16_t* __restrict__ Alp,
    const bf16_t* __restrict__ Whp, const bf16_t* __restrict__ Wlp,
    const float* __restrict__ bias, const float* resid,
    float* outf, bf16_t* __restrict__ outh, bf16_t* __restrict__ outl,
    int N, int K)
{
    constexpr int MF = TM / 32;
    constexpr int NF = TN / 32;
    constexpr int AP = ALO ? 2 : 1;
    constexpr int WP = WLO ? 2 : 1;
    __shared__ bf16_t sA[AP][TM][32];
    __shared__ bf16_t sW[WP][TN][32];

    int t = threadIdx.x;
    int l = t & 63, w = t >> 6;
    int lr = l & 15, lg = l >> 4;

    int gx  = gridDim.x;
    int gy  = gridDim.y;
    int nwg = gx * gy;
    int bid = blockIdx.y * gx + blockIdx.x;
    int xcd = bid & 7, idx = bid >> 3;
    int nb, mb;
    if (CM) {
        int cw = gx >> 3;
        mb = idx % gy;
        nb = xcd * cw + idx / gy;
    } else {
        int s = xcd * (nwg >> 3) + idx;
        nb = s % gx; mb = s / gx;
    }
    int m0 = mb * TM, n0 = nb * TN;
    int wr = (w >> 1) * (TM / 2), wc = (w & 1) * (TN / 2);

    f32x4 acc[MF][NF] = {};

    int srow = (l >> 2);
    int sch  = l & 3;

    for (int kk = 0; kk < K; kk += 32) {
        __syncthreads();
#pragma unroll
        for (int c = 0; c < TM / 64; ++c) {
            int rbase = w * (TM / 4) + c * 16;
            int row = rbase + srow;
            int f = (row >> 1) & 3;
            size_t goff = (size_t)row * K + kk + (size_t)((sch ^ f)) * 8;
            gload_lds16(Ahp + (size_t)m0 * K + goff, &sA[0][rbase][0]);
            if (ALO) gload_lds16(Alp + (size_t)m0 * K + goff, &sA[AP - 1][rbase][0]);
        }
#pragma unroll
        for (int c = 0; c < TN / 64; ++c) {
            int rbase = w * (TN / 4) + c * 16;
            int row = rbase + srow;
            int f = (row >> 1) & 3;
            size_t goff = (size_t)row * K + kk + (size_t)((sch ^ f)) * 8;
            gload_lds16(Whp + (size_t)n0 * K + goff, &sW[0][rbase][0]);
            if (WLO) gload_lds16(Wlp + (size_t)n0 * K + goff, &sW[WP - 1][rbase][0]);
        }
        __syncthreads();

        bf16x8 a0[MF], a1[MF], b0[NF], b1[NF];
#pragma unroll
        for (int m = 0; m < MF; ++m) {
            int row = wr + m * 16 + lr;
            int sl = lg ^ ((row >> 1) & 3);
            a0[m] = *(const bf16x8*)&sA[0][row][sl * 8];
            if (ALO) a1[m] = *(const bf16x8*)&sA[AP - 1][row][sl * 8];
        }
#pragma unroll
        for (int n = 0; n < NF; ++n) {
            int row = wc + n * 16 + lr;
            int sl = lg ^ ((row >> 1) & 3);
            b0[n] = *(const bf16x8*)&sW[0][row][sl * 8];
            if (WLO) b1[n] = *(const bf16x8*)&sW[WP - 1][row][sl * 8];
        }
#pragma unroll
        for (int m = 0; m < MF; ++m)
#pragma unroll
            for (int n = 0; n < NF; ++n)
                acc[m][n] = __builtin_amdgcn_mfma_f32_16x16x32_bf16(a0[m], b0[n], acc[m][n], 0, 0, 0);
        if (WLO) {
#pragma unroll
            for (int m = 0; m < MF; ++m)
#pragma unroll
                for (int n = 0; n < NF; ++n)
                    acc[m][n] = __builtin_amdgcn_mfma_f32_16x16x32_bf16(a0[m], b1[n], acc[m][n], 0, 0, 0);
        }
        if (ALO) {
#pragma unroll
            for (int m = 0; m < MF; ++m)
#pragma unroll
                for (int n = 0; n < NF; ++n)
                    acc[m][n] = __builtin_amdgcn_mfma_f32_16x16x32_bf16(a1[m], b0[n], acc[m][n], 0, 0, 0);
        }
    }

#pragma unroll
    for (int m = 0; m < MF; ++m) {
#pragma unroll
        for (int n = 0; n < NF; ++n) {
            int col = n0 + wc + n * 16 + lr;
            float bval = bias[col];
#pragma unroll
            for (int r = 0; r < 4; ++r) {
                int row = m0 + wr + m * 16 + lg * 4 + r;
                float v = acc[m][n][r] + bval;
                if (RELU)  v = (v >= 0.0f) ? v : 0.1f * v;
                if (RESID) v += resid[(size_t)row * N + col];
                if (OUTM == 0) {
                    outf[(size_t)row * N + col] = v;
                } else if (OUTM == 2) {
                    outh[(size_t)row * N + col] = (bf16_t)v;
                } else {
                    bf16_t h = (bf16_t)v;
                    outh[(size_t)row * N + col] = h;
                    outl[(size_t)row * N + col] = (bf16_t)(v - (float)h);
                }
            }
        }
    }
}

// ---------------------------------------------------------------------------
// Flash attention. Q/K from qk planes (row stride 2D; q at col 0, k at D);
// V from v plane (row stride D, bf16-hi). r13 geometry; XCD head pinning;
// K(t+1) reg prefetch + single-barrier V dbuf (r9); DPP row_ror softmax
// (r21); score scale 8 folded into Q. QK^T split 3-pass; PV bf16-hi.
// ---------------------------------------------------------------------------
template<bool CAUSAL>
__global__ __launch_bounds__(256, 2) void attn_kernel(
    const bf16_t* __restrict__ qkH, const bf16_t* __restrict__ qkL,
    const bf16_t* __restrict__ vP, bf16_t* __restrict__ oh)
{
    __shared__ bf16_t Vth[2][64][70];
    __shared__ bf16_t Ph[4][32][70];

    int tid = threadIdx.x;
    int b = blockIdx.z;
    int qb, h;
    if (CAUSAL) {
        int y = blockIdx.y;
        qb = (blockIdx.z & 2) ? (7 - (y & 7)) : (y & 7);
        h  = (blockIdx.x << 1) | (y >> 3);
    } else {
        h  = blockIdx.x;
        qb = blockIdx.y;
    }
    int l = tid & 63, w = tid >> 6;
    int lr = l & 15, lg = l >> 4;
    int qbase = qb * 128;
    const int QKS = 2 * D;

    bf16x8 aqh[2][2], aql[2][2];
#pragma unroll
    for (int m = 0; m < 2; ++m) {
        size_t qoff = (size_t)(b * TT + qbase + w * 32 + m * 16 + lr) * QKS + h * HS;
#pragma unroll
        for (int c = 0; c < 2; ++c) {
            bf16x8 qh = *(const bf16x8*)(qkH + qoff + c * 32 + lg * 8);
            bf16x8 ql = *(const bf16x8*)(qkL + qoff + c * 32 + lg * 8);
#pragma unroll
            for (int j = 0; j < 8; ++j) {
                qh[j] = (bf16_t)((float)qh[j] * 8.0f);
                ql[j] = (bf16_t)((float)ql[j] * 8.0f);
            }
            aqh[m][c] = qh;
            aql[m][c] = ql;
        }
    }

    float mrow[2][4], lsum[2][4];
    f32x4 acc_o[2][4] = {};
#pragma unroll
    for (int m = 0; m < 2; ++m)
#pragma unroll
        for (int r = 0; r < 4; ++r) { mrow[m][r] = -1e30f; lsum[m][r] = 0.0f; }

    int ktmax = CAUSAL ? (2 * qb + 1) : (TT / 64 - 1);

    int vrow = tid >> 3;
    int vcol = (tid & 7) * 8;

    bf16x8 vreg[2];
#pragma unroll
    for (int rr = 0; rr < 2; ++rr)
        vreg[rr] = *(const bf16x8*)(vP + (size_t)(b * TT + vrow + rr * 32) * D + h * HS + vcol);
#pragma unroll
    for (int rr = 0; rr < 2; ++rr)
#pragma unroll
        for (int j = 0; j < 8; ++j) Vth[0][vcol + j][vrow + rr * 32] = vreg[rr][j];

    bf16x8 kh0[4], kl0[4], kh1[4], kl1[4];
    {
        size_t koff = (size_t)(b * TT + lr) * QKS + D + h * HS;
#pragma unroll
        for (int nt = 0; nt < 4; ++nt) {
            size_t ko = koff + (size_t)(nt * 16) * QKS;
            kh0[nt] = *(const bf16x8*)(qkH + ko + lg * 8);
            kl0[nt] = *(const bf16x8*)(qkL + ko + lg * 8);
            kh1[nt] = *(const bf16x8*)(qkH + ko + 32 + lg * 8);
            kl1[nt] = *(const bf16x8*)(qkL + ko + 32 + lg * 8);
        }
    }
    __syncthreads();
    int cur = 0;

    for (int kt = 0; kt <= ktmax; ++kt) {
        int kbase = kt * 64;
        int ktn = kt < ktmax ? kt + 1 : ktmax;

#pragma unroll
        for (int rr = 0; rr < 2; ++rr)
            vreg[rr] = *(const bf16x8*)(vP + (size_t)(b * TT + ktn * 64 + vrow + rr * 32) * D + h * HS + vcol);

        f32x4 accs[2][4];
#pragma unroll
        for (int nt = 0; nt < 4; ++nt) {
            __builtin_amdgcn_s_setprio(1);
#pragma unroll
            for (int m = 0; m < 2; ++m) {
                f32x4 s = {};
                s = __builtin_amdgcn_mfma_f32_16x16x32_bf16(aqh[m][0], kh0[nt], s, 0, 0, 0);
                s = __builtin_amdgcn_mfma_f32_16x16x32_bf16(aqh[m][0], kl0[nt], s, 0, 0, 0);
                s = __builtin_amdgcn_mfma_f32_16x16x32_bf16(aql[m][0], kh0[nt], s, 0, 0, 0);
                s = __builtin_amdgcn_mfma_f32_16x16x32_bf16(aqh[m][1], kh1[nt], s, 0, 0, 0);
                s = __builtin_amdgcn_mfma_f32_16x16x32_bf16(aqh[m][1], kl1[nt], s, 0, 0, 0);
                s = __builtin_amdgcn_mfma_f32_16x16x32_bf16(aql[m][1], kh1[nt], s, 0, 0, 0);
                accs[m][nt] = s;
            }
            __builtin_amdgcn_s_setprio(0);
        }

        {
            size_t koffn = (size_t)(b * TT + ktn * 64 + lr) * QKS + D + h * HS;
#pragma unroll
            for (int nt = 0; nt < 4; ++nt) {
                size_t ko = koffn + (size_t)(nt * 16) * QKS;
                kh0[nt] = *(const bf16x8*)(qkH + ko + lg * 8);
                kl0[nt] = *(const bf16x8*)(qkL + ko + lg * 8);
                kh1[nt] = *(const bf16x8*)(qkH + ko + 32 + lg * 8);
                kl1[nt] = *(const bf16x8*)(qkL + ko + 32 + lg * 8);
            }
        }

        if (CAUSAL && kt >= 2 * qb) {
#pragma unroll
            for (int m = 0; m < 2; ++m)
#pragma unroll
                for (int nt = 0; nt < 4; ++nt)
#pragma unroll
                    for (int r = 0; r < 4; ++r) {
                        int qrow = qbase + w * 32 + m * 16 + lg * 4 + r;
                        int kcol = kbase + nt * 16 + lr;
                        if (kcol > qrow) accs[m][nt][r] = -1e30f;
                    }
        }

#pragma unroll
        for (int m = 0; m < 2; ++m) {
            float alpha[4];
#pragma unroll
            for (int r = 0; r < 4; ++r) {
                float mx = fmaxf(fmaxf(accs[m][0][r], accs[m][1][r]),
                                 fmaxf(accs[m][2][r], accs[m][3][r]));
                mx = fmaxf(mx, dpp_ror<1>(mx));
                mx = fmaxf(mx, dpp_ror<2>(mx));
                mx = fmaxf(mx, dpp_ror<4>(mx));
                mx = fmaxf(mx, dpp_ror<8>(mx));
                float mnew = fmaxf(mrow[m][r], mx);
                float sum = 0.0f;
#pragma unroll
                for (int nt = 0; nt < 4; ++nt) {
                    float p = __expf(accs[m][nt][r] - mnew);
                    accs[m][nt][r] = p;
                    sum += p;
                }
                sum += dpp_ror<1>(sum);
                sum += dpp_ror<2>(sum);
                sum += dpp_ror<4>(sum);
                sum += dpp_ror<8>(sum);
                alpha[r] = __expf(mrow[m][r] - mnew);
                lsum[m][r] = lsum[m][r] * alpha[r] + sum;
                mrow[m][r] = mnew;
            }
#pragma unroll
            for (int et = 0; et < 4; ++et)
#pragma unroll
                for (int r = 0; r < 4; ++r) acc_o[m][et][r] *= alpha[r];

#pragma unroll
            for (int nt = 0; nt < 4; ++nt)
#pragma unroll
                for (int r = 0; r < 4; ++r)
                    Ph[w][m * 16 + lg * 4 + r][nt * 16 + lr] = (bf16_t)accs[m][nt][r];
        }

#pragma unroll
        for (int m = 0; m < 2; ++m) {
            bf16x8 ap0 = *(const bf16x8*)&Ph[w][m * 16 + lr][lg * 8];
            bf16x8 ap1 = *(const bf16x8*)&Ph[w][m * 16 + lr][32 + lg * 8];
            __builtin_amdgcn_s_setprio(1);
#pragma unroll
            for (int et = 0; et < 4; ++et) {
                bf16x8 bv0 = *(const bf16x8*)&Vth[cur][et * 16 + lr][lg * 8];
                bf16x8 bv1 = *(const bf16x8*)&Vth[cur][et * 16 + lr][32 + lg * 8];
                acc_o[m][et] = __builtin_amdgcn_mfma_f32_16x16x32_bf16(ap0, bv0, acc_o[m][et], 0, 0, 0);
                acc_o[m][et] = __builtin_amdgcn_mfma_f32_16x16x32_bf16(ap1, bv1, acc_o[m][et], 0, 0, 0);
            }
            __builtin_amdgcn_s_setprio(0);
        }

#pragma unroll
        for (int rr = 0; rr < 2; ++rr)
#pragma unroll
            for (int j = 0; j < 8; ++j) Vth[cur ^ 1][vcol + j][vrow + rr * 32] = vreg[rr][j];
        __syncthreads();
        cur ^= 1;
    }

#pragma unroll
    for (int m = 0; m < 2; ++m) {
        size_t obase = (size_t)(b * TT + qbase + w * 32 + m * 16) * D + h * HS;
#pragma unroll
        for (int r = 0; r < 4; ++r) {
            float inv = 1.0f / lsum[m][r];
#pragma unroll
            for (int et = 0; et < 4; ++et) {
                float v = acc_o[m][et][r] * inv;
                size_t idx = obase + (size_t)(lg * 4 + r) * D + et * 16 + lr;
                oh[idx] = (bf16_t)v;
            }
        }
    }
}

// ---------------------------------------------------------------------------
extern "C" void kernel_launch(void* const* d_in, const int* in_sizes, int n_in,
                              void* d_out, int out_size, void* d_ws, size_t ws_size,
                              hipStream_t stream)
{
    const float* x     = (const float*)d_in[0];
    const float* Wq    = (const float*)d_in[1];
    const float* bq    = (const float*)d_in[2];
    const float* Wk    = (const float*)d_in[3];
    const float* bk    = (const float*)d_in[4];
    const float* Wv    = (const float*)d_in[5];
    const float* bv    = (const float*)d_in[6];
    const float* Wp    = (const float*)d_in[7];
    const float* bp    = (const float*)d_in[8];
    const float* gamma = (const float*)d_in[9];
    const float* W1    = (const float*)d_in[10];
    const float* b1    = (const float*)d_in[11];
    const float* W2    = (const float*)d_in[12];
    const float* b2    = (const float*)d_in[13];
    float* out = (float*)d_out;

    // workspace layout (96 MB):
    //  0..16  : nrm hi/lo (8 MB each); ao hi (aliased)
    // 16..48  : qk hi (16) + qk lo (16); h1 bf16-hi (32) aliases (ffn phase)
    // 48..56  : v hi (8); W1 conv slot (8, ffn phase, v dead)
    // 64..72  : W2 conv slot (8, ffn phase)
    // 80..96  : persistent weights: wAll hi 6 (wq|wk|wv), wqk lo 4, wp hi 2
    char* base = (char*)d_ws;
    bf16_t* nrmH  = (bf16_t*)(base);
    bf16_t* nrmL  = (bf16_t*)(base + (8u  << 20));
    bf16_t* qkH   = (bf16_t*)(base + (16u << 20));
    bf16_t* qkL   = (bf16_t*)(base + (32u << 20));
    bf16_t* vH    = (bf16_t*)(base + (48u << 20));
    bf16_t* h1H   = (bf16_t*)(base + (16u << 20));   // 32 MB, hi only
    bf16_t* w1sl  = (bf16_t*)(base + (48u << 20));   // 8 MB (hi only)
    bf16_t* w2sl  = (bf16_t*)(base + (64u << 20));   // 8 MB (hi only)
    bf16_t* wsl   = (bf16_t*)(base + (80u << 20));   // persistent
    bf16_t* aoH = nrmH;
    float* abuf = out;
    float* bbuf = out;

    // persistent weights: wAll hi [3072][1024] (wq|wk|wv), wqk lo, wp hi
    size_t DD = (size_t)D * D;
    bf16_t* wAllH = wsl;              // 3*DD
    bf16_t* wqkL  = wsl + 3 * DD;     // 2*DD
    bf16_t* wpH   = wsl + 5 * DD;     // 1*DD

    dim3 blk(256);
    dim3 gcv4(D / 64, D / 64, 4);
    dim3 gcv1(D / 64, HF / 64);
    dim3 gcv2(HF / 64, D / 64);
    dim3 gQKV(3 * D / 128, MR / 128);   // 24 x 32 = 768 blocks
    dim3 gP(D / 64, MR / 64);           // 16 x 64 = 1024 blocks, TM=TN=64
    dim3 gF(HF / 128, MR / 128);        // 32 x 32 = 1024 blocks, TM=TN=128
    dim3 gAnc(NH, TT / 128, BB);
    dim3 gAc(TT / 128, NH, BB);

    // ---- a = x + attn(rmsnorm(x), causal=false)
    rmsnorm_kernel<true><<<MR, blk, 0, stream>>>(x, gamma, nrmH, nrmL);
    convw4_kernel<<<gcv4, blk, 0, stream>>>(Wq, Wk, Wv, Wp, wAllH, wqkL, wAllH + 2 * DD, wpH);
    qkv_kernel<<<gQKV, blk, 0, stream>>>(nrmH, nrmL, wAllH, wqkL, bq, bk, bv, qkH, qkL, vH);
    attn_kernel<false><<<gAnc, blk, 0, stream>>>(qkH, qkL, vH, aoH);
    gemm_kernel<64, 64, false, false, false, 0, false, true><<<gP, blk, 0, stream>>>(aoH, nullptr, wpH, nullptr, bp, x, abuf, nullptr, nullptr, D, D);

    // ---- b = x + ffwd(rmsnorm(a))
    rmsnorm_kernel<false><<<MR, blk, 0, stream>>>(abuf, gamma, nrmH, nullptr);
    convw_kernel<false><<<gcv1, blk, 0, stream>>>(W1, w1sl, nullptr, D, HF);
    gemm_kernel<128, 128, true, false, false, 2, true, false><<<gF, blk, 0, stream>>>(nrmH, nullptr, w1sl, nullptr, b1, nullptr, nullptr, h1H, nullptr, HF, D);
    convw_kernel<false><<<gcv2, blk, 0, stream>>>(W2, w2sl, nullptr, HF, D);
    gemm_kernel<64, 64, false, false, false, 0, false, true><<<gP, blk, 0, stream>>>(h1H, nullptr, w2sl, nullptr, b2, x, bbuf, nullptr, nullptr, D, HF);

    // ---- c = b + attn(rmsnorm(b), causal=true)  (attn weights still resident)
    rmsnorm_kernel<true><<<MR, blk, 0, stream>>>(bbuf, gamma, nrmH, nrmL);
    qkv_kernel<<<gQKV, blk, 0, stream>>>(nrmH, nrmL, wAllH, wqkL, bq, bk, bv, qkH, qkL, vH);
    attn_kernel<true><<<gAc, blk, 0, stream>>>(qkH, qkL, vH, aoH);
    gemm_kernel<64, 64, false, false, false, 0, false, true><<<gP, blk, 0, stream>>>(aoH, nullptr, wpH, nullptr, bp, bbuf, out, nullptr, nullptr, D, D);
}